// Round 15
// baseline (1201.494 us; speedup 1.0000x reference)
//
#include <hip/hip_runtime.h>
#include <hip/hip_bf16.h>
#include <cmath>

// Problem constants
#define N_   128
#define T_   64
#define D_   1024
#define H_   1024
#define G4_  4096   // 4*H

typedef short bf16x8 __attribute__((ext_vector_type(8)));
typedef float f32x4  __attribute__((ext_vector_type(4)));

__device__ __forceinline__ unsigned short f2bf(float f) {
    union { float f; unsigned int u; } v; v.f = f;
    unsigned int r = (v.u + 0x7FFFu + ((v.u >> 16) & 1u)) >> 16;  // RNE
    return (unsigned short)r;
}
__device__ __forceinline__ float bf2f(unsigned short s) {
    union { unsigned int u; float f; } v; v.u = ((unsigned int)s) << 16;
    return v.f;
}

// Fragment-packed layout (mfma_f32_16x16x32_bf16, lane = kg*16+cl):
//   P[tile][kc][lane][8] bf16 ; wave fragment load = base + lane*8 -> 1KB contiguous.

// ---------------------------------------------------------------- prep ----

// pack weight src f32 [1024][4096] (k-major) -> fragment-packed B (rows = j).
__global__ void k_pack_w(const float* __restrict__ src, unsigned short* __restrict__ dst,
                         int kcoff, int kctot) {
    __shared__ float ld[64][33];
    int j0 = blockIdx.x * 32, k0 = blockIdx.y * 64;
    int tid = threadIdx.x;
    int c = tid & 31, r = tid >> 5;           // 32 j x 8 k
    #pragma unroll
    for (int i = 0; i < 8; i++)
        ld[r + i * 8][c] = src[(long)(k0 + r + i * 8) * G4_ + j0 + c];
    __syncthreads();
    int j = tid & 31, ku = tid >> 5;          // 32 j x 8 k-units of 8
    int kcl = ku >> 2, kg = ku & 3;
    int jti = (j0 + j) >> 4, cl = (j0 + j) & 15;
    int kc = kcoff + (k0 >> 5) + kcl;
    unsigned short q[8];
    #pragma unroll
    for (int e = 0; e < 8; e++) q[e] = f2bf(ld[ku * 8 + e][j]);
    *(uint4*)(dst + ((long)(jti * kctot + kc) * 64 + kg * 16 + cl) * 8) = *(uint4*)q;
}

// pack x f32 [N][T][D] -> xP tiles over m: tile = t*8 + (n>>4), rows = n&15.
__global__ void k_pack_x2(const float* __restrict__ x, unsigned short* __restrict__ xP) {
    long gid = (long)blockIdx.x * 256 + threadIdx.x;   // 8192*128
    int m = (int)(gid >> 7), u = (int)(gid & 127);
    const float* src = x + (long)m * 1024 + u * 8;
    int n = m >> 6, t = m & 63;
    int tile = t * 8 + (n >> 4);
    int kc = u >> 2, kg = u & 3, cl = n & 15;
    float4 a = *(const float4*)src, b = *(const float4*)(src + 4);
    unsigned short q[8] = {f2bf(a.x), f2bf(a.y), f2bf(a.z), f2bf(a.w),
                           f2bf(b.x), f2bf(b.y), f2bf(b.z), f2bf(b.w)};
    *(uint4*)(xP + ((long)(tile * 32 + kc) * 64 + kg * 16 + cl) * 8) = *(uint4*)q;
}

// A f32 [N][H][16] -> AfP (A-operand tiles: tile=n, row=p, k=h) + Af2 bf16 copy.
__global__ void k_pack_af(const float* __restrict__ A, unsigned short* __restrict__ AfP,
                          unsigned short* __restrict__ Af2) {
    __shared__ float ld[64][17];
    int n = blockIdx.x, h0 = blockIdx.y * 64;
    int tid = threadIdx.x;
    int hh = tid >> 2, pq = tid & 3;
    float4 v = *(const float4*)(A + ((long)n * H_ + h0 + hh) * 16 + pq * 4);
    unsigned short o[4] = {f2bf(v.x), f2bf(v.y), f2bf(v.z), f2bf(v.w)};
    *(uint2*)(Af2 + ((long)n * H_ + h0 + hh) * 16 + pq * 4) = *(uint2*)o;
    ld[hh][pq * 4 + 0] = v.x; ld[hh][pq * 4 + 1] = v.y;
    ld[hh][pq * 4 + 2] = v.z; ld[hh][pq * 4 + 3] = v.w;
    __syncthreads();
    if (tid < 128) {
        int p = tid >> 3, ku = tid & 7;
        int kc = (h0 >> 5) + (ku >> 2), kg = ku & 3;
        unsigned short q[8];
        #pragma unroll
        for (int e = 0; e < 8; e++) q[e] = f2bf(ld[ku * 8 + e][p]);
        *(uint4*)(AfP + ((long)(n * 32 + kc) * 64 + kg * 16 + p) * 8) = *(uint4*)q;
    }
}

// h0 = mean_p A; c0 = h0; packed h0.
__global__ void k_h0(const float* __restrict__ A, float* __restrict__ h,
                     float* __restrict__ c, unsigned short* __restrict__ hP0) {
    long id = (long)blockIdx.x * 256 + threadIdx.x;
    const float4* ap = (const float4*)(A + id * 16);
    float s = 0.f;
    #pragma unroll
    for (int q = 0; q < 4; q++) { float4 v = ap[q]; s += v.x + v.y + v.z + v.w; }
    float m = s * (1.0f / 16.0f);
    h[id] = m; c[id] = m;
    int n = (int)(id >> 10), j = (int)(id & 1023);
    hP0[((long)((n >> 4) * 32 + (j >> 5)) * 64 + ((j >> 3) & 3) * 16 + (n & 15)) * 8 + (j & 7)] = f2bf(m);
}

// t=0 score partials
__global__ __launch_bounds__(512)
void k_part0(const float* __restrict__ hbuf, const unsigned short* __restrict__ Af2,
             float* __restrict__ partial0) {
    int n = blockIdx.x;
    int tid = threadIdx.x;
    int jh = tid * 2;
    float sp[16];
    #pragma unroll
    for (int p = 0; p < 16; p++) sp[p] = 0.f;
    #pragma unroll
    for (int u = 0; u < 2; u++) {
        float hv = hbuf[(long)n * H_ + jh + u];
        const unsigned short* afp = Af2 + ((long)n * H_ + jh + u) * 16;
        bf16x8 a0 = *(const bf16x8*)(afp);
        bf16x8 a1 = *(const bf16x8*)(afp + 8);
        #pragma unroll
        for (int p = 0; p < 8; p++) { sp[p] += hv * bf2f((unsigned short)a0[p]);
                                      sp[8+p] += hv * bf2f((unsigned short)a1[p]); }
    }
    #pragma unroll
    for (int off = 1; off < 8; off <<= 1) {
        #pragma unroll
        for (int p = 0; p < 16; p++) sp[p] += __shfl_xor(sp[p], off);
    }
    int jt = tid >> 3;
    if ((tid & 7) == 0) {
        #pragma unroll
        for (int p = 0; p < 16; p++)
            partial0[((long)n * 16 + p) * 64 + jt] = sp[p];
    }
}

// AW = AfP @ WattnP^T (R10-proven, untouched)
__global__ __launch_bounds__(256, 2)
void k_aw(const unsigned short* __restrict__ AfP, const unsigned short* __restrict__ WattnP,
          unsigned short* __restrict__ AW) {
    int tid = threadIdx.x;
    int wv = tid >> 6, lane = tid & 63;
    int wr = wv >> 1, wc = wv & 1;
    int cl = lane & 15, kg = lane >> 4;
    int at0 = blockIdx.x * 8 + wr * 4;
    int jt0 = blockIdx.y * 8 + wc * 4;

    f32x4 acc[4][4];
    #pragma unroll
    for (int i = 0; i < 4; i++)
        #pragma unroll
        for (int j = 0; j < 4; j++) acc[i][j] = (f32x4){0.f, 0.f, 0.f, 0.f};

    const unsigned short* apx[4];
    const unsigned short* bpx[4];
    #pragma unroll
    for (int i = 0; i < 4; i++) {
        apx[i] = AfP    + (long)(at0 + i) * (32 * 512) + lane * 8;
        bpx[i] = WattnP + (long)(jt0 + i) * (32 * 512) + lane * 8;
    }
    #pragma unroll 2
    for (int kc = 0; kc < 32; kc++) {
        bf16x8 a[4], b[4];
        #pragma unroll
        for (int i = 0; i < 4; i++) a[i] = *(const bf16x8*)(apx[i] + kc * 512);
        #pragma unroll
        for (int i = 0; i < 4; i++) b[i] = *(const bf16x8*)(bpx[i] + kc * 512);
        #pragma unroll
        for (int i = 0; i < 4; i++)
            #pragma unroll
            for (int j = 0; j < 4; j++)
                acc[i][j] = __builtin_amdgcn_mfma_f32_16x16x32_bf16(a[i], b[j], acc[i][j], 0, 0, 0);
    }
    #pragma unroll
    for (int i = 0; i < 4; i++) {
        int n = at0 + i;
        #pragma unroll
        for (int j = 0; j < 4; j++) {
            int jj = (jt0 + j) * 16 + cl;
            #pragma unroll
            for (int v = 0; v < 4; v++) {
                int p = kg * 4 + v;
                AW[((long)n * G4_ + jj) * 16 + p] = f2bf(acc[i][j][v]);
            }
        }
    }
}

// actx = xP @ WxP^T (R13-proven 4x4 wave tile, grid (64, 32)).
__global__ __launch_bounds__(256, 2)
void k_actx(const unsigned short* __restrict__ xP, const unsigned short* __restrict__ WxP,
            unsigned short* __restrict__ actx) {
    int tid = threadIdx.x;
    int wv = tid >> 6, lane = tid & 63;
    int wr = wv >> 1, wc = wv & 1;
    int cl = lane & 15, kg = lane >> 4;
    int at0 = blockIdx.x * 8 + wr * 4;    // A tiles (0..511)
    int jt0 = blockIdx.y * 8 + wc * 4;    // B tiles (0..255)

    f32x4 acc[4][4];
    #pragma unroll
    for (int i = 0; i < 4; i++)
        #pragma unroll
        for (int j = 0; j < 4; j++) acc[i][j] = (f32x4){0.f, 0.f, 0.f, 0.f};

    const unsigned short* apx[4];
    const unsigned short* bpx[4];
    #pragma unroll
    for (int i = 0; i < 4; i++) {
        apx[i] = xP  + (long)(at0 + i) * (32 * 512) + lane * 8;
        bpx[i] = WxP + (long)(jt0 + i) * (32 * 512) + lane * 8;
    }
    #pragma unroll 2
    for (int kc = 0; kc < 32; kc++) {
        bf16x8 a[4], b[4];
        #pragma unroll
        for (int i = 0; i < 4; i++) a[i] = *(const bf16x8*)(apx[i] + kc * 512);
        #pragma unroll
        for (int i = 0; i < 4; i++) b[i] = *(const bf16x8*)(bpx[i] + kc * 512);
        #pragma unroll
        for (int i = 0; i < 4; i++)
            #pragma unroll
            for (int j = 0; j < 4; j++)
                acc[i][j] = __builtin_amdgcn_mfma_f32_16x16x32_bf16(a[i], b[j], acc[i][j], 0, 0, 0);
    }
    #pragma unroll
    for (int i = 0; i < 4; i++) {
        long mrow = (long)(at0 + i) * 16;
        #pragma unroll
        for (int j = 0; j < 4; j++) {
            int jj = (jt0 + j) * 16 + cl;
            #pragma unroll
            for (int v = 0; v < 4; v++)
                actx[(mrow + kg * 4 + v) * G4_ + jj] = f2bf(acc[i][j][v]);
        }
    }
}

// ------------------------------------------------------------- per step ----

// ONE kernel per step: front (softmax w from partIN via float4 reads) ->
// K=1024 h-GEMM (R13-proven) -> epilogue.
// grid (64 jt, 4 nt2), 512 thr = 8 waves (ks:4 x rh:2).
__global__ __launch_bounds__(512, 2)
void k_step(const unsigned short* __restrict__ actx,   // bf16 [8192][4096]
            const unsigned short* __restrict__ hPin,   // packed [8 nt][32 kc][64][8]
            unsigned short* __restrict__ hPout,
            const unsigned short* __restrict__ WhP,    // [256 jti][32 kc][64][8]
            const unsigned short* __restrict__ AW,     // [N][4096][16]
            const unsigned short* __restrict__ Af2,    // [N][H][16]
            const float* __restrict__ partIN,          // [N][16][64]
            float* __restrict__ partOUT,               // [N][16][64]
            const float* __restrict__ bvec,
            float* __restrict__ c,
            float* __restrict__ out, int t) {
    int tid = threadIdx.x;
    int wv = tid >> 6, lane = tid & 63;
    int ks = wv & 3, rh = wv >> 2;
    int cl = lane & 15, kg = lane >> 4;
    int jt = blockIdx.x;
    int nt2 = blockIdx.y;
    int colbase = jt * 16;

    __shared__ float wsm[32][17];
    __shared__ float red[3][2][64][17];
    __shared__ float act[4][32][17];

    // ---- front: softmax w for this block's 32 n's; float4 reads (16/thread) ----
    {
        int nloc = tid >> 4, p = tid & 15;
        int n = nt2 * 32 + nloc;
        const float4* src = (const float4*)(partIN + ((long)n * 16 + p) * 64);
        float s = 0.f;
        #pragma unroll
        for (int q = 0; q < 16; q++) {
            float4 v = src[q];
            s += (v.x + v.y) + (v.z + v.w);
        }
        s *= (1.0f / 32.0f);               // /sqrt(H)
        float m = s;
        #pragma unroll
        for (int off = 1; off < 16; off <<= 1) m = fmaxf(m, __shfl_xor(m, off));
        float e = expf(s - m);
        float sum = e;
        #pragma unroll
        for (int off = 1; off < 16; off <<= 1) sum += __shfl_xor(sum, off);
        wsm[nloc][p] = e / sum;
    }

    // ---- GEMM: 16 rows (rh half) x 16 jh x 4 gates over K=256 (8 kc) ----
    f32x4 acc[4];
    #pragma unroll
    for (int g = 0; g < 4; g++) acc[g] = (f32x4){0.f, 0.f, 0.f, 0.f};

    const unsigned short* abase = hPin + ((long)(nt2 * 2 + rh) * 32 + ks * 8) * 512 + lane * 8;
    const unsigned short* bb[4];
    #pragma unroll
    for (int g = 0; g < 4; g++)
        bb[g] = WhP + ((long)(g * 64 + jt) * 32 + ks * 8) * 512 + lane * 8;

    #pragma unroll
    for (int i = 0; i < 8; i++) {
        bf16x8 a = *(const bf16x8*)(abase + i * 512);
        #pragma unroll
        for (int g = 0; g < 4; g++) {
            bf16x8 b = *(const bf16x8*)(bb[g] + i * 512);
            acc[g] = __builtin_amdgcn_mfma_f32_16x16x32_bf16(a, b, acc[g], 0, 0, 0);
        }
    }

    // ---- 4-way K reduce per rh ----
    if (ks != 0) {
        #pragma unroll
        for (int g = 0; g < 4; g++)
            #pragma unroll
            for (int v = 0; v < 4; v++) red[ks - 1][rh][lane][g * 4 + v] = acc[g][v];
    }
    __syncthreads();
    if (ks == 0) {
        #pragma unroll
        for (int g = 0; g < 4; g++)
            #pragma unroll
            for (int v = 0; v < 4; v++) {
                float s = acc[g][v] + red[0][rh][lane][g*4+v] + red[1][rh][lane][g*4+v]
                        + red[2][rh][lane][g*4+v];
                act[g][rh * 16 + kg * 4 + v][cl] = s;   // C/D row = 4*kg + v
            }
    }
    __syncthreads();

    // ---- epilogue: 512 thr x 1 (n, jh) cell ----
    int nloc = tid >> 4, jl = tid & 15;
    int n = nt2 * 32 + nloc, jh = colbase + jl;
    float wv16[16];
    #pragma unroll
    for (int p = 0; p < 16; p++) wv16[p] = wsm[nloc][p];

    long rm = (long)(t * 8 + (n >> 4)) * 16 + (n & 15);   // actx row
    float s4[4];
    #pragma unroll
    for (int g = 0; g < 4; g++) {
        int j = g * 1024 + jh;
        const unsigned short* awp = AW + ((long)n * G4_ + j) * 16;
        bf16x8 aw0 = *(const bf16x8*)(awp);
        bf16x8 aw1 = *(const bf16x8*)(awp + 8);
        float at = 0.f;
        #pragma unroll
        for (int p = 0; p < 8; p++) at += wv16[p]     * bf2f((unsigned short)aw0[p]);
        #pragma unroll
        for (int p = 0; p < 8; p++) at += wv16[8 + p] * bf2f((unsigned short)aw1[p]);
        s4[g] = act[g][nloc][jl] + bf2f(actx[rm * G4_ + j]) + at + bvec[j];
    }
    float ig = 1.f / (1.f + expf(-s4[0]));
    float fg = 1.f / (1.f + expf(-s4[1]));
    float og = 1.f / (1.f + expf(-s4[2]));
    float gg = tanhf(s4[3]);
    long idx = (long)n * H_ + jh;
    float cn = fg * c[idx] + ig * gg;
    float hn = og * tanhf(cn);
    c[idx] = cn;
    out[((long)n * T_ + t) * H_ + jh] = hn;
    hPout[((long)((n >> 4) * 32 + (jh >> 5)) * 64 + ((jh >> 3) & 3) * 16 + (n & 15)) * 8 + (jh & 7)] = f2bf(hn);

    // score partials for t+1
    const unsigned short* afp = Af2 + ((long)n * H_ + jh) * 16;
    bf16x8 af0 = *(const bf16x8*)(afp);
    bf16x8 af1 = *(const bf16x8*)(afp + 8);
    float sp[16];
    #pragma unroll
    for (int p = 0; p < 8; p++) { sp[p]     = hn * bf2f((unsigned short)af0[p]);
                                  sp[8 + p] = hn * bf2f((unsigned short)af1[p]); }
    #pragma unroll
    for (int off = 1; off < 16; off <<= 1) {
        #pragma unroll
        for (int p = 0; p < 16; p++) sp[p] += __shfl_xor(sp[p], off);
    }
    float outv = 0.f;
    #pragma unroll
    for (int p = 0; p < 16; p++) if (jl == p) outv = sp[p];
    partOUT[((long)n * 16 + jl) * 64 + jt] = outv;
}

// ---------------------------------------------------------------- launch ----

extern "C" void kernel_launch(void* const* d_in, const int* in_sizes, int n_in,
                              void* d_out, int out_size, void* d_ws, size_t ws_size,
                              hipStream_t stream) {
    const float* x     = (const float*)d_in[0];
    const float* A     = (const float*)d_in[1];
    const float* Wx    = (const float*)d_in[2];
    const float* Wh    = (const float*)d_in[3];
    const float* Wattn = (const float*)d_in[4];
    const float* b     = (const float*)d_in[5];
    float* out = (float*)d_out;

    char* ws = (char*)d_ws;
    size_t off = 0;
    auto alloc = [&](size_t bytes) -> void* {
        void* p = ws + off;
        off += (bytes + 255) & ~(size_t)255;
        return p;
    };
    unsigned short* xP     = (unsigned short*)alloc((size_t)512 * 32 * 512 * 2);   // 16.8MB
    unsigned short* WxP    = (unsigned short*)alloc((size_t)256 * 32 * 512 * 2);   // 8.4MB
    unsigned short* WhP    = (unsigned short*)alloc((size_t)256 * 32 * 512 * 2);   // 8.4MB
    unsigned short* WattnP = (unsigned short*)alloc((size_t)256 * 32 * 512 * 2);   // 8.4MB
    unsigned short* AfP    = (unsigned short*)alloc((size_t)128 * 32 * 512 * 2);   // 4.2MB
    unsigned short* Af2    = (unsigned short*)alloc((size_t)N_ * H_ * 16 * 2);     // 4.2MB
    unsigned short* AW     = (unsigned short*)alloc((size_t)N_ * G4_ * 16 * 2);    // 16.8MB
    unsigned short* actx   = (unsigned short*)alloc((size_t)8192 * G4_ * 2);       // 67.1MB
    float*          hbuf   = (float*)alloc((size_t)N_ * H_ * 4);
    float*          cbuf   = (float*)alloc((size_t)N_ * H_ * 4);
    unsigned short* hP0    = (unsigned short*)alloc((size_t)8 * 32 * 512 * 2);
    unsigned short* hP1    = (unsigned short*)alloc((size_t)8 * 32 * 512 * 2);
    float*          part0  = (float*)alloc((size_t)N_ * 16 * 64 * 4);
    float*          part1  = (float*)alloc((size_t)N_ * 16 * 64 * 4);

    // prep
    k_pack_w<<<dim3(128, 16), dim3(256), 0, stream>>>(Wx,    WxP,    0, 32);
    k_pack_w<<<dim3(128, 16), dim3(256), 0, stream>>>(Wh,    WhP,    0, 32);
    k_pack_w<<<dim3(128, 16), dim3(256), 0, stream>>>(Wattn, WattnP, 0, 32);
    k_pack_x2<<<dim3(4096), dim3(256), 0, stream>>>(x, xP);
    k_pack_af<<<dim3(128, 16), dim3(256), 0, stream>>>(A, AfP, Af2);
    k_h0<<<dim3(512), dim3(256), 0, stream>>>(A, hbuf, cbuf, hP0);
    k_part0<<<dim3(N_), dim3(512), 0, stream>>>(hbuf, Af2, part0);
    k_aw<<<dim3(16, 32), dim3(256), 0, stream>>>(AfP, WattnP, AW);
    k_actx<<<dim3(64, 32), dim3(256), 0, stream>>>(xP, WxP, actx);

    // recurrence: ONE kernel per step
    for (int t = 0; t < T_; t++) {
        unsigned short* hin  = (t & 1) ? hP1 : hP0;
        unsigned short* hout = (t & 1) ? hP0 : hP1;
        float* pIN  = (t & 1) ? part1 : part0;
        float* pOUT = (t & 1) ? part0 : part1;
        k_step<<<dim3(64, 4), dim3(512), 0, stream>>>(actx, hin, hout, WhP, AW, Af2,
                                                      pIN, pOUT, b, cbuf, out, t);
    }
}

// Round 18
// 1084.593 us; speedup vs baseline: 1.1078x; 1.1078x over previous
//
#include <hip/hip_runtime.h>
#include <hip/hip_bf16.h>
#include <cmath>

// Problem constants
#define N_   128
#define T_   64
#define D_   1024
#define H_   1024
#define G4_  4096   // 4*H

typedef short bf16x8 __attribute__((ext_vector_type(8)));
typedef float f32x4  __attribute__((ext_vector_type(4)));

__device__ __forceinline__ unsigned short f2bf(float f) {
    union { float f; unsigned int u; } v; v.f = f;
    unsigned int r = (v.u + 0x7FFFu + ((v.u >> 16) & 1u)) >> 16;  // RNE
    return (unsigned short)r;
}
__device__ __forceinline__ float bf2f(unsigned short s) {
    union { unsigned int u; float f; } v; v.u = ((unsigned int)s) << 16;
    return v.f;
}

// Fragment-packed layout (mfma_f32_16x16x32_bf16, lane = kg*16+cl):
//   P[tile][kc][lane][8] bf16 ; wave fragment load = base + lane*8 -> 1KB contiguous.
// partial layout: [n][jt][16p]  (16-lane group writes 64B contiguous)

// ---------------------------------------------------------------- prep ----

// pack weight src f32 [1024][4096] (k-major) -> fragment-packed B (rows = j).
__global__ void k_pack_w(const float* __restrict__ src, unsigned short* __restrict__ dst,
                         int kcoff, int kctot) {
    __shared__ float ld[64][33];
    int j0 = blockIdx.x * 32, k0 = blockIdx.y * 64;
    int tid = threadIdx.x;
    int c = tid & 31, r = tid >> 5;           // 32 j x 8 k
    #pragma unroll
    for (int i = 0; i < 8; i++)
        ld[r + i * 8][c] = src[(long)(k0 + r + i * 8) * G4_ + j0 + c];
    __syncthreads();
    int j = tid & 31, ku = tid >> 5;          // 32 j x 8 k-units of 8
    int kcl = ku >> 2, kg = ku & 3;
    int jti = (j0 + j) >> 4, cl = (j0 + j) & 15;
    int kc = kcoff + (k0 >> 5) + kcl;
    unsigned short q[8];
    #pragma unroll
    for (int e = 0; e < 8; e++) q[e] = f2bf(ld[ku * 8 + e][j]);
    *(uint4*)(dst + ((long)(jti * kctot + kc) * 64 + kg * 16 + cl) * 8) = *(uint4*)q;
}

// pack x f32 [N][T][D] -> xP tiles over m: tile = t*8 + (n>>4), rows = n&15.
__global__ void k_pack_x2(const float* __restrict__ x, unsigned short* __restrict__ xP) {
    long gid = (long)blockIdx.x * 256 + threadIdx.x;   // 8192*128
    int m = (int)(gid >> 7), u = (int)(gid & 127);
    const float* src = x + (long)m * 1024 + u * 8;
    int n = m >> 6, t = m & 63;
    int tile = t * 8 + (n >> 4);
    int kc = u >> 2, kg = u & 3, cl = n & 15;
    float4 a = *(const float4*)src, b = *(const float4*)(src + 4);
    unsigned short q[8] = {f2bf(a.x), f2bf(a.y), f2bf(a.z), f2bf(a.w),
                           f2bf(b.x), f2bf(b.y), f2bf(b.z), f2bf(b.w)};
    *(uint4*)(xP + ((long)(tile * 32 + kc) * 64 + kg * 16 + cl) * 8) = *(uint4*)q;
}

// A f32 [N][H][16] -> AfP (A-operand tiles: tile=n, row=p, k=h) + Af2 bf16 copy.
__global__ void k_pack_af(const float* __restrict__ A, unsigned short* __restrict__ AfP,
                          unsigned short* __restrict__ Af2) {
    __shared__ float ld[64][17];
    int n = blockIdx.x, h0 = blockIdx.y * 64;
    int tid = threadIdx.x;
    int hh = tid >> 2, pq = tid & 3;
    float4 v = *(const float4*)(A + ((long)n * H_ + h0 + hh) * 16 + pq * 4);
    unsigned short o[4] = {f2bf(v.x), f2bf(v.y), f2bf(v.z), f2bf(v.w)};
    *(uint2*)(Af2 + ((long)n * H_ + h0 + hh) * 16 + pq * 4) = *(uint2*)o;
    ld[hh][pq * 4 + 0] = v.x; ld[hh][pq * 4 + 1] = v.y;
    ld[hh][pq * 4 + 2] = v.z; ld[hh][pq * 4 + 3] = v.w;
    __syncthreads();
    if (tid < 128) {
        int p = tid >> 3, ku = tid & 7;
        int kc = (h0 >> 5) + (ku >> 2), kg = ku & 3;
        unsigned short q[8];
        #pragma unroll
        for (int e = 0; e < 8; e++) q[e] = f2bf(ld[ku * 8 + e][p]);
        *(uint4*)(AfP + ((long)(n * 32 + kc) * 64 + kg * 16 + p) * 8) = *(uint4*)q;
    }
}

// h0 = mean_p A; c0 = h0; packed h0.
__global__ void k_h0(const float* __restrict__ A, float* __restrict__ h,
                     float* __restrict__ c, unsigned short* __restrict__ hP0) {
    long id = (long)blockIdx.x * 256 + threadIdx.x;
    const float4* ap = (const float4*)(A + id * 16);
    float s = 0.f;
    #pragma unroll
    for (int q = 0; q < 4; q++) { float4 v = ap[q]; s += v.x + v.y + v.z + v.w; }
    float m = s * (1.0f / 16.0f);
    h[id] = m; c[id] = m;
    int n = (int)(id >> 10), j = (int)(id & 1023);
    hP0[((long)((n >> 4) * 32 + (j >> 5)) * 64 + ((j >> 3) & 3) * 16 + (n & 15)) * 8 + (j & 7)] = f2bf(m);
}

// t=0 score partials (new [n][jt][16] layout)
__global__ __launch_bounds__(512)
void k_part0(const float* __restrict__ hbuf, const unsigned short* __restrict__ Af2,
             float* __restrict__ partial0) {
    int n = blockIdx.x;
    int tid = threadIdx.x;
    int jh = tid * 2;
    float sp[16];
    #pragma unroll
    for (int p = 0; p < 16; p++) sp[p] = 0.f;
    #pragma unroll
    for (int u = 0; u < 2; u++) {
        float hv = hbuf[(long)n * H_ + jh + u];
        const unsigned short* afp = Af2 + ((long)n * H_ + jh + u) * 16;
        bf16x8 a0 = *(const bf16x8*)(afp);
        bf16x8 a1 = *(const bf16x8*)(afp + 8);
        #pragma unroll
        for (int p = 0; p < 8; p++) { sp[p] += hv * bf2f((unsigned short)a0[p]);
                                      sp[8+p] += hv * bf2f((unsigned short)a1[p]); }
    }
    #pragma unroll
    for (int off = 1; off < 8; off <<= 1) {
        #pragma unroll
        for (int p = 0; p < 16; p++) sp[p] += __shfl_xor(sp[p], off);
    }
    int jt = tid >> 3;
    if ((tid & 7) == 0) {
        float4* dst = (float4*)(partial0 + ((long)n * 64 + jt) * 16);
        dst[0] = make_float4(sp[0],  sp[1],  sp[2],  sp[3]);
        dst[1] = make_float4(sp[4],  sp[5],  sp[6],  sp[7]);
        dst[2] = make_float4(sp[8],  sp[9],  sp[10], sp[11]);
        dst[3] = make_float4(sp[12], sp[13], sp[14], sp[15]);
    }
}

// reduce partial -> softmax -> w. lane = jt; float4 loads; 6-step butterfly.
__global__ __launch_bounds__(64)
void k_score_tiny(const float* __restrict__ partial, float* __restrict__ wbuf) {
    int n = blockIdx.x;
    int lane = threadIdx.x;   // = jt
    const float4* src = (const float4*)(partial + ((long)n * 64 + lane) * 16);
    float sp[16];
    #pragma unroll
    for (int q = 0; q < 4; q++) {
        float4 v = src[q];
        sp[q*4+0] = v.x; sp[q*4+1] = v.y; sp[q*4+2] = v.z; sp[q*4+3] = v.w;
    }
    #pragma unroll
    for (int off = 1; off < 64; off <<= 1) {
        #pragma unroll
        for (int p = 0; p < 16; p++) sp[p] += __shfl_xor(sp[p], off);
    }
    float m = -1e30f;
    #pragma unroll
    for (int p = 0; p < 16; p++) { sp[p] *= (1.0f / 32.0f); m = fmaxf(m, sp[p]); }
    float sum = 0.f;
    float e[16];
    #pragma unroll
    for (int p = 0; p < 16; p++) { e[p] = expf(sp[p] - m); sum += e[p]; }
    if (lane < 16) wbuf[n * 16 + lane] = e[lane] / sum;
}

// AW = AfP @ WattnP^T (R10-proven, untouched)
__global__ __launch_bounds__(256, 2)
void k_aw(const unsigned short* __restrict__ AfP, const unsigned short* __restrict__ WattnP,
          unsigned short* __restrict__ AW) {
    int tid = threadIdx.x;
    int wv = tid >> 6, lane = tid & 63;
    int wr = wv >> 1, wc = wv & 1;
    int cl = lane & 15, kg = lane >> 4;
    int at0 = blockIdx.x * 8 + wr * 4;
    int jt0 = blockIdx.y * 8 + wc * 4;

    f32x4 acc[4][4];
    #pragma unroll
    for (int i = 0; i < 4; i++)
        #pragma unroll
        for (int j = 0; j < 4; j++) acc[i][j] = (f32x4){0.f, 0.f, 0.f, 0.f};

    const unsigned short* apx[4];
    const unsigned short* bpx[4];
    #pragma unroll
    for (int i = 0; i < 4; i++) {
        apx[i] = AfP    + (long)(at0 + i) * (32 * 512) + lane * 8;
        bpx[i] = WattnP + (long)(jt0 + i) * (32 * 512) + lane * 8;
    }
    #pragma unroll 2
    for (int kc = 0; kc < 32; kc++) {
        bf16x8 a[4], b[4];
        #pragma unroll
        for (int i = 0; i < 4; i++) a[i] = *(const bf16x8*)(apx[i] + kc * 512);
        #pragma unroll
        for (int i = 0; i < 4; i++) b[i] = *(const bf16x8*)(bpx[i] + kc * 512);
        #pragma unroll
        for (int i = 0; i < 4; i++)
            #pragma unroll
            for (int j = 0; j < 4; j++)
                acc[i][j] = __builtin_amdgcn_mfma_f32_16x16x32_bf16(a[i], b[j], acc[i][j], 0, 0, 0);
    }
    #pragma unroll
    for (int i = 0; i < 4; i++) {
        int n = at0 + i;
        #pragma unroll
        for (int j = 0; j < 4; j++) {
            int jj = (jt0 + j) * 16 + cl;
            #pragma unroll
            for (int v = 0; v < 4; v++) {
                int p = kg * 4 + v;
                AW[((long)n * G4_ + jj) * 16 + p] = f2bf(acc[i][j][v]);
            }
        }
    }
}

// actx = xP @ WxP^T (R13-proven 4x4 wave tile, grid (64, 32)).
__global__ __launch_bounds__(256, 2)
void k_actx(const unsigned short* __restrict__ xP, const unsigned short* __restrict__ WxP,
            unsigned short* __restrict__ actx) {
    int tid = threadIdx.x;
    int wv = tid >> 6, lane = tid & 63;
    int wr = wv >> 1, wc = wv & 1;
    int cl = lane & 15, kg = lane >> 4;
    int at0 = blockIdx.x * 8 + wr * 4;    // A tiles (0..511)
    int jt0 = blockIdx.y * 8 + wc * 4;    // B tiles (0..255)

    f32x4 acc[4][4];
    #pragma unroll
    for (int i = 0; i < 4; i++)
        #pragma unroll
        for (int j = 0; j < 4; j++) acc[i][j] = (f32x4){0.f, 0.f, 0.f, 0.f};

    const unsigned short* apx[4];
    const unsigned short* bpx[4];
    #pragma unroll
    for (int i = 0; i < 4; i++) {
        apx[i] = xP  + (long)(at0 + i) * (32 * 512) + lane * 8;
        bpx[i] = WxP + (long)(jt0 + i) * (32 * 512) + lane * 8;
    }
    #pragma unroll 2
    for (int kc = 0; kc < 32; kc++) {
        bf16x8 a[4], b[4];
        #pragma unroll
        for (int i = 0; i < 4; i++) a[i] = *(const bf16x8*)(apx[i] + kc * 512);
        #pragma unroll
        for (int i = 0; i < 4; i++) b[i] = *(const bf16x8*)(bpx[i] + kc * 512);
        #pragma unroll
        for (int i = 0; i < 4; i++)
            #pragma unroll
            for (int j = 0; j < 4; j++)
                acc[i][j] = __builtin_amdgcn_mfma_f32_16x16x32_bf16(a[i], b[j], acc[i][j], 0, 0, 0);
    }
    #pragma unroll
    for (int i = 0; i < 4; i++) {
        long mrow = (long)(at0 + i) * 16;
        #pragma unroll
        for (int j = 0; j < 4; j++) {
            int jj = (jt0 + j) * 16 + cl;
            #pragma unroll
            for (int v = 0; v < 4; v++)
                actx[(mrow + kg * 4 + v) * G4_ + jj] = f2bf(acc[i][j][v]);
        }
    }
}

// ------------------------------------------------------------- per step ----

// k_step (R13 GEMM body; epilogue with coalesced hPout via LDS repack and
// contiguous partOUT writes). grid (64 jt, 4 nt2), 512 thr = 8 waves (ks:4 x rh:2).
__global__ __launch_bounds__(512, 2)
void k_step(const unsigned short* __restrict__ actx,   // bf16 [8192][4096]
            const unsigned short* __restrict__ hPin,   // packed [8 nt][32 kc][64][8]
            unsigned short* __restrict__ hPout,
            const unsigned short* __restrict__ WhP,    // [256 jti][32 kc][64][8]
            const unsigned short* __restrict__ AW,     // [N][4096][16]
            const unsigned short* __restrict__ Af2,    // [N][H][16]
            const float* __restrict__ wbuf,            // [N][16]
            const float* __restrict__ bvec,
            float* __restrict__ c,
            float* __restrict__ partOUT,               // [N][64 jt][16]
            float* __restrict__ out, int t) {
    int tid = threadIdx.x;
    int wv = tid >> 6, lane = tid & 63;
    int ks = wv & 3, rh = wv >> 2;
    int cl = lane & 15, kg = lane >> 4;
    int jt = blockIdx.x;
    int nt2 = blockIdx.y;
    int colbase = jt * 16;

    __shared__ float red[3][2][64][17];
    __shared__ float act[4][32][17];
    __shared__ alignas(16) unsigned short hnb[2][2][16][8];  // hP-mirror staging

    // ---- GEMM: 16 rows (rh half) x 16 jh x 4 gates over K=256 (8 kc) ----
    f32x4 acc[4];
    #pragma unroll
    for (int g = 0; g < 4; g++) acc[g] = (f32x4){0.f, 0.f, 0.f, 0.f};

    const unsigned short* abase = hPin + ((long)(nt2 * 2 + rh) * 32 + ks * 8) * 512 + lane * 8;
    const unsigned short* bb[4];
    #pragma unroll
    for (int g = 0; g < 4; g++)
        bb[g] = WhP + ((long)(g * 64 + jt) * 32 + ks * 8) * 512 + lane * 8;

    #pragma unroll
    for (int i = 0; i < 8; i++) {
        bf16x8 a = *(const bf16x8*)(abase + i * 512);
        #pragma unroll
        for (int g = 0; g < 4; g++) {
            bf16x8 b = *(const bf16x8*)(bb[g] + i * 512);
            acc[g] = __builtin_amdgcn_mfma_f32_16x16x32_bf16(a, b, acc[g], 0, 0, 0);
        }
    }

    // ---- 4-way K reduce per rh ----
    if (ks != 0) {
        #pragma unroll
        for (int g = 0; g < 4; g++)
            #pragma unroll
            for (int v = 0; v < 4; v++) red[ks - 1][rh][lane][g * 4 + v] = acc[g][v];
    }
    __syncthreads();
    if (ks == 0) {
        #pragma unroll
        for (int g = 0; g < 4; g++)
            #pragma unroll
            for (int v = 0; v < 4; v++) {
                float s = acc[g][v] + red[0][rh][lane][g*4+v] + red[1][rh][lane][g*4+v]
                        + red[2][rh][lane][g*4+v];
                act[g][rh * 16 + kg * 4 + v][cl] = s;   // C/D row = 4*kg + v
            }
    }
    __syncthreads();

    // ---- epilogue: 512 thr x 1 (n, jh) cell ----
    int nloc = tid >> 4, jl = tid & 15;
    int n = nt2 * 32 + nloc, jh = colbase + jl;
    float wv16[16];
    #pragma unroll
    for (int p = 0; p < 16; p++) wv16[p] = wbuf[n * 16 + p];

    long rm = (long)(t * 8 + (n >> 4)) * 16 + (n & 15);   // actx row
    float s4[4];
    #pragma unroll
    for (int g = 0; g < 4; g++) {
        int j = g * 1024 + jh;
        const unsigned short* awp = AW + ((long)n * G4_ + j) * 16;
        bf16x8 aw0 = *(const bf16x8*)(awp);
        bf16x8 aw1 = *(const bf16x8*)(awp + 8);
        float at = 0.f;
        #pragma unroll
        for (int p = 0; p < 8; p++) at += wv16[p]     * bf2f((unsigned short)aw0[p]);
        #pragma unroll
        for (int p = 0; p < 8; p++) at += wv16[8 + p] * bf2f((unsigned short)aw1[p]);
        s4[g] = act[g][nloc][jl] + bf2f(actx[rm * G4_ + j]) + at + bvec[j];
    }
    float ig = 1.f / (1.f + expf(-s4[0]));
    float fg = 1.f / (1.f + expf(-s4[1]));
    float og = 1.f / (1.f + expf(-s4[2]));
    float gg = tanhf(s4[3]);
    long idx = (long)n * H_ + jh;
    float cn = fg * c[idx] + ig * gg;
    float hn = og * tanhf(cn);
    c[idx] = cn;
    out[((long)n * T_ + t) * H_ + jh] = hn;
    // stage packed-h in LDS (hP-mirror), coalesced store after barrier
    hnb[nloc >> 4][jl >> 3][nloc & 15][jl & 7] = f2bf(hn);

    // score partials for t+1 (contiguous [n][jt][16] write)
    const unsigned short* afp = Af2 + ((long)n * H_ + jh) * 16;
    bf16x8 af0 = *(const bf16x8*)(afp);
    bf16x8 af1 = *(const bf16x8*)(afp + 8);
    float sp[16];
    #pragma unroll
    for (int p = 0; p < 8; p++) { sp[p]     = hn * bf2f((unsigned short)af0[p]);
                                  sp[8 + p] = hn * bf2f((unsigned short)af1[p]); }
    #pragma unroll
    for (int off = 1; off < 16; off <<= 1) {
        #pragma unroll
        for (int p = 0; p < 16; p++) sp[p] += __shfl_xor(sp[p], off);
    }
    partOUT[((long)n * 64 + jt) * 16 + jl] = sp[jl];

    // ---- coalesced hPout copy: 64 threads x 16B ----
    __syncthreads();
    if (tid < 64) {
        int tile_i = tid >> 5, subi = (tid >> 4) & 1, n15 = tid & 15;
        long dstoff = (((long)(nt2 * 2 + tile_i) * 32 + (jt >> 1)) * 64
                       + ((2 * jt + subi) & 3) * 16 + n15) * 8;
        *(uint4*)(hPout + dstoff) = *(const uint4*)(&hnb[tile_i][subi][n15][0]);
    }
}

// ---------------------------------------------------------------- launch ----

extern "C" void kernel_launch(void* const* d_in, const int* in_sizes, int n_in,
                              void* d_out, int out_size, void* d_ws, size_t ws_size,
                              hipStream_t stream) {
    const float* x     = (const float*)d_in[0];
    const float* A     = (const float*)d_in[1];
    const float* Wx    = (const float*)d_in[2];
    const float* Wh    = (const float*)d_in[3];
    const float* Wattn = (const float*)d_in[4];
    const float* b     = (const float*)d_in[5];
    float* out = (float*)d_out;

    char* ws = (char*)d_ws;
    size_t off = 0;
    auto alloc = [&](size_t bytes) -> void* {
        void* p = ws + off;
        off += (bytes + 255) & ~(size_t)255;
        return p;
    };
    unsigned short* xP     = (unsigned short*)alloc((size_t)512 * 32 * 512 * 2);   // 16.8MB
    unsigned short* WxP    = (unsigned short*)alloc((size_t)256 * 32 * 512 * 2);   // 8.4MB
    unsigned short* WhP    = (unsigned short*)alloc((size_t)256 * 32 * 512 * 2);   // 8.4MB
    unsigned short* WattnP = (unsigned short*)alloc((size_t)256 * 32 * 512 * 2);   // 8.4MB
    unsigned short* AfP    = (unsigned short*)alloc((size_t)128 * 32 * 512 * 2);   // 4.2MB
    unsigned short* Af2    = (unsigned short*)alloc((size_t)N_ * H_ * 16 * 2);     // 4.2MB
    unsigned short* AW     = (unsigned short*)alloc((size_t)N_ * G4_ * 16 * 2);    // 16.8MB
    unsigned short* actx   = (unsigned short*)alloc((size_t)8192 * G4_ * 2);       // 67.1MB
    float*          hbuf   = (float*)alloc((size_t)N_ * H_ * 4);
    float*          cbuf   = (float*)alloc((size_t)N_ * H_ * 4);
    unsigned short* hP0    = (unsigned short*)alloc((size_t)8 * 32 * 512 * 2);
    unsigned short* hP1    = (unsigned short*)alloc((size_t)8 * 32 * 512 * 2);
    float*          part0  = (float*)alloc((size_t)N_ * 16 * 64 * 4);
    float*          part1  = (float*)alloc((size_t)N_ * 16 * 64 * 4);
    float*          wbuf   = (float*)alloc((size_t)N_ * 16 * 4);

    // prep
    k_pack_w<<<dim3(128, 16), dim3(256), 0, stream>>>(Wx,    WxP,    0, 32);
    k_pack_w<<<dim3(128, 16), dim3(256), 0, stream>>>(Wh,    WhP,    0, 32);
    k_pack_w<<<dim3(128, 16), dim3(256), 0, stream>>>(Wattn, WattnP, 0, 32);
    k_pack_x2<<<dim3(4096), dim3(256), 0, stream>>>(x, xP);
    k_pack_af<<<dim3(128, 16), dim3(256), 0, stream>>>(A, AfP, Af2);
    k_h0<<<dim3(512), dim3(256), 0, stream>>>(A, hbuf, cbuf, hP0);
    k_part0<<<dim3(N_), dim3(512), 0, stream>>>(hbuf, Af2, part0);
    k_aw<<<dim3(16, 32), dim3(256), 0, stream>>>(AfP, WattnP, AW);
    k_actx<<<dim3(64, 32), dim3(256), 0, stream>>>(xP, WxP, actx);

    // recurrence
    for (int t = 0; t < T_; t++) {
        unsigned short* hin  = (t & 1) ? hP1 : hP0;
        unsigned short* hout = (t & 1) ? hP0 : hP1;
        float* pIN  = (t & 1) ? part1 : part0;
        float* pOUT = (t & 1) ? part0 : part1;
        k_score_tiny<<<dim3(N_), dim3(64), 0, stream>>>(pIN, wbuf);
        k_step<<<dim3(64, 4), dim3(512), 0, stream>>>(actx, hin, hout, WhP, AW, Af2,
                                                      wbuf, b, cbuf, pOUT, out, t);
    }
}

// Round 19
// 1079.344 us; speedup vs baseline: 1.1132x; 1.0049x over previous
//
#include <hip/hip_runtime.h>
#include <hip/hip_bf16.h>
#include <cmath>

// Problem constants
#define N_   128
#define T_   64
#define D_   1024
#define H_   1024
#define G4_  4096   // 4*H

typedef short bf16x8 __attribute__((ext_vector_type(8)));
typedef float f32x4  __attribute__((ext_vector_type(4)));

__device__ __forceinline__ unsigned short f2bf(float f) {
    union { float f; unsigned int u; } v; v.f = f;
    unsigned int r = (v.u + 0x7FFFu + ((v.u >> 16) & 1u)) >> 16;  // RNE
    return (unsigned short)r;
}
__device__ __forceinline__ float bf2f(unsigned short s) {
    union { unsigned int u; float f; } v; v.u = ((unsigned int)s) << 16;
    return v.f;
}

// Fragment-packed layout (mfma_f32_16x16x32_bf16, lane = kg*16+cl):
//   P[tile][kc][lane][8] bf16 ; wave fragment load = base + lane*8 -> 1KB contiguous.
// Epilogue-fused layouts:
//   AW2  [n][1024 jh][4 g][16 p] bf16  (128B contiguous per (n,jh))
//   actx2[m][1024 jh][4 g]      bf16  (8B per (m,jh))
//   bvec4[1024 jh][4 g]         f32   (16B per jh)

// ---------------------------------------------------------------- prep ----

// pack weight src f32 [1024][4096] (k-major) -> fragment-packed B (rows = j).
__global__ void k_pack_w(const float* __restrict__ src, unsigned short* __restrict__ dst,
                         int kcoff, int kctot) {
    __shared__ float ld[64][33];
    int j0 = blockIdx.x * 32, k0 = blockIdx.y * 64;
    int tid = threadIdx.x;
    int c = tid & 31, r = tid >> 5;           // 32 j x 8 k
    #pragma unroll
    for (int i = 0; i < 8; i++)
        ld[r + i * 8][c] = src[(long)(k0 + r + i * 8) * G4_ + j0 + c];
    __syncthreads();
    int j = tid & 31, ku = tid >> 5;          // 32 j x 8 k-units of 8
    int kcl = ku >> 2, kg = ku & 3;
    int jti = (j0 + j) >> 4, cl = (j0 + j) & 15;
    int kc = kcoff + (k0 >> 5) + kcl;
    unsigned short q[8];
    #pragma unroll
    for (int e = 0; e < 8; e++) q[e] = f2bf(ld[ku * 8 + e][j]);
    *(uint4*)(dst + ((long)(jti * kctot + kc) * 64 + kg * 16 + cl) * 8) = *(uint4*)q;
}

// pack x f32 [N][T][D] -> xP tiles over m: tile = t*8 + (n>>4), rows = n&15.
__global__ void k_pack_x2(const float* __restrict__ x, unsigned short* __restrict__ xP) {
    long gid = (long)blockIdx.x * 256 + threadIdx.x;   // 8192*128
    int m = (int)(gid >> 7), u = (int)(gid & 127);
    const float* src = x + (long)m * 1024 + u * 8;
    int n = m >> 6, t = m & 63;
    int tile = t * 8 + (n >> 4);
    int kc = u >> 2, kg = u & 3, cl = n & 15;
    float4 a = *(const float4*)src, b = *(const float4*)(src + 4);
    unsigned short q[8] = {f2bf(a.x), f2bf(a.y), f2bf(a.z), f2bf(a.w),
                           f2bf(b.x), f2bf(b.y), f2bf(b.z), f2bf(b.w)};
    *(uint4*)(xP + ((long)(tile * 32 + kc) * 64 + kg * 16 + cl) * 8) = *(uint4*)q;
}

// A f32 [N][H][16] -> AfP (A-operand tiles: tile=n, row=p, k=h) + Af2 bf16 copy.
__global__ void k_pack_af(const float* __restrict__ A, unsigned short* __restrict__ AfP,
                          unsigned short* __restrict__ Af2) {
    __shared__ float ld[64][17];
    int n = blockIdx.x, h0 = blockIdx.y * 64;
    int tid = threadIdx.x;
    int hh = tid >> 2, pq = tid & 3;
    float4 v = *(const float4*)(A + ((long)n * H_ + h0 + hh) * 16 + pq * 4);
    unsigned short o[4] = {f2bf(v.x), f2bf(v.y), f2bf(v.z), f2bf(v.w)};
    *(uint2*)(Af2 + ((long)n * H_ + h0 + hh) * 16 + pq * 4) = *(uint2*)o;
    ld[hh][pq * 4 + 0] = v.x; ld[hh][pq * 4 + 1] = v.y;
    ld[hh][pq * 4 + 2] = v.z; ld[hh][pq * 4 + 3] = v.w;
    __syncthreads();
    if (tid < 128) {
        int p = tid >> 3, ku = tid & 7;
        int kc = (h0 >> 5) + (ku >> 2), kg = ku & 3;
        unsigned short q[8];
        #pragma unroll
        for (int e = 0; e < 8; e++) q[e] = f2bf(ld[ku * 8 + e][p]);
        *(uint4*)(AfP + ((long)(n * 32 + kc) * 64 + kg * 16 + p) * 8) = *(uint4*)q;
    }
}

// h0 = mean_p A; c0 = h0; packed h0.
__global__ void k_h0(const float* __restrict__ A, float* __restrict__ h,
                     float* __restrict__ c, unsigned short* __restrict__ hP0) {
    long id = (long)blockIdx.x * 256 + threadIdx.x;
    const float4* ap = (const float4*)(A + id * 16);
    float s = 0.f;
    #pragma unroll
    for (int q = 0; q < 4; q++) { float4 v = ap[q]; s += v.x + v.y + v.z + v.w; }
    float m = s * (1.0f / 16.0f);
    h[id] = m; c[id] = m;
    int n = (int)(id >> 10), j = (int)(id & 1023);
    hP0[((long)((n >> 4) * 32 + (j >> 5)) * 64 + ((j >> 3) & 3) * 16 + (n & 15)) * 8 + (j & 7)] = f2bf(m);
}

// bvec4[jh*4 + g] = b[g*1024 + jh]
__global__ void k_b4(const float* __restrict__ b, float* __restrict__ b4) {
    int i = blockIdx.x * 256 + threadIdx.x;  // 0..4095
    int g = i & 3, jh = i >> 2;
    b4[i] = b[g * 1024 + jh];
}

// t=0 score partials ([n][16][64] layout, R13-proven)
__global__ __launch_bounds__(512)
void k_part0(const float* __restrict__ hbuf, const unsigned short* __restrict__ Af2,
             float* __restrict__ partial0) {
    int n = blockIdx.x;
    int tid = threadIdx.x;
    int jh = tid * 2;
    float sp[16];
    #pragma unroll
    for (int p = 0; p < 16; p++) sp[p] = 0.f;
    #pragma unroll
    for (int u = 0; u < 2; u++) {
        float hv = hbuf[(long)n * H_ + jh + u];
        const unsigned short* afp = Af2 + ((long)n * H_ + jh + u) * 16;
        bf16x8 a0 = *(const bf16x8*)(afp);
        bf16x8 a1 = *(const bf16x8*)(afp + 8);
        #pragma unroll
        for (int p = 0; p < 8; p++) { sp[p] += hv * bf2f((unsigned short)a0[p]);
                                      sp[8+p] += hv * bf2f((unsigned short)a1[p]); }
    }
    #pragma unroll
    for (int off = 1; off < 8; off <<= 1) {
        #pragma unroll
        for (int p = 0; p < 16; p++) sp[p] += __shfl_xor(sp[p], off);
    }
    int jt = tid >> 3;
    if ((tid & 7) == 0) {
        #pragma unroll
        for (int p = 0; p < 16; p++)
            partial0[((long)n * 16 + p) * 64 + jt] = sp[p];
    }
}

// reduce partial -> softmax -> w  (R13-proven)
__global__ __launch_bounds__(64)
void k_score_tiny(const float* __restrict__ partial, float* __restrict__ wbuf) {
    int n = blockIdx.x;
    int lane = threadIdx.x;
    int p = lane & 15, c4 = lane >> 4;
    const float* src = partial + ((long)n * 16 + p) * 64 + c4 * 16;
    float s = 0.f;
    #pragma unroll
    for (int q = 0; q < 16; q++) s += src[q];
    s += __shfl_xor(s, 16);
    s += __shfl_xor(s, 32);
    s *= (1.0f / 32.0f);
    float m = s;
    #pragma unroll
    for (int off = 1; off < 16; off <<= 1) m = fmaxf(m, __shfl_xor(m, off));
    float e = expf(s - m);
    float sum = e;
    #pragma unroll
    for (int off = 1; off < 16; off <<= 1) sum += __shfl_xor(sum, off);
    if (c4 == 0) wbuf[n * 16 + p] = e / sum;
}

// AW2 = AfP @ WattnP^T, output layout [n][jh][4g][16p].
__global__ __launch_bounds__(256, 2)
void k_aw(const unsigned short* __restrict__ AfP, const unsigned short* __restrict__ WattnP,
          unsigned short* __restrict__ AW2) {
    int tid = threadIdx.x;
    int wv = tid >> 6, lane = tid & 63;
    int wr = wv >> 1, wc = wv & 1;
    int cl = lane & 15, kg = lane >> 4;
    int at0 = blockIdx.x * 8 + wr * 4;
    int jt0 = blockIdx.y * 8 + wc * 4;

    f32x4 acc[4][4];
    #pragma unroll
    for (int i = 0; i < 4; i++)
        #pragma unroll
        for (int j = 0; j < 4; j++) acc[i][j] = (f32x4){0.f, 0.f, 0.f, 0.f};

    const unsigned short* apx[4];
    const unsigned short* bpx[4];
    #pragma unroll
    for (int i = 0; i < 4; i++) {
        apx[i] = AfP    + (long)(at0 + i) * (32 * 512) + lane * 8;
        bpx[i] = WattnP + (long)(jt0 + i) * (32 * 512) + lane * 8;
    }
    #pragma unroll 2
    for (int kc = 0; kc < 32; kc++) {
        bf16x8 a[4], b[4];
        #pragma unroll
        for (int i = 0; i < 4; i++) a[i] = *(const bf16x8*)(apx[i] + kc * 512);
        #pragma unroll
        for (int i = 0; i < 4; i++) b[i] = *(const bf16x8*)(bpx[i] + kc * 512);
        #pragma unroll
        for (int i = 0; i < 4; i++)
            #pragma unroll
            for (int j = 0; j < 4; j++)
                acc[i][j] = __builtin_amdgcn_mfma_f32_16x16x32_bf16(a[i], b[j], acc[i][j], 0, 0, 0);
    }
    #pragma unroll
    for (int i = 0; i < 4; i++) {
        int n = at0 + i;
        #pragma unroll
        for (int j = 0; j < 4; j++) {
            int jj = (jt0 + j) * 16 + cl;
            int g = jj >> 10, jh = jj & 1023;
            #pragma unroll
            for (int v = 0; v < 4; v++) {
                int p = kg * 4 + v;
                AW2[(((long)n * 1024 + jh) * 4 + g) * 16 + p] = f2bf(acc[i][j][v]);
            }
        }
    }
}

// actx2 = xP @ WxP^T, output layout [m][jh][4g] bf16.
__global__ __launch_bounds__(256, 2)
void k_actx(const unsigned short* __restrict__ xP, const unsigned short* __restrict__ WxP,
            unsigned short* __restrict__ actx2) {
    int tid = threadIdx.x;
    int wv = tid >> 6, lane = tid & 63;
    int wr = wv >> 1, wc = wv & 1;
    int cl = lane & 15, kg = lane >> 4;
    int at0 = blockIdx.x * 8 + wr * 4;    // A tiles (0..511)
    int jt0 = blockIdx.y * 8 + wc * 4;    // B tiles (0..255)

    f32x4 acc[4][4];
    #pragma unroll
    for (int i = 0; i < 4; i++)
        #pragma unroll
        for (int j = 0; j < 4; j++) acc[i][j] = (f32x4){0.f, 0.f, 0.f, 0.f};

    const unsigned short* apx[4];
    const unsigned short* bpx[4];
    #pragma unroll
    for (int i = 0; i < 4; i++) {
        apx[i] = xP  + (long)(at0 + i) * (32 * 512) + lane * 8;
        bpx[i] = WxP + (long)(jt0 + i) * (32 * 512) + lane * 8;
    }
    #pragma unroll 2
    for (int kc = 0; kc < 32; kc++) {
        bf16x8 a[4], b[4];
        #pragma unroll
        for (int i = 0; i < 4; i++) a[i] = *(const bf16x8*)(apx[i] + kc * 512);
        #pragma unroll
        for (int i = 0; i < 4; i++) b[i] = *(const bf16x8*)(bpx[i] + kc * 512);
        #pragma unroll
        for (int i = 0; i < 4; i++)
            #pragma unroll
            for (int j = 0; j < 4; j++)
                acc[i][j] = __builtin_amdgcn_mfma_f32_16x16x32_bf16(a[i], b[j], acc[i][j], 0, 0, 0);
    }
    #pragma unroll
    for (int i = 0; i < 4; i++) {
        long mrow = (long)(at0 + i) * 16;
        #pragma unroll
        for (int j = 0; j < 4; j++) {
            int jj = (jt0 + j) * 16 + cl;
            int g = jj >> 10, jh = jj & 1023;
            #pragma unroll
            for (int v = 0; v < 4; v++)
                actx2[((mrow + kg * 4 + v) * 1024 + jh) * 4 + g] = f2bf(acc[i][j][v]);
        }
    }
}

// ------------------------------------------------------------- per step ----

// k_step: R13 GEMM body + vectorized-load epilogue (wbuf float4, bvec4,
// actx2 uint2, AW2 single 128B base). grid (64 jt, 4 nt2), 512 thr.
__global__ __launch_bounds__(512, 2)
void k_step(const unsigned short* __restrict__ actx2,  // bf16 [8192][1024][4]
            const unsigned short* __restrict__ hPin,   // packed [8 nt][32 kc][64][8]
            unsigned short* __restrict__ hPout,
            const unsigned short* __restrict__ WhP,    // [256 jti][32 kc][64][8]
            const unsigned short* __restrict__ AW2,    // [N][1024][4][16]
            const unsigned short* __restrict__ Af2,    // [N][H][16]
            const float* __restrict__ wbuf,            // [N][16]
            const float* __restrict__ bvec4,           // [1024][4]
            float* __restrict__ c,
            float* __restrict__ partOUT,               // [N][16][64]
            float* __restrict__ out, int t) {
    int tid = threadIdx.x;
    int wv = tid >> 6, lane = tid & 63;
    int ks = wv & 3, rh = wv >> 2;
    int cl = lane & 15, kg = lane >> 4;
    int jt = blockIdx.x;
    int nt2 = blockIdx.y;
    int colbase = jt * 16;

    __shared__ float red[3][2][64][17];
    __shared__ float act[4][32][17];

    // ---- GEMM: 16 rows (rh half) x 16 jh x 4 gates over K=256 (8 kc) ----
    f32x4 acc[4];
    #pragma unroll
    for (int g = 0; g < 4; g++) acc[g] = (f32x4){0.f, 0.f, 0.f, 0.f};

    const unsigned short* abase = hPin + ((long)(nt2 * 2 + rh) * 32 + ks * 8) * 512 + lane * 8;
    const unsigned short* bb[4];
    #pragma unroll
    for (int g = 0; g < 4; g++)
        bb[g] = WhP + ((long)(g * 64 + jt) * 32 + ks * 8) * 512 + lane * 8;

    #pragma unroll
    for (int i = 0; i < 8; i++) {
        bf16x8 a = *(const bf16x8*)(abase + i * 512);
        #pragma unroll
        for (int g = 0; g < 4; g++) {
            bf16x8 b = *(const bf16x8*)(bb[g] + i * 512);
            acc[g] = __builtin_amdgcn_mfma_f32_16x16x32_bf16(a, b, acc[g], 0, 0, 0);
        }
    }

    // ---- 4-way K reduce per rh ----
    if (ks != 0) {
        #pragma unroll
        for (int g = 0; g < 4; g++)
            #pragma unroll
            for (int v = 0; v < 4; v++) red[ks - 1][rh][lane][g * 4 + v] = acc[g][v];
    }
    __syncthreads();
    if (ks == 0) {
        #pragma unroll
        for (int g = 0; g < 4; g++)
            #pragma unroll
            for (int v = 0; v < 4; v++) {
                float s = acc[g][v] + red[0][rh][lane][g*4+v] + red[1][rh][lane][g*4+v]
                        + red[2][rh][lane][g*4+v];
                act[g][rh * 16 + kg * 4 + v][cl] = s;   // C/D row = 4*kg + v
            }
    }
    __syncthreads();

    // ---- epilogue: 512 thr x 1 (n, jh) cell, vectorized loads ----
    int nloc = tid >> 4, jl = tid & 15;
    int n = nt2 * 32 + nloc, jh = colbase + jl;
    float wv16[16];
    const float4* wsrc = (const float4*)(wbuf + n * 16);
    #pragma unroll
    for (int q = 0; q < 4; q++) {
        float4 v = wsrc[q];
        wv16[q*4+0] = v.x; wv16[q*4+1] = v.y; wv16[q*4+2] = v.z; wv16[q*4+3] = v.w;
    }

    long rm = (long)(t * 8 + (n >> 4)) * 16 + (n & 15);   // actx row
    const unsigned short* awp = AW2 + (((long)n * 1024 + jh) << 6);  // 64 bf16 = 128B
    bf16x8 aw[8];
    #pragma unroll
    for (int q = 0; q < 8; q++) aw[q] = *(const bf16x8*)(awp + q * 8);
    float4 b4 = *(const float4*)(bvec4 + jh * 4);
    uint2 axu = *(const uint2*)(actx2 + ((rm * 1024 + jh) << 2));
    unsigned short ax[4] = {(unsigned short)(axu.x & 0xffff), (unsigned short)(axu.x >> 16),
                            (unsigned short)(axu.y & 0xffff), (unsigned short)(axu.y >> 16)};
    float barr[4] = {b4.x, b4.y, b4.z, b4.w};

    float s4[4];
    #pragma unroll
    for (int g = 0; g < 4; g++) {
        float at = 0.f;
        #pragma unroll
        for (int p = 0; p < 8; p++) at += wv16[p]     * bf2f((unsigned short)aw[2*g][p]);
        #pragma unroll
        for (int p = 0; p < 8; p++) at += wv16[8 + p] * bf2f((unsigned short)aw[2*g+1][p]);
        s4[g] = act[g][nloc][jl] + bf2f(ax[g]) + at + barr[g];
    }
    float ig = 1.f / (1.f + expf(-s4[0]));
    float fg = 1.f / (1.f + expf(-s4[1]));
    float og = 1.f / (1.f + expf(-s4[2]));
    float gg = tanhf(s4[3]);
    long idx = (long)n * H_ + jh;
    float cn = fg * c[idx] + ig * gg;
    float hn = og * tanhf(cn);
    c[idx] = cn;
    out[((long)n * T_ + t) * H_ + jh] = hn;
    hPout[((long)((n >> 4) * 32 + (jh >> 5)) * 64 + ((jh >> 3) & 3) * 16 + (n & 15)) * 8 + (jh & 7)] = f2bf(hn);

    // score partials for t+1 (R13 path)
    const unsigned short* afp = Af2 + ((long)n * H_ + jh) * 16;
    bf16x8 af0 = *(const bf16x8*)(afp);
    bf16x8 af1 = *(const bf16x8*)(afp + 8);
    float sp[16];
    #pragma unroll
    for (int p = 0; p < 8; p++) { sp[p]     = hn * bf2f((unsigned short)af0[p]);
                                  sp[8 + p] = hn * bf2f((unsigned short)af1[p]); }
    #pragma unroll
    for (int off = 1; off < 16; off <<= 1) {
        #pragma unroll
        for (int p = 0; p < 16; p++) sp[p] += __shfl_xor(sp[p], off);
    }
    float outv = 0.f;
    #pragma unroll
    for (int p = 0; p < 16; p++) if (jl == p) outv = sp[p];
    partOUT[((long)n * 16 + jl) * 64 + jt] = outv;
}

// ---------------------------------------------------------------- launch ----

extern "C" void kernel_launch(void* const* d_in, const int* in_sizes, int n_in,
                              void* d_out, int out_size, void* d_ws, size_t ws_size,
                              hipStream_t stream) {
    const float* x     = (const float*)d_in[0];
    const float* A     = (const float*)d_in[1];
    const float* Wx    = (const float*)d_in[2];
    const float* Wh    = (const float*)d_in[3];
    const float* Wattn = (const float*)d_in[4];
    const float* b     = (const float*)d_in[5];
    float* out = (float*)d_out;

    char* ws = (char*)d_ws;
    size_t off = 0;
    auto alloc = [&](size_t bytes) -> void* {
        void* p = ws + off;
        off += (bytes + 255) & ~(size_t)255;
        return p;
    };
    unsigned short* xP     = (unsigned short*)alloc((size_t)512 * 32 * 512 * 2);   // 16.8MB
    unsigned short* WxP    = (unsigned short*)alloc((size_t)256 * 32 * 512 * 2);   // 8.4MB
    unsigned short* WhP    = (unsigned short*)alloc((size_t)256 * 32 * 512 * 2);   // 8.4MB
    unsigned short* WattnP = (unsigned short*)alloc((size_t)256 * 32 * 512 * 2);   // 8.4MB
    unsigned short* AfP    = (unsigned short*)alloc((size_t)128 * 32 * 512 * 2);   // 4.2MB
    unsigned short* Af2    = (unsigned short*)alloc((size_t)N_ * H_ * 16 * 2);     // 4.2MB
    unsigned short* AW2    = (unsigned short*)alloc((size_t)N_ * G4_ * 16 * 2);    // 16.8MB
    unsigned short* actx2  = (unsigned short*)alloc((size_t)8192 * G4_ * 2);       // 67.1MB
    float*          hbuf   = (float*)alloc((size_t)N_ * H_ * 4);
    float*          cbuf   = (float*)alloc((size_t)N_ * H_ * 4);
    unsigned short* hP0    = (unsigned short*)alloc((size_t)8 * 32 * 512 * 2);
    unsigned short* hP1    = (unsigned short*)alloc((size_t)8 * 32 * 512 * 2);
    float*          part0  = (float*)alloc((size_t)N_ * 16 * 64 * 4);
    float*          part1  = (float*)alloc((size_t)N_ * 16 * 64 * 4);
    float*          wbuf   = (float*)alloc((size_t)N_ * 16 * 4);
    float*          bvec4  = (float*)alloc((size_t)G4_ * 4);

    // prep
    k_pack_w<<<dim3(128, 16), dim3(256), 0, stream>>>(Wx,    WxP,    0, 32);
    k_pack_w<<<dim3(128, 16), dim3(256), 0, stream>>>(Wh,    WhP,    0, 32);
    k_pack_w<<<dim3(128, 16), dim3(256), 0, stream>>>(Wattn, WattnP, 0, 32);
    k_pack_x2<<<dim3(4096), dim3(256), 0, stream>>>(x, xP);
    k_pack_af<<<dim3(128, 16), dim3(256), 0, stream>>>(A, AfP, Af2);
    k_h0<<<dim3(512), dim3(256), 0, stream>>>(A, hbuf, cbuf, hP0);
    k_b4<<<dim3(16), dim3(256), 0, stream>>>(b, bvec4);
    k_part0<<<dim3(N_), dim3(512), 0, stream>>>(hbuf, Af2, part0);
    k_aw<<<dim3(16, 32), dim3(256), 0, stream>>>(AfP, WattnP, AW2);
    k_actx<<<dim3(64, 32), dim3(256), 0, stream>>>(xP, WxP, actx2);

    // recurrence
    for (int t = 0; t < T_; t++) {
        unsigned short* hin  = (t & 1) ? hP1 : hP0;
        unsigned short* hout = (t & 1) ? hP0 : hP1;
        float* pIN  = (t & 1) ? part1 : part0;
        float* pOUT = (t & 1) ? part0 : part1;
        k_score_tiny<<<dim3(N_), dim3(64), 0, stream>>>(pIN, wbuf);
        k_step<<<dim3(64, 4), dim3(512), 0, stream>>>(actx2, hin, hout, WhP, AW2, Af2,
                                                      wbuf, bvec4, cbuf, pOUT, out, t);
    }
}

// Round 20
// 1076.591 us; speedup vs baseline: 1.1160x; 1.0026x over previous
//
#include <hip/hip_runtime.h>
#include <hip/hip_bf16.h>
#include <cmath>

// Problem constants
#define N_   128
#define T_   64
#define D_   1024
#define H_   1024
#define G4_  4096   // 4*H

typedef short bf16x8 __attribute__((ext_vector_type(8)));
typedef float f32x4  __attribute__((ext_vector_type(4)));

__device__ __forceinline__ unsigned short f2bf(float f) {
    union { float f; unsigned int u; } v; v.f = f;
    unsigned int r = (v.u + 0x7FFFu + ((v.u >> 16) & 1u)) >> 16;  // RNE
    return (unsigned short)r;
}
__device__ __forceinline__ float bf2f(unsigned short s) {
    union { unsigned int u; float f; } v; v.u = ((unsigned int)s) << 16;
    return v.f;
}

// Fragment-packed layout (mfma_f32_16x16x32_bf16, lane = kg*16+cl):
//   P[tile][kc][lane][8] bf16 ; wave fragment load = base + lane*8 -> 1KB contiguous.
// Epilogue-fused layouts (gate-from-one-wave producers -> dense stores):
//   AW2  [n][1024 jh][16 p][4 g] bf16  (128B contiguous read per (n,jh))
//   actx2[m][1024 jh][4 g]       bf16  (8B read per (m,jh))
//   bvec4[1024 jh][4 g]          f32   (16B per jh)

// ---------------------------------------------------------------- prep ----

// pack weight src f32 [1024][4096] (k-major) -> fragment-packed B (rows = j).
__global__ void k_pack_w(const float* __restrict__ src, unsigned short* __restrict__ dst,
                         int kcoff, int kctot) {
    __shared__ float ld[64][33];
    int j0 = blockIdx.x * 32, k0 = blockIdx.y * 64;
    int tid = threadIdx.x;
    int c = tid & 31, r = tid >> 5;           // 32 j x 8 k
    #pragma unroll
    for (int i = 0; i < 8; i++)
        ld[r + i * 8][c] = src[(long)(k0 + r + i * 8) * G4_ + j0 + c];
    __syncthreads();
    int j = tid & 31, ku = tid >> 5;          // 32 j x 8 k-units of 8
    int kcl = ku >> 2, kg = ku & 3;
    int jti = (j0 + j) >> 4, cl = (j0 + j) & 15;
    int kc = kcoff + (k0 >> 5) + kcl;
    unsigned short q[8];
    #pragma unroll
    for (int e = 0; e < 8; e++) q[e] = f2bf(ld[ku * 8 + e][j]);
    *(uint4*)(dst + ((long)(jti * kctot + kc) * 64 + kg * 16 + cl) * 8) = *(uint4*)q;
}

// pack x f32 [N][T][D] -> xP tiles over m: tile = t*8 + (n>>4), rows = n&15.
__global__ void k_pack_x2(const float* __restrict__ x, unsigned short* __restrict__ xP) {
    long gid = (long)blockIdx.x * 256 + threadIdx.x;   // 8192*128
    int m = (int)(gid >> 7), u = (int)(gid & 127);
    const float* src = x + (long)m * 1024 + u * 8;
    int n = m >> 6, t = m & 63;
    int tile = t * 8 + (n >> 4);
    int kc = u >> 2, kg = u & 3, cl = n & 15;
    float4 a = *(const float4*)src, b = *(const float4*)(src + 4);
    unsigned short q[8] = {f2bf(a.x), f2bf(a.y), f2bf(a.z), f2bf(a.w),
                           f2bf(b.x), f2bf(b.y), f2bf(b.z), f2bf(b.w)};
    *(uint4*)(xP + ((long)(tile * 32 + kc) * 64 + kg * 16 + cl) * 8) = *(uint4*)q;
}

// A f32 [N][H][16] -> AfP (A-operand tiles: tile=n, row=p, k=h) + Af2 bf16 copy.
__global__ void k_pack_af(const float* __restrict__ A, unsigned short* __restrict__ AfP,
                          unsigned short* __restrict__ Af2) {
    __shared__ float ld[64][17];
    int n = blockIdx.x, h0 = blockIdx.y * 64;
    int tid = threadIdx.x;
    int hh = tid >> 2, pq = tid & 3;
    float4 v = *(const float4*)(A + ((long)n * H_ + h0 + hh) * 16 + pq * 4);
    unsigned short o[4] = {f2bf(v.x), f2bf(v.y), f2bf(v.z), f2bf(v.w)};
    *(uint2*)(Af2 + ((long)n * H_ + h0 + hh) * 16 + pq * 4) = *(uint2*)o;
    ld[hh][pq * 4 + 0] = v.x; ld[hh][pq * 4 + 1] = v.y;
    ld[hh][pq * 4 + 2] = v.z; ld[hh][pq * 4 + 3] = v.w;
    __syncthreads();
    if (tid < 128) {
        int p = tid >> 3, ku = tid & 7;
        int kc = (h0 >> 5) + (ku >> 2), kg = ku & 3;
        unsigned short q[8];
        #pragma unroll
        for (int e = 0; e < 8; e++) q[e] = f2bf(ld[ku * 8 + e][p]);
        *(uint4*)(AfP + ((long)(n * 32 + kc) * 64 + kg * 16 + p) * 8) = *(uint4*)q;
    }
}

// h0 = mean_p A; c0 = h0; packed h0.
__global__ void k_h0(const float* __restrict__ A, float* __restrict__ h,
                     float* __restrict__ c, unsigned short* __restrict__ hP0) {
    long id = (long)blockIdx.x * 256 + threadIdx.x;
    const float4* ap = (const float4*)(A + id * 16);
    float s = 0.f;
    #pragma unroll
    for (int q = 0; q < 4; q++) { float4 v = ap[q]; s += v.x + v.y + v.z + v.w; }
    float m = s * (1.0f / 16.0f);
    h[id] = m; c[id] = m;
    int n = (int)(id >> 10), j = (int)(id & 1023);
    hP0[((long)((n >> 4) * 32 + (j >> 5)) * 64 + ((j >> 3) & 3) * 16 + (n & 15)) * 8 + (j & 7)] = f2bf(m);
}

// bvec4[jh*4 + g] = b[g*1024 + jh]
__global__ void k_b4(const float* __restrict__ b, float* __restrict__ b4) {
    int i = blockIdx.x * 256 + threadIdx.x;  // 0..4095
    int g = i & 3, jh = i >> 2;
    b4[i] = b[g * 1024 + jh];
}

// t=0 score partials ([n][16][64] layout, R13-proven)
__global__ __launch_bounds__(512)
void k_part0(const float* __restrict__ hbuf, const unsigned short* __restrict__ Af2,
             float* __restrict__ partial0) {
    int n = blockIdx.x;
    int tid = threadIdx.x;
    int jh = tid * 2;
    float sp[16];
    #pragma unroll
    for (int p = 0; p < 16; p++) sp[p] = 0.f;
    #pragma unroll
    for (int u = 0; u < 2; u++) {
        float hv = hbuf[(long)n * H_ + jh + u];
        const unsigned short* afp = Af2 + ((long)n * H_ + jh + u) * 16;
        bf16x8 a0 = *(const bf16x8*)(afp);
        bf16x8 a1 = *(const bf16x8*)(afp + 8);
        #pragma unroll
        for (int p = 0; p < 8; p++) { sp[p] += hv * bf2f((unsigned short)a0[p]);
                                      sp[8+p] += hv * bf2f((unsigned short)a1[p]); }
    }
    #pragma unroll
    for (int off = 1; off < 8; off <<= 1) {
        #pragma unroll
        for (int p = 0; p < 16; p++) sp[p] += __shfl_xor(sp[p], off);
    }
    int jt = tid >> 3;
    if ((tid & 7) == 0) {
        #pragma unroll
        for (int p = 0; p < 16; p++)
            partial0[((long)n * 16 + p) * 64 + jt] = sp[p];
    }
}

// reduce partial -> softmax -> w  (R13-proven)
__global__ __launch_bounds__(64)
void k_score_tiny(const float* __restrict__ partial, float* __restrict__ wbuf) {
    int n = blockIdx.x;
    int lane = threadIdx.x;
    int p = lane & 15, c4 = lane >> 4;
    const float* src = partial + ((long)n * 16 + p) * 64 + c4 * 16;
    float s = 0.f;
    #pragma unroll
    for (int q = 0; q < 16; q++) s += src[q];
    s += __shfl_xor(s, 16);
    s += __shfl_xor(s, 32);
    s *= (1.0f / 32.0f);
    float m = s;
    #pragma unroll
    for (int off = 1; off < 16; off <<= 1) m = fmaxf(m, __shfl_xor(m, off));
    float e = expf(s - m);
    float sum = e;
    #pragma unroll
    for (int off = 1; off < 16; off <<= 1) sum += __shfl_xor(sum, off);
    if (c4 == 0) wbuf[n * 16 + p] = e / sum;
}

// AW2 = AfP @ WattnP^T. Wave handles 4 GATES of one jh-column set:
// B-tiles = {jb, jb+64, jb+128, jb+192}. Output [n][jh][16p][4g]:
// thread packs 4 gates per v -> uint2; 4 uint2 (32B contiguous) per (i).
__global__ __launch_bounds__(256, 2)
void k_aw(const unsigned short* __restrict__ AfP, const unsigned short* __restrict__ WattnP,
          unsigned short* __restrict__ AW2) {
    int tid = threadIdx.x;
    int wv = tid >> 6, lane = tid & 63;
    int wr = wv >> 1, wc = wv & 1;
    int cl = lane & 15, kg = lane >> 4;
    int at0 = blockIdx.x * 8 + wr * 4;   // n-tiles 0..127 (grid.x = 16)
    int jb  = blockIdx.y * 2 + wc;       // jh-tile 0..63  (grid.y = 32)

    f32x4 acc[4][4];
    #pragma unroll
    for (int i = 0; i < 4; i++)
        #pragma unroll
        for (int g = 0; g < 4; g++) acc[i][g] = (f32x4){0.f, 0.f, 0.f, 0.f};

    const unsigned short* apx[4];
    const unsigned short* bpx[4];
    #pragma unroll
    for (int i = 0; i < 4; i++)
        apx[i] = AfP + (long)(at0 + i) * (32 * 512) + lane * 8;
    #pragma unroll
    for (int g = 0; g < 4; g++)
        bpx[g] = WattnP + (long)(jb + g * 64) * (32 * 512) + lane * 8;
    #pragma unroll 2
    for (int kc = 0; kc < 32; kc++) {
        bf16x8 a[4], b[4];
        #pragma unroll
        for (int i = 0; i < 4; i++) a[i] = *(const bf16x8*)(apx[i] + kc * 512);
        #pragma unroll
        for (int g = 0; g < 4; g++) b[g] = *(const bf16x8*)(bpx[g] + kc * 512);
        #pragma unroll
        for (int i = 0; i < 4; i++)
            #pragma unroll
            for (int g = 0; g < 4; g++)
                acc[i][g] = __builtin_amdgcn_mfma_f32_16x16x32_bf16(a[i], b[g], acc[i][g], 0, 0, 0);
    }
    int jh = jb * 16 + cl;
    #pragma unroll
    for (int i = 0; i < 4; i++) {
        int n = at0 + i;
        #pragma unroll
        for (int v = 0; v < 4; v++) {
            unsigned short q4[4] = {f2bf(acc[i][0][v]), f2bf(acc[i][1][v]),
                                    f2bf(acc[i][2][v]), f2bf(acc[i][3][v])};
            *(uint2*)(AW2 + (((long)n * 1024 + jh) * 16 + kg * 4 + v) * 4) = *(uint2*)q4;
        }
    }
}

// actx2 = xP @ WxP^T. Same gate-grouped B-tiles; output [m][jh][4g]:
// thread packs 4 gates -> uint2; wave stores are dense 128B runs.
__global__ __launch_bounds__(256, 2)
void k_actx(const unsigned short* __restrict__ xP, const unsigned short* __restrict__ WxP,
            unsigned short* __restrict__ actx2) {
    int tid = threadIdx.x;
    int wv = tid >> 6, lane = tid & 63;
    int wr = wv >> 1, wc = wv & 1;
    int cl = lane & 15, kg = lane >> 4;
    int at0 = blockIdx.x * 8 + wr * 4;   // A tiles 0..511 (grid.x = 64)
    int jb  = blockIdx.y * 2 + wc;       // jh-tile 0..63  (grid.y = 32)

    f32x4 acc[4][4];
    #pragma unroll
    for (int i = 0; i < 4; i++)
        #pragma unroll
        for (int g = 0; g < 4; g++) acc[i][g] = (f32x4){0.f, 0.f, 0.f, 0.f};

    const unsigned short* apx[4];
    const unsigned short* bpx[4];
    #pragma unroll
    for (int i = 0; i < 4; i++)
        apx[i] = xP + (long)(at0 + i) * (32 * 512) + lane * 8;
    #pragma unroll
    for (int g = 0; g < 4; g++)
        bpx[g] = WxP + (long)(jb + g * 64) * (32 * 512) + lane * 8;
    #pragma unroll 2
    for (int kc = 0; kc < 32; kc++) {
        bf16x8 a[4], b[4];
        #pragma unroll
        for (int i = 0; i < 4; i++) a[i] = *(const bf16x8*)(apx[i] + kc * 512);
        #pragma unroll
        for (int g = 0; g < 4; g++) b[g] = *(const bf16x8*)(bpx[g] + kc * 512);
        #pragma unroll
        for (int i = 0; i < 4; i++)
            #pragma unroll
            for (int g = 0; g < 4; g++)
                acc[i][g] = __builtin_amdgcn_mfma_f32_16x16x32_bf16(a[i], b[g], acc[i][g], 0, 0, 0);
    }
    int jh = jb * 16 + cl;
    #pragma unroll
    for (int i = 0; i < 4; i++) {
        long mrow = (long)(at0 + i) * 16;
        #pragma unroll
        for (int v = 0; v < 4; v++) {
            unsigned short q4[4] = {f2bf(acc[i][0][v]), f2bf(acc[i][1][v]),
                                    f2bf(acc[i][2][v]), f2bf(acc[i][3][v])};
            *(uint2*)(actx2 + ((mrow + kg * 4 + v) * 1024 + jh) * 4) = *(uint2*)q4;
        }
    }
}

// ------------------------------------------------------------- per step ----

// k_step: R13 GEMM body + vectorized-load epilogue. grid (64 jt, 4 nt2), 512 thr.
__global__ __launch_bounds__(512, 2)
void k_step(const unsigned short* __restrict__ actx2,  // bf16 [8192][1024][4]
            const unsigned short* __restrict__ hPin,   // packed [8 nt][32 kc][64][8]
            unsigned short* __restrict__ hPout,
            const unsigned short* __restrict__ WhP,    // [256 jti][32 kc][64][8]
            const unsigned short* __restrict__ AW2,    // [N][1024][16][4]
            const unsigned short* __restrict__ Af2,    // [N][H][16]
            const float* __restrict__ wbuf,            // [N][16]
            const float* __restrict__ bvec4,           // [1024][4]
            float* __restrict__ c,
            float* __restrict__ partOUT,               // [N][16][64]
            float* __restrict__ out, int t) {
    int tid = threadIdx.x;
    int wv = tid >> 6, lane = tid & 63;
    int ks = wv & 3, rh = wv >> 2;
    int cl = lane & 15, kg = lane >> 4;
    int jt = blockIdx.x;
    int nt2 = blockIdx.y;
    int colbase = jt * 16;

    __shared__ float red[3][2][64][17];
    __shared__ float act[4][32][17];

    // ---- GEMM: 16 rows (rh half) x 16 jh x 4 gates over K=256 (8 kc) ----
    f32x4 acc[4];
    #pragma unroll
    for (int g = 0; g < 4; g++) acc[g] = (f32x4){0.f, 0.f, 0.f, 0.f};

    const unsigned short* abase = hPin + ((long)(nt2 * 2 + rh) * 32 + ks * 8) * 512 + lane * 8;
    const unsigned short* bb[4];
    #pragma unroll
    for (int g = 0; g < 4; g++)
        bb[g] = WhP + ((long)(g * 64 + jt) * 32 + ks * 8) * 512 + lane * 8;

    #pragma unroll
    for (int i = 0; i < 8; i++) {
        bf16x8 a = *(const bf16x8*)(abase + i * 512);
        #pragma unroll
        for (int g = 0; g < 4; g++) {
            bf16x8 b = *(const bf16x8*)(bb[g] + i * 512);
            acc[g] = __builtin_amdgcn_mfma_f32_16x16x32_bf16(a, b, acc[g], 0, 0, 0);
        }
    }

    // ---- 4-way K reduce per rh ----
    if (ks != 0) {
        #pragma unroll
        for (int g = 0; g < 4; g++)
            #pragma unroll
            for (int v = 0; v < 4; v++) red[ks - 1][rh][lane][g * 4 + v] = acc[g][v];
    }
    __syncthreads();
    if (ks == 0) {
        #pragma unroll
        for (int g = 0; g < 4; g++)
            #pragma unroll
            for (int v = 0; v < 4; v++) {
                float s = acc[g][v] + red[0][rh][lane][g*4+v] + red[1][rh][lane][g*4+v]
                        + red[2][rh][lane][g*4+v];
                act[g][rh * 16 + kg * 4 + v][cl] = s;   // C/D row = 4*kg + v
            }
    }
    __syncthreads();

    // ---- epilogue: 512 thr x 1 (n, jh) cell, vectorized loads ----
    int nloc = tid >> 4, jl = tid & 15;
    int n = nt2 * 32 + nloc, jh = colbase + jl;
    float wv16[16];
    const float4* wsrc = (const float4*)(wbuf + n * 16);
    #pragma unroll
    for (int q = 0; q < 4; q++) {
        float4 v = wsrc[q];
        wv16[q*4+0] = v.x; wv16[q*4+1] = v.y; wv16[q*4+2] = v.z; wv16[q*4+3] = v.w;
    }

    long rm = (long)(t * 8 + (n >> 4)) * 16 + (n & 15);   // actx row
    const unsigned short* awp = AW2 + (((long)n * 1024 + jh) << 6);  // 64 bf16 = 128B
    bf16x8 aw[8];
    #pragma unroll
    for (int q = 0; q < 8; q++) aw[q] = *(const bf16x8*)(awp + q * 8);
    float4 b4 = *(const float4*)(bvec4 + jh * 4);
    uint2 axu = *(const uint2*)(actx2 + ((rm * 1024 + jh) << 2));
    unsigned short ax[4] = {(unsigned short)(axu.x & 0xffff), (unsigned short)(axu.x >> 16),
                            (unsigned short)(axu.y & 0xffff), (unsigned short)(axu.y >> 16)};
    float barr[4] = {b4.x, b4.y, b4.z, b4.w};

    // AW2 inner layout: elem (p, g) at aw[p>>1][(p&1)*4 + g]
    float at4[4] = {0.f, 0.f, 0.f, 0.f};
    #pragma unroll
    for (int q = 0; q < 8; q++) {
        #pragma unroll
        for (int e = 0; e < 8; e++) {
            int p = q * 2 + (e >> 2), g = e & 3;
            at4[g] += wv16[p] * bf2f((unsigned short)aw[q][e]);
        }
    }
    float s4[4];
    #pragma unroll
    for (int g = 0; g < 4; g++)
        s4[g] = act[g][nloc][jl] + bf2f(ax[g]) + at4[g] + barr[g];
    float ig = 1.f / (1.f + expf(-s4[0]));
    float fg = 1.f / (1.f + expf(-s4[1]));
    float og = 1.f / (1.f + expf(-s4[2]));
    float gg = tanhf(s4[3]);
    long idx = (long)n * H_ + jh;
    float cn = fg * c[idx] + ig * gg;
    float hn = og * tanhf(cn);
    c[idx] = cn;
    out[((long)n * T_ + t) * H_ + jh] = hn;
    hPout[((long)((n >> 4) * 32 + (jh >> 5)) * 64 + ((jh >> 3) & 3) * 16 + (n & 15)) * 8 + (jh & 7)] = f2bf(hn);

    // score partials for t+1 (R13 path)
    const unsigned short* afp = Af2 + ((long)n * H_ + jh) * 16;
    bf16x8 af0 = *(const bf16x8*)(afp);
    bf16x8 af1 = *(const bf16x8*)(afp + 8);
    float sp[16];
    #pragma unroll
    for (int p = 0; p < 8; p++) { sp[p]     = hn * bf2f((unsigned short)af0[p]);
                                  sp[8 + p] = hn * bf2f((unsigned short)af1[p]); }
    #pragma unroll
    for (int off = 1; off < 16; off <<= 1) {
        #pragma unroll
        for (int p = 0; p < 16; p++) sp[p] += __shfl_xor(sp[p], off);
    }
    float outv = 0.f;
    #pragma unroll
    for (int p = 0; p < 16; p++) if (jl == p) outv = sp[p];
    partOUT[((long)n * 16 + jl) * 64 + jt] = outv;
}

// ---------------------------------------------------------------- launch ----

extern "C" void kernel_launch(void* const* d_in, const int* in_sizes, int n_in,
                              void* d_out, int out_size, void* d_ws, size_t ws_size,
                              hipStream_t stream) {
    const float* x     = (const float*)d_in[0];
    const float* A     = (const float*)d_in[1];
    const float* Wx    = (const float*)d_in[2];
    const float* Wh    = (const float*)d_in[3];
    const float* Wattn = (const float*)d_in[4];
    const float* b     = (const float*)d_in[5];
    float* out = (float*)d_out;

    char* ws = (char*)d_ws;
    size_t off = 0;
    auto alloc = [&](size_t bytes) -> void* {
        void* p = ws + off;
        off += (bytes + 255) & ~(size_t)255;
        return p;
    };
    unsigned short* xP     = (unsigned short*)alloc((size_t)512 * 32 * 512 * 2);   // 16.8MB
    unsigned short* WxP    = (unsigned short*)alloc((size_t)256 * 32 * 512 * 2);   // 8.4MB
    unsigned short* WhP    = (unsigned short*)alloc((size_t)256 * 32 * 512 * 2);   // 8.4MB
    unsigned short* WattnP = (unsigned short*)alloc((size_t)256 * 32 * 512 * 2);   // 8.4MB
    unsigned short* AfP    = (unsigned short*)alloc((size_t)128 * 32 * 512 * 2);   // 4.2MB
    unsigned short* Af2    = (unsigned short*)alloc((size_t)N_ * H_ * 16 * 2);     // 4.2MB
    unsigned short* AW2    = (unsigned short*)alloc((size_t)N_ * G4_ * 16 * 2);    // 16.8MB
    unsigned short* actx2  = (unsigned short*)alloc((size_t)8192 * G4_ * 2);       // 67.1MB
    float*          hbuf   = (float*)alloc((size_t)N_ * H_ * 4);
    float*          cbuf   = (float*)alloc((size_t)N_ * H_ * 4);
    unsigned short* hP0    = (unsigned short*)alloc((size_t)8 * 32 * 512 * 2);
    unsigned short* hP1    = (unsigned short*)alloc((size_t)8 * 32 * 512 * 2);
    float*          part0  = (float*)alloc((size_t)N_ * 16 * 64 * 4);
    float*          part1  = (float*)alloc((size_t)N_ * 16 * 64 * 4);
    float*          wbuf   = (float*)alloc((size_t)N_ * 16 * 4);
    float*          bvec4  = (float*)alloc((size_t)G4_ * 4);

    // prep
    k_pack_w<<<dim3(128, 16), dim3(256), 0, stream>>>(Wx,    WxP,    0, 32);
    k_pack_w<<<dim3(128, 16), dim3(256), 0, stream>>>(Wh,    WhP,    0, 32);
    k_pack_w<<<dim3(128, 16), dim3(256), 0, stream>>>(Wattn, WattnP, 0, 32);
    k_pack_x2<<<dim3(4096), dim3(256), 0, stream>>>(x, xP);
    k_pack_af<<<dim3(128, 16), dim3(256), 0, stream>>>(A, AfP, Af2);
    k_h0<<<dim3(512), dim3(256), 0, stream>>>(A, hbuf, cbuf, hP0);
    k_b4<<<dim3(16), dim3(256), 0, stream>>>(b, bvec4);
    k_part0<<<dim3(N_), dim3(512), 0, stream>>>(hbuf, Af2, part0);
    k_aw<<<dim3(16, 32), dim3(256), 0, stream>>>(AfP, WattnP, AW2);
    k_actx<<<dim3(64, 32), dim3(256), 0, stream>>>(xP, WxP, actx2);

    // recurrence
    for (int t = 0; t < T_; t++) {
        unsigned short* hin  = (t & 1) ? hP1 : hP0;
        unsigned short* hout = (t & 1) ? hP0 : hP1;
        float* pIN  = (t & 1) ? part1 : part0;
        float* pOUT = (t & 1) ? part0 : part1;
        k_score_tiny<<<dim3(N_), dim3(64), 0, stream>>>(pIN, wbuf);
        k_step<<<dim3(64, 4), dim3(512), 0, stream>>>(actx2, hin, hout, WhP, AW2, Af2,
                                                      wbuf, bvec4, cbuf, pOUT, out, t);
    }
}

// Round 21
// 1061.150 us; speedup vs baseline: 1.1323x; 1.0146x over previous
//
#include <hip/hip_runtime.h>
#include <hip/hip_bf16.h>
#include <cmath>

// Problem constants
#define N_   128
#define T_   64
#define D_   1024
#define H_   1024
#define G4_  4096   // 4*H

typedef short bf16x8 __attribute__((ext_vector_type(8)));
typedef float f32x4  __attribute__((ext_vector_type(4)));

__device__ __forceinline__ unsigned short f2bf(float f) {
    union { float f; unsigned int u; } v; v.f = f;
    unsigned int r = (v.u + 0x7FFFu + ((v.u >> 16) & 1u)) >> 16;  // RNE
    return (unsigned short)r;
}
__device__ __forceinline__ float bf2f(unsigned short s) {
    union { unsigned int u; float f; } v; v.u = ((unsigned int)s) << 16;
    return v.f;
}

// Fragment-packed layout (mfma_f32_16x16x32_bf16, lane = kg*16+cl):
//   P[tile][kc][lane][8] bf16 ; wave fragment load = base + lane*8 -> 1KB contiguous.

// ---------------------------------------------------------------- prep ----

// pack weight src f32 [1024][4096] (k-major) -> fragment-packed B (rows = j).
__global__ void k_pack_w(const float* __restrict__ src, unsigned short* __restrict__ dst,
                         int kcoff, int kctot) {
    __shared__ float ld[64][33];
    int j0 = blockIdx.x * 32, k0 = blockIdx.y * 64;
    int tid = threadIdx.x;
    int c = tid & 31, r = tid >> 5;           // 32 j x 8 k
    #pragma unroll
    for (int i = 0; i < 8; i++)
        ld[r + i * 8][c] = src[(long)(k0 + r + i * 8) * G4_ + j0 + c];
    __syncthreads();
    int j = tid & 31, ku = tid >> 5;          // 32 j x 8 k-units of 8
    int kcl = ku >> 2, kg = ku & 3;
    int jti = (j0 + j) >> 4, cl = (j0 + j) & 15;
    int kc = kcoff + (k0 >> 5) + kcl;
    unsigned short q[8];
    #pragma unroll
    for (int e = 0; e < 8; e++) q[e] = f2bf(ld[ku * 8 + e][j]);
    *(uint4*)(dst + ((long)(jti * kctot + kc) * 64 + kg * 16 + cl) * 8) = *(uint4*)q;
}

// pack x f32 [N][T][D] -> xP tiles over m: tile = t*8 + (n>>4), rows = n&15.
__global__ void k_pack_x2(const float* __restrict__ x, unsigned short* __restrict__ xP) {
    long gid = (long)blockIdx.x * 256 + threadIdx.x;   // 8192*128
    int m = (int)(gid >> 7), u = (int)(gid & 127);
    const float* src = x + (long)m * 1024 + u * 8;
    int n = m >> 6, t = m & 63;
    int tile = t * 8 + (n >> 4);
    int kc = u >> 2, kg = u & 3, cl = n & 15;
    float4 a = *(const float4*)src, b = *(const float4*)(src + 4);
    unsigned short q[8] = {f2bf(a.x), f2bf(a.y), f2bf(a.z), f2bf(a.w),
                           f2bf(b.x), f2bf(b.y), f2bf(b.z), f2bf(b.w)};
    *(uint4*)(xP + ((long)(tile * 32 + kc) * 64 + kg * 16 + cl) * 8) = *(uint4*)q;
}

// A f32 [N][H][16] -> AfP (A-operand tiles: tile=n, row=p, k=h) + Af2 bf16 copy.
__global__ void k_pack_af(const float* __restrict__ A, unsigned short* __restrict__ AfP,
                          unsigned short* __restrict__ Af2) {
    __shared__ float ld[64][17];
    int n = blockIdx.x, h0 = blockIdx.y * 64;
    int tid = threadIdx.x;
    int hh = tid >> 2, pq = tid & 3;
    float4 v = *(const float4*)(A + ((long)n * H_ + h0 + hh) * 16 + pq * 4);
    unsigned short o[4] = {f2bf(v.x), f2bf(v.y), f2bf(v.z), f2bf(v.w)};
    *(uint2*)(Af2 + ((long)n * H_ + h0 + hh) * 16 + pq * 4) = *(uint2*)o;
    ld[hh][pq * 4 + 0] = v.x; ld[hh][pq * 4 + 1] = v.y;
    ld[hh][pq * 4 + 2] = v.z; ld[hh][pq * 4 + 3] = v.w;
    __syncthreads();
    if (tid < 128) {
        int p = tid >> 3, ku = tid & 7;
        int kc = (h0 >> 5) + (ku >> 2), kg = ku & 3;
        unsigned short q[8];
        #pragma unroll
        for (int e = 0; e < 8; e++) q[e] = f2bf(ld[ku * 8 + e][p]);
        *(uint4*)(AfP + ((long)(n * 32 + kc) * 64 + kg * 16 + p) * 8) = *(uint4*)q;
    }
}

// h0 = mean_p A; c0 = h0; packed h0.
__global__ void k_h0(const float* __restrict__ A, float* __restrict__ h,
                     float* __restrict__ c, unsigned short* __restrict__ hP0) {
    long id = (long)blockIdx.x * 256 + threadIdx.x;
    const float4* ap = (const float4*)(A + id * 16);
    float s = 0.f;
    #pragma unroll
    for (int q = 0; q < 4; q++) { float4 v = ap[q]; s += v.x + v.y + v.z + v.w; }
    float m = s * (1.0f / 16.0f);
    h[id] = m; c[id] = m;
    int n = (int)(id >> 10), j = (int)(id & 1023);
    hP0[((long)((n >> 4) * 32 + (j >> 5)) * 64 + ((j >> 3) & 3) * 16 + (n & 15)) * 8 + (j & 7)] = f2bf(m);
}

// t=0 score partials
__global__ __launch_bounds__(512)
void k_part0(const float* __restrict__ hbuf, const unsigned short* __restrict__ Af2,
             float* __restrict__ partial0) {
    int n = blockIdx.x;
    int tid = threadIdx.x;
    int jh = tid * 2;
    float sp[16];
    #pragma unroll
    for (int p = 0; p < 16; p++) sp[p] = 0.f;
    #pragma unroll
    for (int u = 0; u < 2; u++) {
        float hv = hbuf[(long)n * H_ + jh + u];
        const unsigned short* afp = Af2 + ((long)n * H_ + jh + u) * 16;
        bf16x8 a0 = *(const bf16x8*)(afp);
        bf16x8 a1 = *(const bf16x8*)(afp + 8);
        #pragma unroll
        for (int p = 0; p < 8; p++) { sp[p] += hv * bf2f((unsigned short)a0[p]);
                                      sp[8+p] += hv * bf2f((unsigned short)a1[p]); }
    }
    #pragma unroll
    for (int off = 1; off < 8; off <<= 1) {
        #pragma unroll
        for (int p = 0; p < 16; p++) sp[p] += __shfl_xor(sp[p], off);
    }
    int jt = tid >> 3;
    if ((tid & 7) == 0) {
        #pragma unroll
        for (int p = 0; p < 16; p++)
            partial0[((long)n * 16 + p) * 64 + jt] = sp[p];
    }
}

// reduce partial -> softmax -> w  (per-step, proven)
__global__ __launch_bounds__(64)
void k_score_tiny(const float* __restrict__ partial, float* __restrict__ wbuf) {
    int n = blockIdx.x;
    int lane = threadIdx.x;
    int p = lane & 15, c4 = lane >> 4;
    const float* src = partial + ((long)n * 16 + p) * 64 + c4 * 16;
    float s = 0.f;
    #pragma unroll
    for (int q = 0; q < 16; q++) s += src[q];
    s += __shfl_xor(s, 16);
    s += __shfl_xor(s, 32);
    s *= (1.0f / 32.0f);
    float m = s;
    #pragma unroll
    for (int off = 1; off < 16; off <<= 1) m = fmaxf(m, __shfl_xor(m, off));
    float e = expf(s - m);
    float sum = e;
    #pragma unroll
    for (int off = 1; off < 16; off <<= 1) sum += __shfl_xor(sum, off);
    if (c4 == 0) wbuf[n * 16 + p] = e / sum;
}

// AW = AfP @ WattnP^T. R13 body; grid axes swapped so XCD = jt-block%8:
// per-XCD B slice = 1MB (L2-resident) instead of full 8.4MB thrash.
__global__ __launch_bounds__(256, 2)
void k_aw(const unsigned short* __restrict__ AfP, const unsigned short* __restrict__ WattnP,
          unsigned short* __restrict__ AW) {
    int tid = threadIdx.x;
    int wv = tid >> 6, lane = tid & 63;
    int wr = wv >> 1, wc = wv & 1;
    int cl = lane & 15, kg = lane >> 4;
    int jt0 = blockIdx.x * 8 + wc * 4;   // grid.x = 32 (B tiles 0..255)
    int at0 = blockIdx.y * 8 + wr * 4;   // grid.y = 16 (n tiles 0..127)

    f32x4 acc[4][4];
    #pragma unroll
    for (int i = 0; i < 4; i++)
        #pragma unroll
        for (int j = 0; j < 4; j++) acc[i][j] = (f32x4){0.f, 0.f, 0.f, 0.f};

    const unsigned short* apx[4];
    const unsigned short* bpx[4];
    #pragma unroll
    for (int i = 0; i < 4; i++) {
        apx[i] = AfP    + (long)(at0 + i) * (32 * 512) + lane * 8;
        bpx[i] = WattnP + (long)(jt0 + i) * (32 * 512) + lane * 8;
    }
    #pragma unroll 2
    for (int kc = 0; kc < 32; kc++) {
        bf16x8 a[4], b[4];
        #pragma unroll
        for (int i = 0; i < 4; i++) a[i] = *(const bf16x8*)(apx[i] + kc * 512);
        #pragma unroll
        for (int i = 0; i < 4; i++) b[i] = *(const bf16x8*)(bpx[i] + kc * 512);
        #pragma unroll
        for (int i = 0; i < 4; i++)
            #pragma unroll
            for (int j = 0; j < 4; j++)
                acc[i][j] = __builtin_amdgcn_mfma_f32_16x16x32_bf16(a[i], b[j], acc[i][j], 0, 0, 0);
    }
    #pragma unroll
    for (int i = 0; i < 4; i++) {
        int n = at0 + i;
        #pragma unroll
        for (int j = 0; j < 4; j++) {
            int jj = (jt0 + j) * 16 + cl;
            #pragma unroll
            for (int v = 0; v < 4; v++) {
                int p = kg * 4 + v;
                AW[((long)n * G4_ + jj) * 16 + p] = f2bf(acc[i][j][v]);
            }
        }
    }
}

// actx = xP @ WxP^T. R13 body; grid axes swapped so XCD = jt-block%8:
// per-XCD B slice = 1MB (L2-resident); A-tiles get 4-way concurrent reuse.
__global__ __launch_bounds__(256, 2)
void k_actx(const unsigned short* __restrict__ xP, const unsigned short* __restrict__ WxP,
            unsigned short* __restrict__ actx) {
    int tid = threadIdx.x;
    int wv = tid >> 6, lane = tid & 63;
    int wr = wv >> 1, wc = wv & 1;
    int cl = lane & 15, kg = lane >> 4;
    int jt0 = blockIdx.x * 8 + wc * 4;   // grid.x = 32 (B tiles 0..255)
    int at0 = blockIdx.y * 8 + wr * 4;   // grid.y = 64 (A tiles 0..511)

    f32x4 acc[4][4];
    #pragma unroll
    for (int i = 0; i < 4; i++)
        #pragma unroll
        for (int j = 0; j < 4; j++) acc[i][j] = (f32x4){0.f, 0.f, 0.f, 0.f};

    const unsigned short* apx[4];
    const unsigned short* bpx[4];
    #pragma unroll
    for (int i = 0; i < 4; i++) {
        apx[i] = xP  + (long)(at0 + i) * (32 * 512) + lane * 8;
        bpx[i] = WxP + (long)(jt0 + i) * (32 * 512) + lane * 8;
    }
    #pragma unroll 2
    for (int kc = 0; kc < 32; kc++) {
        bf16x8 a[4], b[4];
        #pragma unroll
        for (int i = 0; i < 4; i++) a[i] = *(const bf16x8*)(apx[i] + kc * 512);
        #pragma unroll
        for (int i = 0; i < 4; i++) b[i] = *(const bf16x8*)(bpx[i] + kc * 512);
        #pragma unroll
        for (int i = 0; i < 4; i++)
            #pragma unroll
            for (int j = 0; j < 4; j++)
                acc[i][j] = __builtin_amdgcn_mfma_f32_16x16x32_bf16(a[i], b[j], acc[i][j], 0, 0, 0);
    }
    #pragma unroll
    for (int i = 0; i < 4; i++) {
        long mrow = (long)(at0 + i) * 16;
        #pragma unroll
        for (int j = 0; j < 4; j++) {
            int jj = (jt0 + j) * 16 + cl;
            #pragma unroll
            for (int v = 0; v < 4; v++)
                actx[(mrow + kg * 4 + v) * G4_ + jj] = f2bf(acc[i][j][v]);
        }
    }
}

// ------------------------------------------------------------- per step ----

// k_step: K=1024 h-only GEMM + actx/AW epilogue (R13-proven, verbatim).
// grid (64 jt, 4 nt2), 512 thr = 8 waves (ks:4 K-quarters x rh:2 row halves).
__global__ __launch_bounds__(512, 2)
void k_step(const unsigned short* __restrict__ actx,   // bf16 [8192][4096]
            const unsigned short* __restrict__ hPin,   // packed [8 nt][32 kc][64][8]
            unsigned short* __restrict__ hPout,
            const unsigned short* __restrict__ WhP,    // [256 jti][32 kc][64][8]
            const unsigned short* __restrict__ AW,     // [N][4096][16]
            const unsigned short* __restrict__ Af2,    // [N][H][16]
            const float* __restrict__ wbuf,            // [N][16]
            const float* __restrict__ bvec,
            float* __restrict__ c,
            float* __restrict__ partOUT,               // [N][16][64]
            float* __restrict__ out, int t) {
    int tid = threadIdx.x;
    int wv = tid >> 6, lane = tid & 63;
    int ks = wv & 3, rh = wv >> 2;
    int cl = lane & 15, kg = lane >> 4;
    int jt = blockIdx.x;
    int nt2 = blockIdx.y;
    int colbase = jt * 16;

    // ---- GEMM: 16 rows (rh half) x 16 jh x 4 gates over K=256 (8 kc) ----
    f32x4 acc[4];
    #pragma unroll
    for (int g = 0; g < 4; g++) acc[g] = (f32x4){0.f, 0.f, 0.f, 0.f};

    const unsigned short* abase = hPin + ((long)(nt2 * 2 + rh) * 32 + ks * 8) * 512 + lane * 8;
    const unsigned short* bb[4];
    #pragma unroll
    for (int g = 0; g < 4; g++)
        bb[g] = WhP + ((long)(g * 64 + jt) * 32 + ks * 8) * 512 + lane * 8;

    #pragma unroll
    for (int i = 0; i < 8; i++) {
        bf16x8 a = *(const bf16x8*)(abase + i * 512);
        #pragma unroll
        for (int g = 0; g < 4; g++) {
            bf16x8 b = *(const bf16x8*)(bb[g] + i * 512);
            acc[g] = __builtin_amdgcn_mfma_f32_16x16x32_bf16(a, b, acc[g], 0, 0, 0);
        }
    }

    // ---- 4-way K reduce per rh ----
    __shared__ float red[3][2][64][17];
    __shared__ float act[4][32][17];
    if (ks != 0) {
        #pragma unroll
        for (int g = 0; g < 4; g++)
            #pragma unroll
            for (int v = 0; v < 4; v++) red[ks - 1][rh][lane][g * 4 + v] = acc[g][v];
    }
    __syncthreads();
    if (ks == 0) {
        #pragma unroll
        for (int g = 0; g < 4; g++)
            #pragma unroll
            for (int v = 0; v < 4; v++) {
                float s = acc[g][v] + red[0][rh][lane][g*4+v] + red[1][rh][lane][g*4+v]
                        + red[2][rh][lane][g*4+v];
                act[g][rh * 16 + kg * 4 + v][cl] = s;   // C/D row = 4*kg + v
            }
    }
    __syncthreads();

    // ---- epilogue: 512 thr x 1 (n, jh) cell ----
    int nloc = tid >> 4, jl = tid & 15;
    int n = nt2 * 32 + nloc, jh = colbase + jl;
    float wv16[16];
    #pragma unroll
    for (int p = 0; p < 16; p++) wv16[p] = wbuf[n * 16 + p];

    long rm = (long)(t * 8 + (n >> 4)) * 16 + (n & 15);   // actx row
    float s4[4];
    #pragma unroll
    for (int g = 0; g < 4; g++) {
        int j = g * 1024 + jh;
        const unsigned short* awp = AW + ((long)n * G4_ + j) * 16;
        bf16x8 aw0 = *(const bf16x8*)(awp);
        bf16x8 aw1 = *(const bf16x8*)(awp + 8);
        float at = 0.f;
        #pragma unroll
        for (int p = 0; p < 8; p++) at += wv16[p]     * bf2f((unsigned short)aw0[p]);
        #pragma unroll
        for (int p = 0; p < 8; p++) at += wv16[8 + p] * bf2f((unsigned short)aw1[p]);
        s4[g] = act[g][nloc][jl] + bf2f(actx[rm * G4_ + j]) + at + bvec[j];
    }
    float ig = 1.f / (1.f + expf(-s4[0]));
    float fg = 1.f / (1.f + expf(-s4[1]));
    float og = 1.f / (1.f + expf(-s4[2]));
    float gg = tanhf(s4[3]);
    long idx = (long)n * H_ + jh;
    float cn = fg * c[idx] + ig * gg;
    float hn = og * tanhf(cn);
    c[idx] = cn;
    out[((long)n * T_ + t) * H_ + jh] = hn;
    hPout[((long)((n >> 4) * 32 + (jh >> 5)) * 64 + ((jh >> 3) & 3) * 16 + (n & 15)) * 8 + (jh & 7)] = f2bf(hn);

    // score partials for t+1
    const unsigned short* afp = Af2 + ((long)n * H_ + jh) * 16;
    bf16x8 af0 = *(const bf16x8*)(afp);
    bf16x8 af1 = *(const bf16x8*)(afp + 8);
    float sp[16];
    #pragma unroll
    for (int p = 0; p < 8; p++) { sp[p]     = hn * bf2f((unsigned short)af0[p]);
                                  sp[8 + p] = hn * bf2f((unsigned short)af1[p]); }
    #pragma unroll
    for (int off = 1; off < 16; off <<= 1) {
        #pragma unroll
        for (int p = 0; p < 16; p++) sp[p] += __shfl_xor(sp[p], off);
    }
    float outv = 0.f;
    #pragma unroll
    for (int p = 0; p < 16; p++) if (jl == p) outv = sp[p];
    partOUT[((long)n * 16 + jl) * 64 + jt] = outv;
}

// ---------------------------------------------------------------- launch ----

extern "C" void kernel_launch(void* const* d_in, const int* in_sizes, int n_in,
                              void* d_out, int out_size, void* d_ws, size_t ws_size,
                              hipStream_t stream) {
    const float* x     = (const float*)d_in[0];
    const float* A     = (const float*)d_in[1];
    const float* Wx    = (const float*)d_in[2];
    const float* Wh    = (const float*)d_in[3];
    const float* Wattn = (const float*)d_in[4];
    const float* b     = (const float*)d_in[5];
    float* out = (float*)d_out;

    char* ws = (char*)d_ws;
    size_t off = 0;
    auto alloc = [&](size_t bytes) -> void* {
        void* p = ws + off;
        off += (bytes + 255) & ~(size_t)255;
        return p;
    };
    unsigned short* xP     = (unsigned short*)alloc((size_t)512 * 32 * 512 * 2);   // 16.8MB
    unsigned short* WxP    = (unsigned short*)alloc((size_t)256 * 32 * 512 * 2);   // 8.4MB
    unsigned short* WhP    = (unsigned short*)alloc((size_t)256 * 32 * 512 * 2);   // 8.4MB
    unsigned short* WattnP = (unsigned short*)alloc((size_t)256 * 32 * 512 * 2);   // 8.4MB
    unsigned short* AfP    = (unsigned short*)alloc((size_t)128 * 32 * 512 * 2);   // 4.2MB
    unsigned short* Af2    = (unsigned short*)alloc((size_t)N_ * H_ * 16 * 2);     // 4.2MB
    unsigned short* AW     = (unsigned short*)alloc((size_t)N_ * G4_ * 16 * 2);    // 16.8MB
    unsigned short* actx   = (unsigned short*)alloc((size_t)8192 * G4_ * 2);       // 67.1MB
    float*          hbuf   = (float*)alloc((size_t)N_ * H_ * 4);
    float*          cbuf   = (float*)alloc((size_t)N_ * H_ * 4);
    unsigned short* hP0    = (unsigned short*)alloc((size_t)8 * 32 * 512 * 2);
    unsigned short* hP1    = (unsigned short*)alloc((size_t)8 * 32 * 512 * 2);
    float*          part0  = (float*)alloc((size_t)N_ * 16 * 64 * 4);
    float*          part1  = (float*)alloc((size_t)N_ * 16 * 64 * 4);
    float*          wbuf   = (float*)alloc((size_t)N_ * 16 * 4);

    // prep
    k_pack_w<<<dim3(128, 16), dim3(256), 0, stream>>>(Wx,    WxP,    0, 32);
    k_pack_w<<<dim3(128, 16), dim3(256), 0, stream>>>(Wh,    WhP,    0, 32);
    k_pack_w<<<dim3(128, 16), dim3(256), 0, stream>>>(Wattn, WattnP, 0, 32);
    k_pack_x2<<<dim3(4096), dim3(256), 0, stream>>>(x, xP);
    k_pack_af<<<dim3(128, 16), dim3(256), 0, stream>>>(A, AfP, Af2);
    k_h0<<<dim3(512), dim3(256), 0, stream>>>(A, hbuf, cbuf, hP0);
    k_part0<<<dim3(N_), dim3(512), 0, stream>>>(hbuf, Af2, part0);
    k_aw<<<dim3(32, 16), dim3(256), 0, stream>>>(AfP, WattnP, AW);
    k_actx<<<dim3(32, 64), dim3(256), 0, stream>>>(xP, WxP, actx);

    // recurrence
    for (int t = 0; t < T_; t++) {
        unsigned short* hin  = (t & 1) ? hP1 : hP0;
        unsigned short* hout = (t & 1) ? hP0 : hP1;
        float* pIN  = (t & 1) ? part1 : part0;
        float* pOUT = (t & 1) ? part0 : part1;
        k_score_tiny<<<dim3(N_), dim3(64), 0, stream>>>(pIN, wbuf);
        k_step<<<dim3(64, 4), dim3(512), 0, stream>>>(actx, hin, hout, WhP, AW, Af2,
                                                      wbuf, b, cbuf, pOUT, out, t);
    }
}

// Round 22
// 1046.092 us; speedup vs baseline: 1.1486x; 1.0144x over previous
//
#include <hip/hip_runtime.h>
#include <hip/hip_bf16.h>
#include <cmath>

// Problem constants
#define N_   128
#define T_   64
#define D_   1024
#define H_   1024
#define G4_  4096   // 4*H

typedef short bf16x8 __attribute__((ext_vector_type(8)));
typedef float f32x4  __attribute__((ext_vector_type(4)));

__device__ __forceinline__ unsigned short f2bf(float f) {
    union { float f; unsigned int u; } v; v.f = f;
    unsigned int r = (v.u + 0x7FFFu + ((v.u >> 16) & 1u)) >> 16;  // RNE
    return (unsigned short)r;
}
__device__ __forceinline__ float bf2f(unsigned short s) {
    union { unsigned int u; float f; } v; v.u = ((unsigned int)s) << 16;
    return v.f;
}

// Fragment-packed layout (mfma_f32_16x16x32_bf16, lane = kg*16+cl):
//   P[tile][kc][lane][8] bf16 ; wave fragment load = base + lane*8 -> 1KB contiguous.

// ---------------------------------------------------------------- prep ----

// pack weight src f32 [1024][4096] (k-major) -> fragment-packed B (rows = j).
__global__ void k_pack_w(const float* __restrict__ src, unsigned short* __restrict__ dst,
                         int kcoff, int kctot) {
    __shared__ float ld[64][33];
    int j0 = blockIdx.x * 32, k0 = blockIdx.y * 64;
    int tid = threadIdx.x;
    int c = tid & 31, r = tid >> 5;           // 32 j x 8 k
    #pragma unroll
    for (int i = 0; i < 8; i++)
        ld[r + i * 8][c] = src[(long)(k0 + r + i * 8) * G4_ + j0 + c];
    __syncthreads();
    int j = tid & 31, ku = tid >> 5;          // 32 j x 8 k-units of 8
    int kcl = ku >> 2, kg = ku & 3;
    int jti = (j0 + j) >> 4, cl = (j0 + j) & 15;
    int kc = kcoff + (k0 >> 5) + kcl;
    unsigned short q[8];
    #pragma unroll
    for (int e = 0; e < 8; e++) q[e] = f2bf(ld[ku * 8 + e][j]);
    *(uint4*)(dst + ((long)(jti * kctot + kc) * 64 + kg * 16 + cl) * 8) = *(uint4*)q;
}

// pack x f32 [N][T][D] -> xP tiles over m: tile = t*8 + (n>>4), rows = n&15.
__global__ void k_pack_x2(const float* __restrict__ x, unsigned short* __restrict__ xP) {
    long gid = (long)blockIdx.x * 256 + threadIdx.x;   // 8192*128
    int m = (int)(gid >> 7), u = (int)(gid & 127);
    const float* src = x + (long)m * 1024 + u * 8;
    int n = m >> 6, t = m & 63;
    int tile = t * 8 + (n >> 4);
    int kc = u >> 2, kg = u & 3, cl = n & 15;
    float4 a = *(const float4*)src, b = *(const float4*)(src + 4);
    unsigned short q[8] = {f2bf(a.x), f2bf(a.y), f2bf(a.z), f2bf(a.w),
                           f2bf(b.x), f2bf(b.y), f2bf(b.z), f2bf(b.w)};
    *(uint4*)(xP + ((long)(tile * 32 + kc) * 64 + kg * 16 + cl) * 8) = *(uint4*)q;
}

// A f32 [N][H][16] -> AfP (A-operand tiles: tile=n, row=p, k=h) + Af2 bf16 copy.
__global__ void k_pack_af(const float* __restrict__ A, unsigned short* __restrict__ AfP,
                          unsigned short* __restrict__ Af2) {
    __shared__ float ld[64][17];
    int n = blockIdx.x, h0 = blockIdx.y * 64;
    int tid = threadIdx.x;
    int hh = tid >> 2, pq = tid & 3;
    float4 v = *(const float4*)(A + ((long)n * H_ + h0 + hh) * 16 + pq * 4);
    unsigned short o[4] = {f2bf(v.x), f2bf(v.y), f2bf(v.z), f2bf(v.w)};
    *(uint2*)(Af2 + ((long)n * H_ + h0 + hh) * 16 + pq * 4) = *(uint2*)o;
    ld[hh][pq * 4 + 0] = v.x; ld[hh][pq * 4 + 1] = v.y;
    ld[hh][pq * 4 + 2] = v.z; ld[hh][pq * 4 + 3] = v.w;
    __syncthreads();
    if (tid < 128) {
        int p = tid >> 3, ku = tid & 7;
        int kc = (h0 >> 5) + (ku >> 2), kg = ku & 3;
        unsigned short q[8];
        #pragma unroll
        for (int e = 0; e < 8; e++) q[e] = f2bf(ld[ku * 8 + e][p]);
        *(uint4*)(AfP + ((long)(n * 32 + kc) * 64 + kg * 16 + p) * 8) = *(uint4*)q;
    }
}

// h0 = mean_p A; c0 = h0; packed h0.
__global__ void k_h0(const float* __restrict__ A, float* __restrict__ h,
                     float* __restrict__ c, unsigned short* __restrict__ hP0) {
    long id = (long)blockIdx.x * 256 + threadIdx.x;
    const float4* ap = (const float4*)(A + id * 16);
    float s = 0.f;
    #pragma unroll
    for (int q = 0; q < 4; q++) { float4 v = ap[q]; s += v.x + v.y + v.z + v.w; }
    float m = s * (1.0f / 16.0f);
    h[id] = m; c[id] = m;
    int n = (int)(id >> 10), j = (int)(id & 1023);
    hP0[((long)((n >> 4) * 32 + (j >> 5)) * 64 + ((j >> 3) & 3) * 16 + (n & 15)) * 8 + (j & 7)] = f2bf(m);
}

// t=0 score partials
__global__ __launch_bounds__(512)
void k_part0(const float* __restrict__ hbuf, const unsigned short* __restrict__ Af2,
             float* __restrict__ partial0) {
    int n = blockIdx.x;
    int tid = threadIdx.x;
    int jh = tid * 2;
    float sp[16];
    #pragma unroll
    for (int p = 0; p < 16; p++) sp[p] = 0.f;
    #pragma unroll
    for (int u = 0; u < 2; u++) {
        float hv = hbuf[(long)n * H_ + jh + u];
        const unsigned short* afp = Af2 + ((long)n * H_ + jh + u) * 16;
        bf16x8 a0 = *(const bf16x8*)(afp);
        bf16x8 a1 = *(const bf16x8*)(afp + 8);
        #pragma unroll
        for (int p = 0; p < 8; p++) { sp[p] += hv * bf2f((unsigned short)a0[p]);
                                      sp[8+p] += hv * bf2f((unsigned short)a1[p]); }
    }
    #pragma unroll
    for (int off = 1; off < 8; off <<= 1) {
        #pragma unroll
        for (int p = 0; p < 16; p++) sp[p] += __shfl_xor(sp[p], off);
    }
    int jt = tid >> 3;
    if ((tid & 7) == 0) {
        #pragma unroll
        for (int p = 0; p < 16; p++)
            partial0[((long)n * 16 + p) * 64 + jt] = sp[p];
    }
}

// reduce partial -> softmax -> w  (per-step, proven)
__global__ __launch_bounds__(64)
void k_score_tiny(const float* __restrict__ partial, float* __restrict__ wbuf) {
    int n = blockIdx.x;
    int lane = threadIdx.x;
    int p = lane & 15, c4 = lane >> 4;
    const float* src = partial + ((long)n * 16 + p) * 64 + c4 * 16;
    float s = 0.f;
    #pragma unroll
    for (int q = 0; q < 16; q++) s += src[q];
    s += __shfl_xor(s, 16);
    s += __shfl_xor(s, 32);
    s *= (1.0f / 32.0f);
    float m = s;
    #pragma unroll
    for (int off = 1; off < 16; off <<= 1) m = fmaxf(m, __shfl_xor(m, off));
    float e = expf(s - m);
    float sum = e;
    #pragma unroll
    for (int off = 1; off < 16; off <<= 1) sum += __shfl_xor(sum, off);
    if (c4 == 0) wbuf[n * 16 + p] = e / sum;
}

// AW = AfP @ WattnP^T (R13 grid/body; occupancy 4 blocks/CU).
__global__ __launch_bounds__(256, 4)
void k_aw(const unsigned short* __restrict__ AfP, const unsigned short* __restrict__ WattnP,
          unsigned short* __restrict__ AW) {
    int tid = threadIdx.x;
    int wv = tid >> 6, lane = tid & 63;
    int wr = wv >> 1, wc = wv & 1;
    int cl = lane & 15, kg = lane >> 4;
    int at0 = blockIdx.x * 8 + wr * 4;
    int jt0 = blockIdx.y * 8 + wc * 4;

    f32x4 acc[4][4];
    #pragma unroll
    for (int i = 0; i < 4; i++)
        #pragma unroll
        for (int j = 0; j < 4; j++) acc[i][j] = (f32x4){0.f, 0.f, 0.f, 0.f};

    const unsigned short* apx[4];
    const unsigned short* bpx[4];
    #pragma unroll
    for (int i = 0; i < 4; i++) {
        apx[i] = AfP    + (long)(at0 + i) * (32 * 512) + lane * 8;
        bpx[i] = WattnP + (long)(jt0 + i) * (32 * 512) + lane * 8;
    }
    #pragma unroll 2
    for (int kc = 0; kc < 32; kc++) {
        bf16x8 a[4], b[4];
        #pragma unroll
        for (int i = 0; i < 4; i++) a[i] = *(const bf16x8*)(apx[i] + kc * 512);
        #pragma unroll
        for (int i = 0; i < 4; i++) b[i] = *(const bf16x8*)(bpx[i] + kc * 512);
        #pragma unroll
        for (int i = 0; i < 4; i++)
            #pragma unroll
            for (int j = 0; j < 4; j++)
                acc[i][j] = __builtin_amdgcn_mfma_f32_16x16x32_bf16(a[i], b[j], acc[i][j], 0, 0, 0);
    }
    #pragma unroll
    for (int i = 0; i < 4; i++) {
        int n = at0 + i;
        #pragma unroll
        for (int j = 0; j < 4; j++) {
            int jj = (jt0 + j) * 16 + cl;
            #pragma unroll
            for (int v = 0; v < 4; v++) {
                int p = kg * 4 + v;
                AW[((long)n * G4_ + jj) * 16 + p] = f2bf(acc[i][j][v]);
            }
        }
    }
}

// actx = xP @ WxP^T (R13 grid/body; occupancy 4 blocks/CU).
__global__ __launch_bounds__(256, 4)
void k_actx(const unsigned short* __restrict__ xP, const unsigned short* __restrict__ WxP,
            unsigned short* __restrict__ actx) {
    int tid = threadIdx.x;
    int wv = tid >> 6, lane = tid & 63;
    int wr = wv >> 1, wc = wv & 1;
    int cl = lane & 15, kg = lane >> 4;
    int at0 = blockIdx.x * 8 + wr * 4;    // A tiles (0..511)
    int jt0 = blockIdx.y * 8 + wc * 4;    // B tiles (0..255)

    f32x4 acc[4][4];
    #pragma unroll
    for (int i = 0; i < 4; i++)
        #pragma unroll
        for (int j = 0; j < 4; j++) acc[i][j] = (f32x4){0.f, 0.f, 0.f, 0.f};

    const unsigned short* apx[4];
    const unsigned short* bpx[4];
    #pragma unroll
    for (int i = 0; i < 4; i++) {
        apx[i] = xP  + (long)(at0 + i) * (32 * 512) + lane * 8;
        bpx[i] = WxP + (long)(jt0 + i) * (32 * 512) + lane * 8;
    }
    #pragma unroll 2
    for (int kc = 0; kc < 32; kc++) {
        bf16x8 a[4], b[4];
        #pragma unroll
        for (int i = 0; i < 4; i++) a[i] = *(const bf16x8*)(apx[i] + kc * 512);
        #pragma unroll
        for (int i = 0; i < 4; i++) b[i] = *(const bf16x8*)(bpx[i] + kc * 512);
        #pragma unroll
        for (int i = 0; i < 4; i++)
            #pragma unroll
            for (int j = 0; j < 4; j++)
                acc[i][j] = __builtin_amdgcn_mfma_f32_16x16x32_bf16(a[i], b[j], acc[i][j], 0, 0, 0);
    }
    #pragma unroll
    for (int i = 0; i < 4; i++) {
        long mrow = (long)(at0 + i) * 16;
        #pragma unroll
        for (int j = 0; j < 4; j++) {
            int jj = (jt0 + j) * 16 + cl;
            #pragma unroll
            for (int v = 0; v < 4; v++)
                actx[(mrow + kg * 4 + v) * G4_ + jj] = f2bf(acc[i][j][v]);
        }
    }
}

// ------------------------------------------------------------- per step ----

// k_step: K=1024 h-only GEMM + actx/AW epilogue (R13-proven, verbatim).
// grid (64 jt, 4 nt2), 512 thr = 8 waves (ks:4 K-quarters x rh:2 row halves).
__global__ __launch_bounds__(512, 2)
void k_step(const unsigned short* __restrict__ actx,   // bf16 [8192][4096]
            const unsigned short* __restrict__ hPin,   // packed [8 nt][32 kc][64][8]
            unsigned short* __restrict__ hPout,
            const unsigned short* __restrict__ WhP,    // [256 jti][32 kc][64][8]
            const unsigned short* __restrict__ AW,     // [N][4096][16]
            const unsigned short* __restrict__ Af2,    // [N][H][16]
            const float* __restrict__ wbuf,            // [N][16]
            const float* __restrict__ bvec,
            float* __restrict__ c,
            float* __restrict__ partOUT,               // [N][16][64]
            float* __restrict__ out, int t) {
    int tid = threadIdx.x;
    int wv = tid >> 6, lane = tid & 63;
    int ks = wv & 3, rh = wv >> 2;
    int cl = lane & 15, kg = lane >> 4;
    int jt = blockIdx.x;
    int nt2 = blockIdx.y;
    int colbase = jt * 16;

    // ---- GEMM: 16 rows (rh half) x 16 jh x 4 gates over K=256 (8 kc) ----
    f32x4 acc[4];
    #pragma unroll
    for (int g = 0; g < 4; g++) acc[g] = (f32x4){0.f, 0.f, 0.f, 0.f};

    const unsigned short* abase = hPin + ((long)(nt2 * 2 + rh) * 32 + ks * 8) * 512 + lane * 8;
    const unsigned short* bb[4];
    #pragma unroll
    for (int g = 0; g < 4; g++)
        bb[g] = WhP + ((long)(g * 64 + jt) * 32 + ks * 8) * 512 + lane * 8;

    #pragma unroll
    for (int i = 0; i < 8; i++) {
        bf16x8 a = *(const bf16x8*)(abase + i * 512);
        #pragma unroll
        for (int g = 0; g < 4; g++) {
            bf16x8 b = *(const bf16x8*)(bb[g] + i * 512);
            acc[g] = __builtin_amdgcn_mfma_f32_16x16x32_bf16(a, b, acc[g], 0, 0, 0);
        }
    }

    // ---- 4-way K reduce per rh ----
    __shared__ float red[3][2][64][17];
    __shared__ float act[4][32][17];
    if (ks != 0) {
        #pragma unroll
        for (int g = 0; g < 4; g++)
            #pragma unroll
            for (int v = 0; v < 4; v++) red[ks - 1][rh][lane][g * 4 + v] = acc[g][v];
    }
    __syncthreads();
    if (ks == 0) {
        #pragma unroll
        for (int g = 0; g < 4; g++)
            #pragma unroll
            for (int v = 0; v < 4; v++) {
                float s = acc[g][v] + red[0][rh][lane][g*4+v] + red[1][rh][lane][g*4+v]
                        + red[2][rh][lane][g*4+v];
                act[g][rh * 16 + kg * 4 + v][cl] = s;   // C/D row = 4*kg + v
            }
    }
    __syncthreads();

    // ---- epilogue: 512 thr x 1 (n, jh) cell ----
    int nloc = tid >> 4, jl = tid & 15;
    int n = nt2 * 32 + nloc, jh = colbase + jl;
    float wv16[16];
    #pragma unroll
    for (int p = 0; p < 16; p++) wv16[p] = wbuf[n * 16 + p];

    long rm = (long)(t * 8 + (n >> 4)) * 16 + (n & 15);   // actx row
    float s4[4];
    #pragma unroll
    for (int g = 0; g < 4; g++) {
        int j = g * 1024 + jh;
        const unsigned short* awp = AW + ((long)n * G4_ + j) * 16;
        bf16x8 aw0 = *(const bf16x8*)(awp);
        bf16x8 aw1 = *(const bf16x8*)(awp + 8);
        float at = 0.f;
        #pragma unroll
        for (int p = 0; p < 8; p++) at += wv16[p]     * bf2f((unsigned short)aw0[p]);
        #pragma unroll
        for (int p = 0; p < 8; p++) at += wv16[8 + p] * bf2f((unsigned short)aw1[p]);
        s4[g] = act[g][nloc][jl] + bf2f(actx[rm * G4_ + j]) + at + bvec[j];
    }
    float ig = 1.f / (1.f + expf(-s4[0]));
    float fg = 1.f / (1.f + expf(-s4[1]));
    float og = 1.f / (1.f + expf(-s4[2]));
    float gg = tanhf(s4[3]);
    long idx = (long)n * H_ + jh;
    float cn = fg * c[idx] + ig * gg;
    float hn = og * tanhf(cn);
    c[idx] = cn;
    out[((long)n * T_ + t) * H_ + jh] = hn;
    hPout[((long)((n >> 4) * 32 + (jh >> 5)) * 64 + ((jh >> 3) & 3) * 16 + (n & 15)) * 8 + (jh & 7)] = f2bf(hn);

    // score partials for t+1
    const unsigned short* afp = Af2 + ((long)n * H_ + jh) * 16;
    bf16x8 af0 = *(const bf16x8*)(afp);
    bf16x8 af1 = *(const bf16x8*)(afp + 8);
    float sp[16];
    #pragma unroll
    for (int p = 0; p < 8; p++) { sp[p]     = hn * bf2f((unsigned short)af0[p]);
                                  sp[8 + p] = hn * bf2f((unsigned short)af1[p]); }
    #pragma unroll
    for (int off = 1; off < 16; off <<= 1) {
        #pragma unroll
        for (int p = 0; p < 16; p++) sp[p] += __shfl_xor(sp[p], off);
    }
    float outv = 0.f;
    #pragma unroll
    for (int p = 0; p < 16; p++) if (jl == p) outv = sp[p];
    partOUT[((long)n * 16 + jl) * 64 + jt] = outv;
}

// ---------------------------------------------------------------- launch ----

extern "C" void kernel_launch(void* const* d_in, const int* in_sizes, int n_in,
                              void* d_out, int out_size, void* d_ws, size_t ws_size,
                              hipStream_t stream) {
    const float* x     = (const float*)d_in[0];
    const float* A     = (const float*)d_in[1];
    const float* Wx    = (const float*)d_in[2];
    const float* Wh    = (const float*)d_in[3];
    const float* Wattn = (const float*)d_in[4];
    const float* b     = (const float*)d_in[5];
    float* out = (float*)d_out;

    char* ws = (char*)d_ws;
    size_t off = 0;
    auto alloc = [&](size_t bytes) -> void* {
        void* p = ws + off;
        off += (bytes + 255) & ~(size_t)255;
        return p;
    };
    unsigned short* xP     = (unsigned short*)alloc((size_t)512 * 32 * 512 * 2);   // 16.8MB
    unsigned short* WxP    = (unsigned short*)alloc((size_t)256 * 32 * 512 * 2);   // 8.4MB
    unsigned short* WhP    = (unsigned short*)alloc((size_t)256 * 32 * 512 * 2);   // 8.4MB
    unsigned short* WattnP = (unsigned short*)alloc((size_t)256 * 32 * 512 * 2);   // 8.4MB
    unsigned short* AfP    = (unsigned short*)alloc((size_t)128 * 32 * 512 * 2);   // 4.2MB
    unsigned short* Af2    = (unsigned short*)alloc((size_t)N_ * H_ * 16 * 2);     // 4.2MB
    unsigned short* AW     = (unsigned short*)alloc((size_t)N_ * G4_ * 16 * 2);    // 16.8MB
    unsigned short* actx   = (unsigned short*)alloc((size_t)8192 * G4_ * 2);       // 67.1MB
    float*          hbuf   = (float*)alloc((size_t)N_ * H_ * 4);
    float*          cbuf   = (float*)alloc((size_t)N_ * H_ * 4);
    unsigned short* hP0    = (unsigned short*)alloc((size_t)8 * 32 * 512 * 2);
    unsigned short* hP1    = (unsigned short*)alloc((size_t)8 * 32 * 512 * 2);
    float*          part0  = (float*)alloc((size_t)N_ * 16 * 64 * 4);
    float*          part1  = (float*)alloc((size_t)N_ * 16 * 64 * 4);
    float*          wbuf   = (float*)alloc((size_t)N_ * 16 * 4);

    // prep
    k_pack_w<<<dim3(128, 16), dim3(256), 0, stream>>>(Wx,    WxP,    0, 32);
    k_pack_w<<<dim3(128, 16), dim3(256), 0, stream>>>(Wh,    WhP,    0, 32);
    k_pack_w<<<dim3(128, 16), dim3(256), 0, stream>>>(Wattn, WattnP, 0, 32);
    k_pack_x2<<<dim3(4096), dim3(256), 0, stream>>>(x, xP);
    k_pack_af<<<dim3(128, 16), dim3(256), 0, stream>>>(A, AfP, Af2);
    k_h0<<<dim3(512), dim3(256), 0, stream>>>(A, hbuf, cbuf, hP0);
    k_part0<<<dim3(N_), dim3(512), 0, stream>>>(hbuf, Af2, part0);
    k_aw<<<dim3(16, 32), dim3(256), 0, stream>>>(AfP, WattnP, AW);
    k_actx<<<dim3(64, 32), dim3(256), 0, stream>>>(xP, WxP, actx);

    // recurrence
    for (int t = 0; t < T_; t++) {
        unsigned short* hin  = (t & 1) ? hP1 : hP0;
        unsigned short* hout = (t & 1) ? hP0 : hP1;
        float* pIN  = (t & 1) ? part1 : part0;
        float* pOUT = (t & 1) ? part0 : part1;
        k_score_tiny<<<dim3(N_), dim3(64), 0, stream>>>(pIN, wbuf);
        k_step<<<dim3(64, 4), dim3(512), 0, stream>>>(actx, hin, hout, WhP, AW, Af2,
                                                      wbuf, b, cbuf, pOUT, out, t);
    }
}

// Round 23
// 1034.700 us; speedup vs baseline: 1.1612x; 1.0110x over previous
//
#include <hip/hip_runtime.h>
#include <hip/hip_bf16.h>
#include <cmath>

// Problem constants
#define N_   128
#define T_   64
#define D_   1024
#define H_   1024
#define G4_  4096   // 4*H

typedef short bf16x8  __attribute__((ext_vector_type(8)));
typedef float f32x4   __attribute__((ext_vector_type(4)));
typedef float f32x16  __attribute__((ext_vector_type(16)));

__device__ __forceinline__ unsigned short f2bf(float f) {
    union { float f; unsigned int u; } v; v.f = f;
    unsigned int r = (v.u + 0x7FFFu + ((v.u >> 16) & 1u)) >> 16;  // RNE
    return (unsigned short)r;
}
__device__ __forceinline__ float bf2f(unsigned short s) {
    union { unsigned int u; float f; } v; v.u = ((unsigned int)s) << 16;
    return v.f;
}

// 16-row fragment packing (mfma_f32_16x16x32_bf16, lane = kg*16+cl):
//   P[tile][kc32][lane][8] ; fragment load = base + lane*8 -> 1KB contiguous.
// 32-row fragment packing (mfma_f32_32x32x16_bf16, lane = kgrp*32+row):
//   P32[tile32][kc16][lane][8] ; row = lane&31, k = (lane>>5)*8 + e.
//   C/D: col = lane&31, row = (reg&3) + 8*(reg>>2) + 4*(lane>>5).

// ---------------------------------------------------------------- prep ----

// 16-row pack (WhP only): src f32 [1024][4096] k-major -> P[jti][kc][64][8].
__global__ void k_pack_w(const float* __restrict__ src, unsigned short* __restrict__ dst,
                         int kcoff, int kctot) {
    __shared__ float ld[64][33];
    int j0 = blockIdx.x * 32, k0 = blockIdx.y * 64;
    int tid = threadIdx.x;
    int c = tid & 31, r = tid >> 5;
    #pragma unroll
    for (int i = 0; i < 8; i++)
        ld[r + i * 8][c] = src[(long)(k0 + r + i * 8) * G4_ + j0 + c];
    __syncthreads();
    int j = tid & 31, ku = tid >> 5;
    int kcl = ku >> 2, kg = ku & 3;
    int jti = (j0 + j) >> 4, cl = (j0 + j) & 15;
    int kc = kcoff + (k0 >> 5) + kcl;
    unsigned short q[8];
    #pragma unroll
    for (int e = 0; e < 8; e++) q[e] = f2bf(ld[ku * 8 + e][j]);
    *(uint4*)(dst + ((long)(jti * kctot + kc) * 64 + kg * 16 + cl) * 8) = *(uint4*)q;
}

// 32-row pack: src f32 [1024][4096] k-major -> P32[j>>5][kc16][64][8].
__global__ void k_pack_w32(const float* __restrict__ src, unsigned short* __restrict__ dst) {
    __shared__ float ld[64][33];
    int j0 = blockIdx.x * 32, k0 = blockIdx.y * 64;
    int tid = threadIdx.x;
    int c = tid & 31, r = tid >> 5;
    #pragma unroll
    for (int i = 0; i < 8; i++)
        ld[r + i * 8][c] = src[(long)(k0 + r + i * 8) * G4_ + j0 + c];
    __syncthreads();
    int cl = tid & 31, kgrp = (tid >> 5) & 1, kcl = tid >> 6;   // kcl 0..3
    int kc = (k0 >> 4) + kcl;
    unsigned short q[8];
    #pragma unroll
    for (int e = 0; e < 8; e++) q[e] = f2bf(ld[kcl * 16 + kgrp * 8 + e][cl]);
    *(uint4*)(dst + (((long)blockIdx.x * 64 + kc) * 64 + kgrp * 32 + cl) * 8) = *(uint4*)q;
}

// x f32 [N][T][D] -> xP32 rows m = t*128+n: tile32 = t*4 + (n>>5), row = n&31.
__global__ void k_pack_x32(const float* __restrict__ x, unsigned short* __restrict__ xP32) {
    long gid = (long)blockIdx.x * 256 + threadIdx.x;   // 8192*128
    int mm = (int)(gid >> 7), u = (int)(gid & 127);
    const float* src = x + (long)mm * 1024 + u * 8;
    int n = mm >> 6, t = mm & 63;
    int tile = t * 4 + (n >> 5);
    int row = n & 31;
    int kc = u >> 1, kgrp = u & 1;
    float4 a = *(const float4*)src, b = *(const float4*)(src + 4);
    unsigned short q[8] = {f2bf(a.x), f2bf(a.y), f2bf(a.z), f2bf(a.w),
                           f2bf(b.x), f2bf(b.y), f2bf(b.z), f2bf(b.w)};
    *(uint4*)(xP32 + (((long)tile * 64 + kc) * 64 + kgrp * 32 + row) * 8) = *(uint4*)q;
}

// A f32 [N][H][16] -> AfP32 (rows = n*16+p: tile = n>>1, row = (n&1)*16+p) + Af2.
__global__ void k_pack_af32(const float* __restrict__ A, unsigned short* __restrict__ AfP32,
                            unsigned short* __restrict__ Af2) {
    __shared__ float ld[64][17];
    int n = blockIdx.x, h0 = blockIdx.y * 64;
    int tid = threadIdx.x;
    int hh = tid >> 2, pq = tid & 3;
    float4 v = *(const float4*)(A + ((long)n * H_ + h0 + hh) * 16 + pq * 4);
    unsigned short o[4] = {f2bf(v.x), f2bf(v.y), f2bf(v.z), f2bf(v.w)};
    *(uint2*)(Af2 + ((long)n * H_ + h0 + hh) * 16 + pq * 4) = *(uint2*)o;
    ld[hh][pq * 4 + 0] = v.x; ld[hh][pq * 4 + 1] = v.y;
    ld[hh][pq * 4 + 2] = v.z; ld[hh][pq * 4 + 3] = v.w;
    __syncthreads();
    if (tid < 128) {
        int p = tid >> 3, ku = tid & 7;
        int kc = (h0 >> 4) + (ku >> 1), kgrp = ku & 1;
        int row = (n & 1) * 16 + p;
        unsigned short q[8];
        #pragma unroll
        for (int e = 0; e < 8; e++) q[e] = f2bf(ld[ku * 8 + e][p]);
        *(uint4*)(AfP32 + (((long)(n >> 1) * 64 + kc) * 64 + kgrp * 32 + row) * 8) = *(uint4*)q;
    }
}

// h0 = mean_p A; c0 = h0; packed h0.
__global__ void k_h0(const float* __restrict__ A, float* __restrict__ h,
                     float* __restrict__ c, unsigned short* __restrict__ hP0) {
    long id = (long)blockIdx.x * 256 + threadIdx.x;
    const float4* ap = (const float4*)(A + id * 16);
    float s = 0.f;
    #pragma unroll
    for (int q = 0; q < 4; q++) { float4 v = ap[q]; s += v.x + v.y + v.z + v.w; }
    float m = s * (1.0f / 16.0f);
    h[id] = m; c[id] = m;
    int n = (int)(id >> 10), j = (int)(id & 1023);
    hP0[((long)((n >> 4) * 32 + (j >> 5)) * 64 + ((j >> 3) & 3) * 16 + (n & 15)) * 8 + (j & 7)] = f2bf(m);
}

// t=0 score partials
__global__ __launch_bounds__(512)
void k_part0(const float* __restrict__ hbuf, const unsigned short* __restrict__ Af2,
             float* __restrict__ partial0) {
    int n = blockIdx.x;
    int tid = threadIdx.x;
    int jh = tid * 2;
    float sp[16];
    #pragma unroll
    for (int p = 0; p < 16; p++) sp[p] = 0.f;
    #pragma unroll
    for (int u = 0; u < 2; u++) {
        float hv = hbuf[(long)n * H_ + jh + u];
        const unsigned short* afp = Af2 + ((long)n * H_ + jh + u) * 16;
        bf16x8 a0 = *(const bf16x8*)(afp);
        bf16x8 a1 = *(const bf16x8*)(afp + 8);
        #pragma unroll
        for (int p = 0; p < 8; p++) { sp[p] += hv * bf2f((unsigned short)a0[p]);
                                      sp[8+p] += hv * bf2f((unsigned short)a1[p]); }
    }
    #pragma unroll
    for (int off = 1; off < 8; off <<= 1) {
        #pragma unroll
        for (int p = 0; p < 16; p++) sp[p] += __shfl_xor(sp[p], off);
    }
    int jt = tid >> 3;
    if ((tid & 7) == 0) {
        #pragma unroll
        for (int p = 0; p < 16; p++)
            partial0[((long)n * 16 + p) * 64 + jt] = sp[p];
    }
}

// reduce partial -> softmax -> w  (per-step, proven)
__global__ __launch_bounds__(64)
void k_score_tiny(const float* __restrict__ partial, float* __restrict__ wbuf) {
    int n = blockIdx.x;
    int lane = threadIdx.x;
    int p = lane & 15, c4 = lane >> 4;
    const float* src = partial + ((long)n * 16 + p) * 64 + c4 * 16;
    float s = 0.f;
    #pragma unroll
    for (int q = 0; q < 16; q++) s += src[q];
    s += __shfl_xor(s, 16);
    s += __shfl_xor(s, 32);
    s *= (1.0f / 32.0f);
    float m = s;
    #pragma unroll
    for (int off = 1; off < 16; off <<= 1) m = fmaxf(m, __shfl_xor(m, off));
    float e = expf(s - m);
    float sum = e;
    #pragma unroll
    for (int off = 1; off < 16; off <<= 1) sum += __shfl_xor(sum, off);
    if (c4 == 0) wbuf[n * 16 + p] = e / sum;
}

// AW = AfP32 @ WattnP32^T via 32x32x16 MFMA. Wave 2x2 tiles (64x64 out).
// grid (16 Mb, 32 jNb). Output AW[n][4096][16] unchanged.
__global__ __launch_bounds__(256, 2)
void k_aw(const unsigned short* __restrict__ AfP32, const unsigned short* __restrict__ WattnP32,
          unsigned short* __restrict__ AW) {
    int tid = threadIdx.x;
    int wv = tid >> 6, lane = tid & 63;
    int wr = wv >> 1, wc = wv & 1;
    int at0 = blockIdx.x * 4 + wr * 2;   // M tiles (0..63)
    int jt0 = blockIdx.y * 4 + wc * 2;   // j tiles (0..127)

    f32x16 acc[2][2];
    #pragma unroll
    for (int i = 0; i < 2; i++)
        #pragma unroll
        for (int j = 0; j < 2; j++)
            #pragma unroll
            for (int r = 0; r < 16; r++) acc[i][j][r] = 0.f;

    const unsigned short* apx[2];
    const unsigned short* bpx[2];
    #pragma unroll
    for (int i = 0; i < 2; i++) {
        apx[i] = AfP32     + (long)(at0 + i) * (64 * 512) + lane * 8;
        bpx[i] = WattnP32  + (long)(jt0 + i) * (64 * 512) + lane * 8;
    }
    #pragma unroll 2
    for (int kc = 0; kc < 64; kc++) {
        bf16x8 a[2], b[2];
        #pragma unroll
        for (int i = 0; i < 2; i++) a[i] = *(const bf16x8*)(apx[i] + kc * 512);
        #pragma unroll
        for (int i = 0; i < 2; i++) b[i] = *(const bf16x8*)(bpx[i] + kc * 512);
        #pragma unroll
        for (int i = 0; i < 2; i++)
            #pragma unroll
            for (int j = 0; j < 2; j++)
                acc[i][j] = __builtin_amdgcn_mfma_f32_32x32x16_bf16(a[i], b[j], acc[i][j], 0, 0, 0);
    }
    int col_l = lane & 31, rbase = 4 * (lane >> 5);
    #pragma unroll
    for (int i = 0; i < 2; i++) {
        #pragma unroll
        for (int j = 0; j < 2; j++) {
            int col = (jt0 + j) * 32 + col_l;
            #pragma unroll
            for (int r = 0; r < 16; r++) {
                int grow = (at0 + i) * 32 + (r & 3) + 8 * (r >> 2) + rbase;
                int n = grow >> 4, p = grow & 15;
                AW[((long)n * G4_ + col) * 16 + p] = f2bf(acc[i][j][r]);
            }
        }
    }
}

// actx = xP32 @ WxP32^T via 32x32x16 MFMA. Wave 2x2 tiles (64x64 out).
// grid (64 Mb, 32 jNb). Output actx[m][4096] unchanged.
__global__ __launch_bounds__(256, 2)
void k_actx(const unsigned short* __restrict__ xP32, const unsigned short* __restrict__ WxP32,
            unsigned short* __restrict__ actx) {
    int tid = threadIdx.x;
    int wv = tid >> 6, lane = tid & 63;
    int wr = wv >> 1, wc = wv & 1;
    int at0 = blockIdx.x * 4 + wr * 2;   // M tiles (0..255)
    int jt0 = blockIdx.y * 4 + wc * 2;   // j tiles (0..127)

    f32x16 acc[2][2];
    #pragma unroll
    for (int i = 0; i < 2; i++)
        #pragma unroll
        for (int j = 0; j < 2; j++)
            #pragma unroll
            for (int r = 0; r < 16; r++) acc[i][j][r] = 0.f;

    const unsigned short* apx[2];
    const unsigned short* bpx[2];
    #pragma unroll
    for (int i = 0; i < 2; i++) {
        apx[i] = xP32  + (long)(at0 + i) * (64 * 512) + lane * 8;
        bpx[i] = WxP32 + (long)(jt0 + i) * (64 * 512) + lane * 8;
    }
    #pragma unroll 2
    for (int kc = 0; kc < 64; kc++) {
        bf16x8 a[2], b[2];
        #pragma unroll
        for (int i = 0; i < 2; i++) a[i] = *(const bf16x8*)(apx[i] + kc * 512);
        #pragma unroll
        for (int i = 0; i < 2; i++) b[i] = *(const bf16x8*)(bpx[i] + kc * 512);
        #pragma unroll
        for (int i = 0; i < 2; i++)
            #pragma unroll
            for (int j = 0; j < 2; j++)
                acc[i][j] = __builtin_amdgcn_mfma_f32_32x32x16_bf16(a[i], b[j], acc[i][j], 0, 0, 0);
    }
    int col_l = lane & 31, rbase = 4 * (lane >> 5);
    #pragma unroll
    for (int i = 0; i < 2; i++) {
        #pragma unroll
        for (int j = 0; j < 2; j++) {
            int col = (jt0 + j) * 32 + col_l;
            #pragma unroll
            for (int r = 0; r < 16; r++) {
                long m = (long)(at0 + i) * 32 + (r & 3) + 8 * (r >> 2) + rbase;
                actx[m * G4_ + col] = f2bf(acc[i][j][r]);
            }
        }
    }
}

// ------------------------------------------------------------- per step ----

// k_step: K=1024 h-only GEMM + actx/AW epilogue (R13-proven, verbatim).
__global__ __launch_bounds__(512, 2)
void k_step(const unsigned short* __restrict__ actx,   // bf16 [8192][4096]
            const unsigned short* __restrict__ hPin,   // packed [8 nt][32 kc][64][8]
            unsigned short* __restrict__ hPout,
            const unsigned short* __restrict__ WhP,    // [256 jti][32 kc][64][8]
            const unsigned short* __restrict__ AW,     // [N][4096][16]
            const unsigned short* __restrict__ Af2,    // [N][H][16]
            const float* __restrict__ wbuf,            // [N][16]
            const float* __restrict__ bvec,
            float* __restrict__ c,
            float* __restrict__ partOUT,               // [N][16][64]
            float* __restrict__ out, int t) {
    int tid = threadIdx.x;
    int wv = tid >> 6, lane = tid & 63;
    int ks = wv & 3, rh = wv >> 2;
    int cl = lane & 15, kg = lane >> 4;
    int jt = blockIdx.x;
    int nt2 = blockIdx.y;
    int colbase = jt * 16;

    f32x4 acc[4];
    #pragma unroll
    for (int g = 0; g < 4; g++) acc[g] = (f32x4){0.f, 0.f, 0.f, 0.f};

    const unsigned short* abase = hPin + ((long)(nt2 * 2 + rh) * 32 + ks * 8) * 512 + lane * 8;
    const unsigned short* bb[4];
    #pragma unroll
    for (int g = 0; g < 4; g++)
        bb[g] = WhP + ((long)(g * 64 + jt) * 32 + ks * 8) * 512 + lane * 8;

    #pragma unroll
    for (int i = 0; i < 8; i++) {
        bf16x8 a = *(const bf16x8*)(abase + i * 512);
        #pragma unroll
        for (int g = 0; g < 4; g++) {
            bf16x8 b = *(const bf16x8*)(bb[g] + i * 512);
            acc[g] = __builtin_amdgcn_mfma_f32_16x16x32_bf16(a, b, acc[g], 0, 0, 0);
        }
    }

    __shared__ float red[3][2][64][17];
    __shared__ float act[4][32][17];
    if (ks != 0) {
        #pragma unroll
        for (int g = 0; g < 4; g++)
            #pragma unroll
            for (int v = 0; v < 4; v++) red[ks - 1][rh][lane][g * 4 + v] = acc[g][v];
    }
    __syncthreads();
    if (ks == 0) {
        #pragma unroll
        for (int g = 0; g < 4; g++)
            #pragma unroll
            for (int v = 0; v < 4; v++) {
                float s = acc[g][v] + red[0][rh][lane][g*4+v] + red[1][rh][lane][g*4+v]
                        + red[2][rh][lane][g*4+v];
                act[g][rh * 16 + kg * 4 + v][cl] = s;
            }
    }
    __syncthreads();

    int nloc = tid >> 4, jl = tid & 15;
    int n = nt2 * 32 + nloc, jh = colbase + jl;
    float wv16[16];
    #pragma unroll
    for (int p = 0; p < 16; p++) wv16[p] = wbuf[n * 16 + p];

    long rm = (long)(t * 8 + (n >> 4)) * 16 + (n & 15);
    float s4[4];
    #pragma unroll
    for (int g = 0; g < 4; g++) {
        int j = g * 1024 + jh;
        const unsigned short* awp = AW + ((long)n * G4_ + j) * 16;
        bf16x8 aw0 = *(const bf16x8*)(awp);
        bf16x8 aw1 = *(const bf16x8*)(awp + 8);
        float at = 0.f;
        #pragma unroll
        for (int p = 0; p < 8; p++) at += wv16[p]     * bf2f((unsigned short)aw0[p]);
        #pragma unroll
        for (int p = 0; p < 8; p++) at += wv16[8 + p] * bf2f((unsigned short)aw1[p]);
        s4[g] = act[g][nloc][jl] + bf2f(actx[rm * G4_ + j]) + at + bvec[j];
    }
    float ig = 1.f / (1.f + expf(-s4[0]));
    float fg = 1.f / (1.f + expf(-s4[1]));
    float og = 1.f / (1.f + expf(-s4[2]));
    float gg = tanhf(s4[3]);
    long idx = (long)n * H_ + jh;
    float cn = fg * c[idx] + ig * gg;
    float hn = og * tanhf(cn);
    c[idx] = cn;
    out[((long)n * T_ + t) * H_ + jh] = hn;
    hPout[((long)((n >> 4) * 32 + (jh >> 5)) * 64 + ((jh >> 3) & 3) * 16 + (n & 15)) * 8 + (jh & 7)] = f2bf(hn);

    const unsigned short* afp = Af2 + ((long)n * H_ + jh) * 16;
    bf16x8 af0 = *(const bf16x8*)(afp);
    bf16x8 af1 = *(const bf16x8*)(afp + 8);
    float sp[16];
    #pragma unroll
    for (int p = 0; p < 8; p++) { sp[p]     = hn * bf2f((unsigned short)af0[p]);
                                  sp[8 + p] = hn * bf2f((unsigned short)af1[p]); }
    #pragma unroll
    for (int off = 1; off < 16; off <<= 1) {
        #pragma unroll
        for (int p = 0; p < 16; p++) sp[p] += __shfl_xor(sp[p], off);
    }
    float outv = 0.f;
    #pragma unroll
    for (int p = 0; p < 16; p++) if (jl == p) outv = sp[p];
    partOUT[((long)n * 16 + jl) * 64 + jt] = outv;
}

// ---------------------------------------------------------------- launch ----

extern "C" void kernel_launch(void* const* d_in, const int* in_sizes, int n_in,
                              void* d_out, int out_size, void* d_ws, size_t ws_size,
                              hipStream_t stream) {
    const float* x     = (const float*)d_in[0];
    const float* A     = (const float*)d_in[1];
    const float* Wx    = (const float*)d_in[2];
    const float* Wh    = (const float*)d_in[3];
    const float* Wattn = (const float*)d_in[4];
    const float* b     = (const float*)d_in[5];
    float* out = (float*)d_out;

    char* ws = (char*)d_ws;
    size_t off = 0;
    auto alloc = [&](size_t bytes) -> void* {
        void* p = ws + off;
        off += (bytes + 255) & ~(size_t)255;
        return p;
    };
    unsigned short* xP32   = (unsigned short*)alloc((size_t)256 * 64 * 512 * 2);   // 16.8MB
    unsigned short* WxP32  = (unsigned short*)alloc((size_t)128 * 64 * 512 * 2);   // 8.4MB
    unsigned short* WhP    = (unsigned short*)alloc((size_t)256 * 32 * 512 * 2);   // 8.4MB
    unsigned short* WatP32 = (unsigned short*)alloc((size_t)128 * 64 * 512 * 2);   // 8.4MB
    unsigned short* AfP32  = (unsigned short*)alloc((size_t)64 * 64 * 512 * 2);    // 4.2MB
    unsigned short* Af2    = (unsigned short*)alloc((size_t)N_ * H_ * 16 * 2);     // 4.2MB
    unsigned short* AW     = (unsigned short*)alloc((size_t)N_ * G4_ * 16 * 2);    // 16.8MB
    unsigned short* actx   = (unsigned short*)alloc((size_t)8192 * G4_ * 2);       // 67.1MB
    float*          hbuf   = (float*)alloc((size_t)N_ * H_ * 4);
    float*          cbuf   = (float*)alloc((size_t)N_ * H_ * 4);
    unsigned short* hP0    = (unsigned short*)alloc((size_t)8 * 32 * 512 * 2);
    unsigned short* hP1    = (unsigned short*)alloc((size_t)8 * 32 * 512 * 2);
    float*          part0  = (float*)alloc((size_t)N_ * 16 * 64 * 4);
    float*          part1  = (float*)alloc((size_t)N_ * 16 * 64 * 4);
    float*          wbuf   = (float*)alloc((size_t)N_ * 16 * 4);

    // prep
    k_pack_w32<<<dim3(128, 16), dim3(256), 0, stream>>>(Wx,    WxP32);
    k_pack_w  <<<dim3(128, 16), dim3(256), 0, stream>>>(Wh,    WhP, 0, 32);
    k_pack_w32<<<dim3(128, 16), dim3(256), 0, stream>>>(Wattn, WatP32);
    k_pack_x32<<<dim3(4096), dim3(256), 0, stream>>>(x, xP32);
    k_pack_af32<<<dim3(128, 16), dim3(256), 0, stream>>>(A, AfP32, Af2);
    k_h0<<<dim3(512), dim3(256), 0, stream>>>(A, hbuf, cbuf, hP0);
    k_part0<<<dim3(N_), dim3(512), 0, stream>>>(hbuf, Af2, part0);
    k_aw<<<dim3(16, 32), dim3(256), 0, stream>>>(AfP32, WatP32, AW);
    k_actx<<<dim3(64, 32), dim3(256), 0, stream>>>(xP32, WxP32, actx);

    // recurrence
    for (int t = 0; t < T_; t++) {
        unsigned short* hin  = (t & 1) ? hP1 : hP0;
        unsigned short* hout = (t & 1) ? hP0 : hP1;
        float* pIN  = (t & 1) ? part1 : part0;
        float* pOUT = (t & 1) ? part0 : part1;
        k_score_tiny<<<dim3(N_), dim3(64), 0, stream>>>(pIN, wbuf);
        k_step<<<dim3(64, 4), dim3(512), 0, stream>>>(actx, hin, hout, WhP, AW, Af2,
                                                      wbuf, b, cbuf, pOUT, out, t);
    }
}

// Round 24
// 907.337 us; speedup vs baseline: 1.3242x; 1.1404x over previous
//
#include <hip/hip_runtime.h>
#include <hip/hip_bf16.h>
#include <cmath>

// Problem constants
#define N_   128
#define T_   64
#define D_   1024
#define H_   1024
#define G4_  4096   // 4*H

typedef short bf16x8  __attribute__((ext_vector_type(8)));
typedef float f32x4   __attribute__((ext_vector_type(4)));
typedef float f32x16  __attribute__((ext_vector_type(16)));

__device__ __forceinline__ unsigned short f2bf(float f) {
    union { float f; unsigned int u; } v; v.f = f;
    unsigned int r = (v.u + 0x7FFFu + ((v.u >> 16) & 1u)) >> 16;  // RNE
    return (unsigned short)r;
}
__device__ __forceinline__ float bf2f(unsigned short s) {
    union { unsigned int u; float f; } v; v.u = ((unsigned int)s) << 16;
    return v.f;
}

// 16-row fragment packing (mfma_f32_16x16x32_bf16, lane = kg*16+cl):
//   P[tile][kc32][lane][8] ; fragment load = base + lane*8 -> 1KB contiguous.
// 32-row fragment packing (mfma_f32_32x32x16_bf16, lane = kgrp*32+row):
//   P32[tile32][kc16][lane][8] ; row = lane&31, k = (lane>>5)*8 + e.
//   C/D: col = lane&31, row = (reg&3) + 8*(reg>>2) + 4*(lane>>5).
// Score partials: tiny [128][16] accumulator, atomicAdd from k_step epilogue;
// 3-buffer rotation (read t%3 / acc (t+1)%3 / zero (t+2)%3).

// ---------------------------------------------------------------- prep ----

// 16-row pack (WhP only): src f32 [1024][4096] k-major -> P[jti][kc][64][8].
__global__ void k_pack_w(const float* __restrict__ src, unsigned short* __restrict__ dst,
                         int kcoff, int kctot) {
    __shared__ float ld[64][33];
    int j0 = blockIdx.x * 32, k0 = blockIdx.y * 64;
    int tid = threadIdx.x;
    int c = tid & 31, r = tid >> 5;
    #pragma unroll
    for (int i = 0; i < 8; i++)
        ld[r + i * 8][c] = src[(long)(k0 + r + i * 8) * G4_ + j0 + c];
    __syncthreads();
    int j = tid & 31, ku = tid >> 5;
    int kcl = ku >> 2, kg = ku & 3;
    int jti = (j0 + j) >> 4, cl = (j0 + j) & 15;
    int kc = kcoff + (k0 >> 5) + kcl;
    unsigned short q[8];
    #pragma unroll
    for (int e = 0; e < 8; e++) q[e] = f2bf(ld[ku * 8 + e][j]);
    *(uint4*)(dst + ((long)(jti * kctot + kc) * 64 + kg * 16 + cl) * 8) = *(uint4*)q;
}

// 32-row pack: src f32 [1024][4096] k-major -> P32[j>>5][kc16][64][8].
__global__ void k_pack_w32(const float* __restrict__ src, unsigned short* __restrict__ dst) {
    __shared__ float ld[64][33];
    int j0 = blockIdx.x * 32, k0 = blockIdx.y * 64;
    int tid = threadIdx.x;
    int c = tid & 31, r = tid >> 5;
    #pragma unroll
    for (int i = 0; i < 8; i++)
        ld[r + i * 8][c] = src[(long)(k0 + r + i * 8) * G4_ + j0 + c];
    __syncthreads();
    int cl = tid & 31, kgrp = (tid >> 5) & 1, kcl = tid >> 6;   // kcl 0..3
    int kc = (k0 >> 4) + kcl;
    unsigned short q[8];
    #pragma unroll
    for (int e = 0; e < 8; e++) q[e] = f2bf(ld[kcl * 16 + kgrp * 8 + e][cl]);
    *(uint4*)(dst + (((long)blockIdx.x * 64 + kc) * 64 + kgrp * 32 + cl) * 8) = *(uint4*)q;
}

// x f32 [N][T][D] -> xP32 rows m = t*128+n: tile32 = t*4 + (n>>5), row = n&31.
__global__ void k_pack_x32(const float* __restrict__ x, unsigned short* __restrict__ xP32) {
    long gid = (long)blockIdx.x * 256 + threadIdx.x;   // 8192*128
    int mm = (int)(gid >> 7), u = (int)(gid & 127);
    const float* src = x + (long)mm * 1024 + u * 8;
    int n = mm >> 6, t = mm & 63;
    int tile = t * 4 + (n >> 5);
    int row = n & 31;
    int kc = u >> 1, kgrp = u & 1;
    float4 a = *(const float4*)src, b = *(const float4*)(src + 4);
    unsigned short q[8] = {f2bf(a.x), f2bf(a.y), f2bf(a.z), f2bf(a.w),
                           f2bf(b.x), f2bf(b.y), f2bf(b.z), f2bf(b.w)};
    *(uint4*)(xP32 + (((long)tile * 64 + kc) * 64 + kgrp * 32 + row) * 8) = *(uint4*)q;
}

// A f32 [N][H][16] -> AfP32 (rows = n*16+p: tile = n>>1, row = (n&1)*16+p) + Af2.
__global__ void k_pack_af32(const float* __restrict__ A, unsigned short* __restrict__ AfP32,
                            unsigned short* __restrict__ Af2) {
    __shared__ float ld[64][17];
    int n = blockIdx.x, h0 = blockIdx.y * 64;
    int tid = threadIdx.x;
    int hh = tid >> 2, pq = tid & 3;
    float4 v = *(const float4*)(A + ((long)n * H_ + h0 + hh) * 16 + pq * 4);
    unsigned short o[4] = {f2bf(v.x), f2bf(v.y), f2bf(v.z), f2bf(v.w)};
    *(uint2*)(Af2 + ((long)n * H_ + h0 + hh) * 16 + pq * 4) = *(uint2*)o;
    ld[hh][pq * 4 + 0] = v.x; ld[hh][pq * 4 + 1] = v.y;
    ld[hh][pq * 4 + 2] = v.z; ld[hh][pq * 4 + 3] = v.w;
    __syncthreads();
    if (tid < 128) {
        int p = tid >> 3, ku = tid & 7;
        int kc = (h0 >> 4) + (ku >> 1), kgrp = ku & 1;
        int row = (n & 1) * 16 + p;
        unsigned short q[8];
        #pragma unroll
        for (int e = 0; e < 8; e++) q[e] = f2bf(ld[ku * 8 + e][p]);
        *(uint4*)(AfP32 + (((long)(n >> 1) * 64 + kc) * 64 + kgrp * 32 + row) * 8) = *(uint4*)q;
    }
}

// h0 = mean_p A; c0 = h0; packed h0.
__global__ void k_h0(const float* __restrict__ A, float* __restrict__ h,
                     float* __restrict__ c, unsigned short* __restrict__ hP0) {
    long id = (long)blockIdx.x * 256 + threadIdx.x;
    const float4* ap = (const float4*)(A + id * 16);
    float s = 0.f;
    #pragma unroll
    for (int q = 0; q < 4; q++) { float4 v = ap[q]; s += v.x + v.y + v.z + v.w; }
    float m = s * (1.0f / 16.0f);
    h[id] = m; c[id] = m;
    int n = (int)(id >> 10), j = (int)(id & 1023);
    hP0[((long)((n >> 4) * 32 + (j >> 5)) * 64 + ((j >> 3) & 3) * 16 + (n & 15)) * 8 + (j & 7)] = f2bf(m);
}

// t=0 score partials (per-jt scratch)
__global__ __launch_bounds__(512)
void k_part0(const float* __restrict__ hbuf, const unsigned short* __restrict__ Af2,
             float* __restrict__ partial0) {
    int n = blockIdx.x;
    int tid = threadIdx.x;
    int jh = tid * 2;
    float sp[16];
    #pragma unroll
    for (int p = 0; p < 16; p++) sp[p] = 0.f;
    #pragma unroll
    for (int u = 0; u < 2; u++) {
        float hv = hbuf[(long)n * H_ + jh + u];
        const unsigned short* afp = Af2 + ((long)n * H_ + jh + u) * 16;
        bf16x8 a0 = *(const bf16x8*)(afp);
        bf16x8 a1 = *(const bf16x8*)(afp + 8);
        #pragma unroll
        for (int p = 0; p < 8; p++) { sp[p] += hv * bf2f((unsigned short)a0[p]);
                                      sp[8+p] += hv * bf2f((unsigned short)a1[p]); }
    }
    #pragma unroll
    for (int off = 1; off < 8; off <<= 1) {
        #pragma unroll
        for (int p = 0; p < 16; p++) sp[p] += __shfl_xor(sp[p], off);
    }
    int jt = tid >> 3;
    if ((tid & 7) == 0) {
        #pragma unroll
        for (int p = 0; p < 16; p++)
            partial0[((long)n * 16 + p) * 64 + jt] = sp[p];
    }
}

// prep: reduce scratch -> pbuf0 raw sums [128][16]
__global__ __launch_bounds__(64)
void k_red0(const float* __restrict__ partial, float* __restrict__ p0) {
    int n = blockIdx.x;
    int lane = threadIdx.x;
    int p = lane & 15, c4 = lane >> 4;
    const float* src = partial + ((long)n * 16 + p) * 64 + c4 * 16;
    float s = 0.f;
    #pragma unroll
    for (int q = 0; q < 16; q++) s += src[q];
    s += __shfl_xor(s, 16);
    s += __shfl_xor(s, 32);
    if (c4 == 0) p0[n * 16 + p] = s;
}

__global__ void k_zerobuf(float* __restrict__ p) {
    p[blockIdx.x * 1024 + threadIdx.x] = 0.f;
}

// AW = AfP32 @ WattnP32^T via 32x32x16 MFMA (R23-proven).
__global__ __launch_bounds__(256, 2)
void k_aw(const unsigned short* __restrict__ AfP32, const unsigned short* __restrict__ WattnP32,
          unsigned short* __restrict__ AW) {
    int tid = threadIdx.x;
    int wv = tid >> 6, lane = tid & 63;
    int wr = wv >> 1, wc = wv & 1;
    int at0 = blockIdx.x * 4 + wr * 2;
    int jt0 = blockIdx.y * 4 + wc * 2;

    f32x16 acc[2][2];
    #pragma unroll
    for (int i = 0; i < 2; i++)
        #pragma unroll
        for (int j = 0; j < 2; j++)
            #pragma unroll
            for (int r = 0; r < 16; r++) acc[i][j][r] = 0.f;

    const unsigned short* apx[2];
    const unsigned short* bpx[2];
    #pragma unroll
    for (int i = 0; i < 2; i++) {
        apx[i] = AfP32     + (long)(at0 + i) * (64 * 512) + lane * 8;
        bpx[i] = WattnP32  + (long)(jt0 + i) * (64 * 512) + lane * 8;
    }
    #pragma unroll 2
    for (int kc = 0; kc < 64; kc++) {
        bf16x8 a[2], b[2];
        #pragma unroll
        for (int i = 0; i < 2; i++) a[i] = *(const bf16x8*)(apx[i] + kc * 512);
        #pragma unroll
        for (int i = 0; i < 2; i++) b[i] = *(const bf16x8*)(bpx[i] + kc * 512);
        #pragma unroll
        for (int i = 0; i < 2; i++)
            #pragma unroll
            for (int j = 0; j < 2; j++)
                acc[i][j] = __builtin_amdgcn_mfma_f32_32x32x16_bf16(a[i], b[j], acc[i][j], 0, 0, 0);
    }
    int col_l = lane & 31, rbase = 4 * (lane >> 5);
    #pragma unroll
    for (int i = 0; i < 2; i++) {
        #pragma unroll
        for (int j = 0; j < 2; j++) {
            int col = (jt0 + j) * 32 + col_l;
            #pragma unroll
            for (int r = 0; r < 16; r++) {
                int grow = (at0 + i) * 32 + (r & 3) + 8 * (r >> 2) + rbase;
                int n = grow >> 4, p = grow & 15;
                AW[((long)n * G4_ + col) * 16 + p] = f2bf(acc[i][j][r]);
            }
        }
    }
}

// actx = xP32 @ WxP32^T via 32x32x16 MFMA (R23-proven).
__global__ __launch_bounds__(256, 2)
void k_actx(const unsigned short* __restrict__ xP32, const unsigned short* __restrict__ WxP32,
            unsigned short* __restrict__ actx) {
    int tid = threadIdx.x;
    int wv = tid >> 6, lane = tid & 63;
    int wr = wv >> 1, wc = wv & 1;
    int at0 = blockIdx.x * 4 + wr * 2;
    int jt0 = blockIdx.y * 4 + wc * 2;

    f32x16 acc[2][2];
    #pragma unroll
    for (int i = 0; i < 2; i++)
        #pragma unroll
        for (int j = 0; j < 2; j++)
            #pragma unroll
            for (int r = 0; r < 16; r++) acc[i][j][r] = 0.f;

    const unsigned short* apx[2];
    const unsigned short* bpx[2];
    #pragma unroll
    for (int i = 0; i < 2; i++) {
        apx[i] = xP32  + (long)(at0 + i) * (64 * 512) + lane * 8;
        bpx[i] = WxP32 + (long)(jt0 + i) * (64 * 512) + lane * 8;
    }
    #pragma unroll 2
    for (int kc = 0; kc < 64; kc++) {
        bf16x8 a[2], b[2];
        #pragma unroll
        for (int i = 0; i < 2; i++) a[i] = *(const bf16x8*)(apx[i] + kc * 512);
        #pragma unroll
        for (int i = 0; i < 2; i++) b[i] = *(const bf16x8*)(bpx[i] + kc * 512);
        #pragma unroll
        for (int i = 0; i < 2; i++)
            #pragma unroll
            for (int j = 0; j < 2; j++)
                acc[i][j] = __builtin_amdgcn_mfma_f32_32x32x16_bf16(a[i], b[j], acc[i][j], 0, 0, 0);
    }
    int col_l = lane & 31, rbase = 4 * (lane >> 5);
    #pragma unroll
    for (int i = 0; i < 2; i++) {
        #pragma unroll
        for (int j = 0; j < 2; j++) {
            int col = (jt0 + j) * 32 + col_l;
            #pragma unroll
            for (int r = 0; r < 16; r++) {
                long m = (long)(at0 + i) * 32 + (r & 3) + 8 * (r >> 2) + rbase;
                actx[m * G4_ + col] = f2bf(acc[i][j][r]);
            }
        }
    }
}

// ------------------------------------------------------------- per step ----

// ONE kernel per step. Front: softmax w from reduced pRead (1 load + shuffles)
// + jt==0 blocks zero pZero. GEMM + epilogue: R13/R23-proven; score partial
// via one atomicAdd per thread into pAcc. grid (64 jt, 4 nt2), 512 thr.
__global__ __launch_bounds__(512, 2)
void k_step(const unsigned short* __restrict__ actx,   // bf16 [8192][4096]
            const unsigned short* __restrict__ hPin,
            unsigned short* __restrict__ hPout,
            const unsigned short* __restrict__ WhP,    // [256 jti][32 kc][64][8]
            const unsigned short* __restrict__ AW,     // [N][4096][16]
            const unsigned short* __restrict__ Af2,    // [N][H][16]
            const float* __restrict__ pRead,           // [128][16] raw sums
            float* __restrict__ pAcc,                  // [128][16] atomic target
            float* __restrict__ pZero,                 // [128][16] zero duty
            const float* __restrict__ bvec,
            float* __restrict__ c,
            float* __restrict__ out, int t) {
    int tid = threadIdx.x;
    int wv = tid >> 6, lane = tid & 63;
    int ks = wv & 3, rh = wv >> 2;
    int cl = lane & 15, kg = lane >> 4;
    int jt = blockIdx.x;
    int nt2 = blockIdx.y;
    int colbase = jt * 16;

    __shared__ float red[3][2][64][17];
    __shared__ float act[4][32][17];
    __shared__ float wsm[32][17];

    // ---- front: softmax w for (nloc, jl) from reduced partials ----
    {
        int nloc_f = tid >> 4, jl_f = tid & 15;
        int n_f = nt2 * 32 + nloc_f;
        float s = pRead[n_f * 16 + jl_f] * (1.0f / 32.0f);   // /sqrt(H)
        float m = s;
        #pragma unroll
        for (int off = 1; off < 16; off <<= 1) m = fmaxf(m, __shfl_xor(m, off));
        float e = expf(s - m);
        float sum = e;
        #pragma unroll
        for (int off = 1; off < 16; off <<= 1) sum += __shfl_xor(sum, off);
        wsm[nloc_f][jl_f] = e / sum;
        if (jt == 0) pZero[nt2 * 512 + tid] = 0.f;
    }

    // ---- GEMM: 16 rows (rh half) x 16 jh x 4 gates over K=256 (8 kc) ----
    f32x4 acc[4];
    #pragma unroll
    for (int g = 0; g < 4; g++) acc[g] = (f32x4){0.f, 0.f, 0.f, 0.f};

    const unsigned short* abase = hPin + ((long)(nt2 * 2 + rh) * 32 + ks * 8) * 512 + lane * 8;
    const unsigned short* bb[4];
    #pragma unroll
    for (int g = 0; g < 4; g++)
        bb[g] = WhP + ((long)(g * 64 + jt) * 32 + ks * 8) * 512 + lane * 8;

    #pragma unroll
    for (int i = 0; i < 8; i++) {
        bf16x8 a = *(const bf16x8*)(abase + i * 512);
        #pragma unroll
        for (int g = 0; g < 4; g++) {
            bf16x8 b = *(const bf16x8*)(bb[g] + i * 512);
            acc[g] = __builtin_amdgcn_mfma_f32_16x16x32_bf16(a, b, acc[g], 0, 0, 0);
        }
    }

    // ---- 4-way K reduce per rh ----
    if (ks != 0) {
        #pragma unroll
        for (int g = 0; g < 4; g++)
            #pragma unroll
            for (int v = 0; v < 4; v++) red[ks - 1][rh][lane][g * 4 + v] = acc[g][v];
    }
    __syncthreads();
    if (ks == 0) {
        #pragma unroll
        for (int g = 0; g < 4; g++)
            #pragma unroll
            for (int v = 0; v < 4; v++) {
                float s = acc[g][v] + red[0][rh][lane][g*4+v] + red[1][rh][lane][g*4+v]
                        + red[2][rh][lane][g*4+v];
                act[g][rh * 16 + kg * 4 + v][cl] = s;   // C/D row = 4*kg + v
            }
    }
    __syncthreads();

    // ---- epilogue: 512 thr x 1 (n, jh) cell ----
    int nloc = tid >> 4, jl = tid & 15;
    int n = nt2 * 32 + nloc, jh = colbase + jl;
    float wv16[16];
    #pragma unroll
    for (int p = 0; p < 16; p++) wv16[p] = wsm[nloc][p];

    long rm = (long)(t * 8 + (n >> 4)) * 16 + (n & 15);   // actx row
    float s4[4];
    #pragma unroll
    for (int g = 0; g < 4; g++) {
        int j = g * 1024 + jh;
        const unsigned short* awp = AW + ((long)n * G4_ + j) * 16;
        bf16x8 aw0 = *(const bf16x8*)(awp);
        bf16x8 aw1 = *(const bf16x8*)(awp + 8);
        float at = 0.f;
        #pragma unroll
        for (int p = 0; p < 8; p++) at += wv16[p]     * bf2f((unsigned short)aw0[p]);
        #pragma unroll
        for (int p = 0; p < 8; p++) at += wv16[8 + p] * bf2f((unsigned short)aw1[p]);
        s4[g] = act[g][nloc][jl] + bf2f(actx[rm * G4_ + j]) + at + bvec[j];
    }
    float ig = 1.f / (1.f + expf(-s4[0]));
    float fg = 1.f / (1.f + expf(-s4[1]));
    float og = 1.f / (1.f + expf(-s4[2]));
    float gg = tanhf(s4[3]);
    long idx = (long)n * H_ + jh;
    float cn = fg * c[idx] + ig * gg;
    float hn = og * tanhf(cn);
    c[idx] = cn;
    out[((long)n * T_ + t) * H_ + jh] = hn;
    hPout[((long)((n >> 4) * 32 + (jh >> 5)) * 64 + ((jh >> 3) & 3) * 16 + (n & 15)) * 8 + (jh & 7)] = f2bf(hn);

    // score partials for t+1: 16-lane reduce then ONE atomicAdd per thread
    const unsigned short* afp = Af2 + ((long)n * H_ + jh) * 16;
    bf16x8 af0 = *(const bf16x8*)(afp);
    bf16x8 af1 = *(const bf16x8*)(afp + 8);
    float sp[16];
    #pragma unroll
    for (int p = 0; p < 8; p++) { sp[p]     = hn * bf2f((unsigned short)af0[p]);
                                  sp[8 + p] = hn * bf2f((unsigned short)af1[p]); }
    #pragma unroll
    for (int off = 1; off < 16; off <<= 1) {
        #pragma unroll
        for (int p = 0; p < 16; p++) sp[p] += __shfl_xor(sp[p], off);
    }
    float outv = 0.f;
    #pragma unroll
    for (int p = 0; p < 16; p++) if (jl == p) outv = sp[p];
    atomicAdd(&pAcc[n * 16 + jl], outv);
}

// ---------------------------------------------------------------- launch ----

extern "C" void kernel_launch(void* const* d_in, const int* in_sizes, int n_in,
                              void* d_out, int out_size, void* d_ws, size_t ws_size,
                              hipStream_t stream) {
    const float* x     = (const float*)d_in[0];
    const float* A     = (const float*)d_in[1];
    const float* Wx    = (const float*)d_in[2];
    const float* Wh    = (const float*)d_in[3];
    const float* Wattn = (const float*)d_in[4];
    const float* b     = (const float*)d_in[5];
    float* out = (float*)d_out;

    char* ws = (char*)d_ws;
    size_t off = 0;
    auto alloc = [&](size_t bytes) -> void* {
        void* p = ws + off;
        off += (bytes + 255) & ~(size_t)255;
        return p;
    };
    unsigned short* xP32   = (unsigned short*)alloc((size_t)256 * 64 * 512 * 2);   // 16.8MB
    unsigned short* WxP32  = (unsigned short*)alloc((size_t)128 * 64 * 512 * 2);   // 8.4MB
    unsigned short* WhP    = (unsigned short*)alloc((size_t)256 * 32 * 512 * 2);   // 8.4MB
    unsigned short* WatP32 = (unsigned short*)alloc((size_t)128 * 64 * 512 * 2);   // 8.4MB
    unsigned short* AfP32  = (unsigned short*)alloc((size_t)64 * 64 * 512 * 2);    // 4.2MB
    unsigned short* Af2    = (unsigned short*)alloc((size_t)N_ * H_ * 16 * 2);     // 4.2MB
    unsigned short* AW     = (unsigned short*)alloc((size_t)N_ * G4_ * 16 * 2);    // 16.8MB
    unsigned short* actx   = (unsigned short*)alloc((size_t)8192 * G4_ * 2);       // 67.1MB
    float*          hbuf   = (float*)alloc((size_t)N_ * H_ * 4);
    float*          cbuf   = (float*)alloc((size_t)N_ * H_ * 4);
    unsigned short* hP0    = (unsigned short*)alloc((size_t)8 * 32 * 512 * 2);
    unsigned short* hP1    = (unsigned short*)alloc((size_t)8 * 32 * 512 * 2);
    float*          scr    = (float*)alloc((size_t)N_ * 16 * 64 * 4);
    float*          pb     = (float*)alloc((size_t)3 * N_ * 16 * 4);   // 3 x [128][16]

    // prep
    k_pack_w32<<<dim3(128, 16), dim3(256), 0, stream>>>(Wx,    WxP32);
    k_pack_w  <<<dim3(128, 16), dim3(256), 0, stream>>>(Wh,    WhP, 0, 32);
    k_pack_w32<<<dim3(128, 16), dim3(256), 0, stream>>>(Wattn, WatP32);
    k_pack_x32<<<dim3(4096), dim3(256), 0, stream>>>(x, xP32);
    k_pack_af32<<<dim3(128, 16), dim3(256), 0, stream>>>(A, AfP32, Af2);
    k_h0<<<dim3(512), dim3(256), 0, stream>>>(A, hbuf, cbuf, hP0);
    k_part0<<<dim3(N_), dim3(512), 0, stream>>>(hbuf, Af2, scr);
    k_red0<<<dim3(N_), dim3(64), 0, stream>>>(scr, pb);            // pb[0] = sums
    k_zerobuf<<<dim3(4), dim3(1024), 0, stream>>>(pb + 2048);      // pb[1], pb[2] = 0
    k_aw<<<dim3(16, 32), dim3(256), 0, stream>>>(AfP32, WatP32, AW);
    k_actx<<<dim3(64, 32), dim3(256), 0, stream>>>(xP32, WxP32, actx);

    // recurrence: ONE kernel per step; 3-buffer score-partial rotation
    for (int t = 0; t < T_; t++) {
        unsigned short* hin  = (t & 1) ? hP1 : hP0;
        unsigned short* hout = (t & 1) ? hP0 : hP1;
        float* pRead = pb + (t % 3) * 2048;
        float* pAcc  = pb + ((t + 1) % 3) * 2048;
        float* pZero = pb + ((t + 2) % 3) * 2048;
        k_step<<<dim3(64, 4), dim3(512), 0, stream>>>(actx, hin, hout, WhP, AW, Af2,
                                                      pRead, pAcc, pZero, b, cbuf, out, t);
    }
}

// Round 25
// 905.236 us; speedup vs baseline: 1.3273x; 1.0023x over previous
//
#include <hip/hip_runtime.h>
#include <hip/hip_bf16.h>
#include <cmath>

// Problem constants
#define N_   128
#define T_   64
#define D_   1024
#define H_   1024
#define G4_  4096   // 4*H

typedef short bf16x8  __attribute__((ext_vector_type(8)));
typedef float f32x4   __attribute__((ext_vector_type(4)));
typedef float f32x16  __attribute__((ext_vector_type(16)));

__device__ __forceinline__ unsigned short f2bf(float f) {
    union { float f; unsigned int u; } v; v.f = f;
    unsigned int r = (v.u + 0x7FFFu + ((v.u >> 16) & 1u)) >> 16;  // RNE
    return (unsigned short)r;
}
__device__ __forceinline__ float bf2f(unsigned short s) {
    union { unsigned int u; float f; } v; v.u = ((unsigned int)s) << 16;
    return v.f;
}

// 16-row fragment packing (mfma_f32_16x16x32_bf16, lane = kg*16+cl):
//   P[tile][kc32][lane][8] ; fragment load = base + lane*8 -> 1KB contiguous.
// 32-row fragment packing (mfma_f32_32x32x16_bf16, lane = kgrp*32+row):
//   P32[tile32][kc16][lane][8] ; row = lane&31, k = (lane>>5)*8 + e.
//   C/D: col = lane&31, row = (reg&3) + 8*(reg>>2) + 4*(lane>>5).
// Score partials: tiny [128][16] accumulator, atomicAdd from k_step epilogue;
// 3-buffer rotation (read t%3 / acc (t+1)%3 / zero (t+2)%3).

// ---------------------------------------------------------------- prep ----

// 16-row pack (WhP only): src f32 [1024][4096] k-major -> P[jti][kc][64][8].
__global__ void k_pack_w(const float* __restrict__ src, unsigned short* __restrict__ dst,
                         int kcoff, int kctot) {
    __shared__ float ld[64][33];
    int j0 = blockIdx.x * 32, k0 = blockIdx.y * 64;
    int tid = threadIdx.x;
    int c = tid & 31, r = tid >> 5;
    #pragma unroll
    for (int i = 0; i < 8; i++)
        ld[r + i * 8][c] = src[(long)(k0 + r + i * 8) * G4_ + j0 + c];
    __syncthreads();
    int j = tid & 31, ku = tid >> 5;
    int kcl = ku >> 2, kg = ku & 3;
    int jti = (j0 + j) >> 4, cl = (j0 + j) & 15;
    int kc = kcoff + (k0 >> 5) + kcl;
    unsigned short q[8];
    #pragma unroll
    for (int e = 0; e < 8; e++) q[e] = f2bf(ld[ku * 8 + e][j]);
    *(uint4*)(dst + ((long)(jti * kctot + kc) * 64 + kg * 16 + cl) * 8) = *(uint4*)q;
}

// 32-row pack: src f32 [1024][4096] k-major -> P32[j>>5][kc16][64][8].
__global__ void k_pack_w32(const float* __restrict__ src, unsigned short* __restrict__ dst) {
    __shared__ float ld[64][33];
    int j0 = blockIdx.x * 32, k0 = blockIdx.y * 64;
    int tid = threadIdx.x;
    int c = tid & 31, r = tid >> 5;
    #pragma unroll
    for (int i = 0; i < 8; i++)
        ld[r + i * 8][c] = src[(long)(k0 + r + i * 8) * G4_ + j0 + c];
    __syncthreads();
    int cl = tid & 31, kgrp = (tid >> 5) & 1, kcl = tid >> 6;   // kcl 0..3
    int kc = (k0 >> 4) + kcl;
    unsigned short q[8];
    #pragma unroll
    for (int e = 0; e < 8; e++) q[e] = f2bf(ld[kcl * 16 + kgrp * 8 + e][cl]);
    *(uint4*)(dst + (((long)blockIdx.x * 64 + kc) * 64 + kgrp * 32 + cl) * 8) = *(uint4*)q;
}

// x f32 [N][T][D] -> xP32 rows m = t*128+n: tile32 = t*4 + (n>>5), row = n&31.
__global__ void k_pack_x32(const float* __restrict__ x, unsigned short* __restrict__ xP32) {
    long gid = (long)blockIdx.x * 256 + threadIdx.x;   // 8192*128
    int mm = (int)(gid >> 7), u = (int)(gid & 127);
    const float* src = x + (long)mm * 1024 + u * 8;
    int n = mm >> 6, t = mm & 63;
    int tile = t * 4 + (n >> 5);
    int row = n & 31;
    int kc = u >> 1, kgrp = u & 1;
    float4 a = *(const float4*)src, b = *(const float4*)(src + 4);
    unsigned short q[8] = {f2bf(a.x), f2bf(a.y), f2bf(a.z), f2bf(a.w),
                           f2bf(b.x), f2bf(b.y), f2bf(b.z), f2bf(b.w)};
    *(uint4*)(xP32 + (((long)tile * 64 + kc) * 64 + kgrp * 32 + row) * 8) = *(uint4*)q;
}

// A f32 [N][H][16] -> AfP32 (rows = n*16+p: tile = n>>1, row = (n&1)*16+p) + Af2.
__global__ void k_pack_af32(const float* __restrict__ A, unsigned short* __restrict__ AfP32,
                            unsigned short* __restrict__ Af2) {
    __shared__ float ld[64][17];
    int n = blockIdx.x, h0 = blockIdx.y * 64;
    int tid = threadIdx.x;
    int hh = tid >> 2, pq = tid & 3;
    float4 v = *(const float4*)(A + ((long)n * H_ + h0 + hh) * 16 + pq * 4);
    unsigned short o[4] = {f2bf(v.x), f2bf(v.y), f2bf(v.z), f2bf(v.w)};
    *(uint2*)(Af2 + ((long)n * H_ + h0 + hh) * 16 + pq * 4) = *(uint2*)o;
    ld[hh][pq * 4 + 0] = v.x; ld[hh][pq * 4 + 1] = v.y;
    ld[hh][pq * 4 + 2] = v.z; ld[hh][pq * 4 + 3] = v.w;
    __syncthreads();
    if (tid < 128) {
        int p = tid >> 3, ku = tid & 7;
        int kc = (h0 >> 4) + (ku >> 1), kgrp = ku & 1;
        int row = (n & 1) * 16 + p;
        unsigned short q[8];
        #pragma unroll
        for (int e = 0; e < 8; e++) q[e] = f2bf(ld[ku * 8 + e][p]);
        *(uint4*)(AfP32 + (((long)(n >> 1) * 64 + kc) * 64 + kgrp * 32 + row) * 8) = *(uint4*)q;
    }
}

// h0 = mean_p A; c0 = h0; packed h0.
__global__ void k_h0(const float* __restrict__ A, float* __restrict__ h,
                     float* __restrict__ c, unsigned short* __restrict__ hP0) {
    long id = (long)blockIdx.x * 256 + threadIdx.x;
    const float4* ap = (const float4*)(A + id * 16);
    float s = 0.f;
    #pragma unroll
    for (int q = 0; q < 4; q++) { float4 v = ap[q]; s += v.x + v.y + v.z + v.w; }
    float m = s * (1.0f / 16.0f);
    h[id] = m; c[id] = m;
    int n = (int)(id >> 10), j = (int)(id & 1023);
    hP0[((long)((n >> 4) * 32 + (j >> 5)) * 64 + ((j >> 3) & 3) * 16 + (n & 15)) * 8 + (j & 7)] = f2bf(m);
}

// t=0 score partials (per-jt scratch)
__global__ __launch_bounds__(512)
void k_part0(const float* __restrict__ hbuf, const unsigned short* __restrict__ Af2,
             float* __restrict__ partial0) {
    int n = blockIdx.x;
    int tid = threadIdx.x;
    int jh = tid * 2;
    float sp[16];
    #pragma unroll
    for (int p = 0; p < 16; p++) sp[p] = 0.f;
    #pragma unroll
    for (int u = 0; u < 2; u++) {
        float hv = hbuf[(long)n * H_ + jh + u];
        const unsigned short* afp = Af2 + ((long)n * H_ + jh + u) * 16;
        bf16x8 a0 = *(const bf16x8*)(afp);
        bf16x8 a1 = *(const bf16x8*)(afp + 8);
        #pragma unroll
        for (int p = 0; p < 8; p++) { sp[p] += hv * bf2f((unsigned short)a0[p]);
                                      sp[8+p] += hv * bf2f((unsigned short)a1[p]); }
    }
    #pragma unroll
    for (int off = 1; off < 8; off <<= 1) {
        #pragma unroll
        for (int p = 0; p < 16; p++) sp[p] += __shfl_xor(sp[p], off);
    }
    int jt = tid >> 3;
    if ((tid & 7) == 0) {
        #pragma unroll
        for (int p = 0; p < 16; p++)
            partial0[((long)n * 16 + p) * 64 + jt] = sp[p];
    }
}

// prep: reduce scratch -> pbuf0 raw sums [128][16]
__global__ __launch_bounds__(64)
void k_red0(const float* __restrict__ partial, float* __restrict__ p0) {
    int n = blockIdx.x;
    int lane = threadIdx.x;
    int p = lane & 15, c4 = lane >> 4;
    const float* src = partial + ((long)n * 16 + p) * 64 + c4 * 16;
    float s = 0.f;
    #pragma unroll
    for (int q = 0; q < 16; q++) s += src[q];
    s += __shfl_xor(s, 16);
    s += __shfl_xor(s, 32);
    if (c4 == 0) p0[n * 16 + p] = s;
}

__global__ void k_zerobuf(float* __restrict__ p) {
    p[blockIdx.x * 1024 + threadIdx.x] = 0.f;
}

// AW = AfP32 @ WattnP32^T via 32x32x16 MFMA (R23-proven).
__global__ __launch_bounds__(256, 2)
void k_aw(const unsigned short* __restrict__ AfP32, const unsigned short* __restrict__ WattnP32,
          unsigned short* __restrict__ AW) {
    int tid = threadIdx.x;
    int wv = tid >> 6, lane = tid & 63;
    int wr = wv >> 1, wc = wv & 1;
    int at0 = blockIdx.x * 4 + wr * 2;
    int jt0 = blockIdx.y * 4 + wc * 2;

    f32x16 acc[2][2];
    #pragma unroll
    for (int i = 0; i < 2; i++)
        #pragma unroll
        for (int j = 0; j < 2; j++)
            #pragma unroll
            for (int r = 0; r < 16; r++) acc[i][j][r] = 0.f;

    const unsigned short* apx[2];
    const unsigned short* bpx[2];
    #pragma unroll
    for (int i = 0; i < 2; i++) {
        apx[i] = AfP32     + (long)(at0 + i) * (64 * 512) + lane * 8;
        bpx[i] = WattnP32  + (long)(jt0 + i) * (64 * 512) + lane * 8;
    }
    #pragma unroll 2
    for (int kc = 0; kc < 64; kc++) {
        bf16x8 a[2], b[2];
        #pragma unroll
        for (int i = 0; i < 2; i++) a[i] = *(const bf16x8*)(apx[i] + kc * 512);
        #pragma unroll
        for (int i = 0; i < 2; i++) b[i] = *(const bf16x8*)(bpx[i] + kc * 512);
        #pragma unroll
        for (int i = 0; i < 2; i++)
            #pragma unroll
            for (int j = 0; j < 2; j++)
                acc[i][j] = __builtin_amdgcn_mfma_f32_32x32x16_bf16(a[i], b[j], acc[i][j], 0, 0, 0);
    }
    int col_l = lane & 31, rbase = 4 * (lane >> 5);
    #pragma unroll
    for (int i = 0; i < 2; i++) {
        #pragma unroll
        for (int j = 0; j < 2; j++) {
            int col = (jt0 + j) * 32 + col_l;
            #pragma unroll
            for (int r = 0; r < 16; r++) {
                int grow = (at0 + i) * 32 + (r & 3) + 8 * (r >> 2) + rbase;
                int n = grow >> 4, p = grow & 15;
                AW[((long)n * G4_ + col) * 16 + p] = f2bf(acc[i][j][r]);
            }
        }
    }
}

// actx = xP32 @ WxP32^T via 32x32x16 MFMA (R23-proven).
__global__ __launch_bounds__(256, 2)
void k_actx(const unsigned short* __restrict__ xP32, const unsigned short* __restrict__ WxP32,
            unsigned short* __restrict__ actx) {
    int tid = threadIdx.x;
    int wv = tid >> 6, lane = tid & 63;
    int wr = wv >> 1, wc = wv & 1;
    int at0 = blockIdx.x * 4 + wr * 2;
    int jt0 = blockIdx.y * 4 + wc * 2;

    f32x16 acc[2][2];
    #pragma unroll
    for (int i = 0; i < 2; i++)
        #pragma unroll
        for (int j = 0; j < 2; j++)
            #pragma unroll
            for (int r = 0; r < 16; r++) acc[i][j][r] = 0.f;

    const unsigned short* apx[2];
    const unsigned short* bpx[2];
    #pragma unroll
    for (int i = 0; i < 2; i++) {
        apx[i] = xP32  + (long)(at0 + i) * (64 * 512) + lane * 8;
        bpx[i] = WxP32 + (long)(jt0 + i) * (64 * 512) + lane * 8;
    }
    #pragma unroll 2
    for (int kc = 0; kc < 64; kc++) {
        bf16x8 a[2], b[2];
        #pragma unroll
        for (int i = 0; i < 2; i++) a[i] = *(const bf16x8*)(apx[i] + kc * 512);
        #pragma unroll
        for (int i = 0; i < 2; i++) b[i] = *(const bf16x8*)(bpx[i] + kc * 512);
        #pragma unroll
        for (int i = 0; i < 2; i++)
            #pragma unroll
            for (int j = 0; j < 2; j++)
                acc[i][j] = __builtin_amdgcn_mfma_f32_32x32x16_bf16(a[i], b[j], acc[i][j], 0, 0, 0);
    }
    int col_l = lane & 31, rbase = 4 * (lane >> 5);
    #pragma unroll
    for (int i = 0; i < 2; i++) {
        #pragma unroll
        for (int j = 0; j < 2; j++) {
            int col = (jt0 + j) * 32 + col_l;
            #pragma unroll
            for (int r = 0; r < 16; r++) {
                long m = (long)(at0 + i) * 32 + (r & 3) + 8 * (r >> 2) + rbase;
                actx[m * G4_ + col] = f2bf(acc[i][j][r]);
            }
        }
    }
}

// ------------------------------------------------------------- per step ----

// ONE kernel per step. grid (64 jt, 8 nt), 256 thr = 4 ks-waves; block =
// 16 n x 16 jh x 4 gates. 512 blocks = 2/CU so GEMM of one block overlaps
// the epilogue/atomic tail of the other. Front/epilogue logic as R24.
__global__ __launch_bounds__(256, 2)
void k_step(const unsigned short* __restrict__ actx,   // bf16 [8192][4096]
            const unsigned short* __restrict__ hPin,
            unsigned short* __restrict__ hPout,
            const unsigned short* __restrict__ WhP,    // [256 jti][32 kc][64][8]
            const unsigned short* __restrict__ AW,     // [N][4096][16]
            const unsigned short* __restrict__ Af2,    // [N][H][16]
            const float* __restrict__ pRead,           // [128][16] raw sums
            float* __restrict__ pAcc,                  // [128][16] atomic target
            float* __restrict__ pZero,                 // [128][16] zero duty
            const float* __restrict__ bvec,
            float* __restrict__ c,
            float* __restrict__ out, int t) {
    int tid = threadIdx.x;
    int ks = tid >> 6, lane = tid & 63;
    int cl = lane & 15, kg = lane >> 4;
    int jt = blockIdx.x;
    int nt = blockIdx.y;                 // 16-row tile
    int colbase = jt * 16;

    __shared__ float red[3][64][17];
    __shared__ float act[4][16][17];
    __shared__ float wsm[16][17];

    // ---- front: softmax w for (nloc, jl); jt==0 blocks zero pZero ----
    {
        int nloc_f = tid >> 4, jl_f = tid & 15;
        int n_f = nt * 16 + nloc_f;
        float s = pRead[n_f * 16 + jl_f] * (1.0f / 32.0f);   // /sqrt(H)
        float m = s;
        #pragma unroll
        for (int off = 1; off < 16; off <<= 1) m = fmaxf(m, __shfl_xor(m, off));
        float e = expf(s - m);
        float sum = e;
        #pragma unroll
        for (int off = 1; off < 16; off <<= 1) sum += __shfl_xor(sum, off);
        wsm[nloc_f][jl_f] = e / sum;
        if (jt == 0) pZero[nt * 256 + tid] = 0.f;
    }

    // ---- GEMM: 16 rows x 16 jh x 4 gates over K-quarter 256 (8 kc) ----
    f32x4 acc[4];
    #pragma unroll
    for (int g = 0; g < 4; g++) acc[g] = (f32x4){0.f, 0.f, 0.f, 0.f};

    const unsigned short* abase = hPin + ((long)nt * 32 + ks * 8) * 512 + lane * 8;
    const unsigned short* bb[4];
    #pragma unroll
    for (int g = 0; g < 4; g++)
        bb[g] = WhP + ((long)(g * 64 + jt) * 32 + ks * 8) * 512 + lane * 8;

    #pragma unroll
    for (int i = 0; i < 8; i++) {
        bf16x8 a = *(const bf16x8*)(abase + i * 512);
        #pragma unroll
        for (int g = 0; g < 4; g++) {
            bf16x8 b = *(const bf16x8*)(bb[g] + i * 512);
            acc[g] = __builtin_amdgcn_mfma_f32_16x16x32_bf16(a, b, acc[g], 0, 0, 0);
        }
    }

    // ---- 4-way K reduce ----
    if (ks != 0) {
        #pragma unroll
        for (int g = 0; g < 4; g++)
            #pragma unroll
            for (int v = 0; v < 4; v++) red[ks - 1][lane][g * 4 + v] = acc[g][v];
    }
    __syncthreads();
    if (ks == 0) {
        #pragma unroll
        for (int g = 0; g < 4; g++)
            #pragma unroll
            for (int v = 0; v < 4; v++) {
                float s = acc[g][v] + red[0][lane][g*4+v] + red[1][lane][g*4+v]
                        + red[2][lane][g*4+v];
                act[g][kg * 4 + v][cl] = s;   // C/D row = 4*kg + v
            }
    }
    __syncthreads();

    // ---- epilogue: 256 thr x 1 (n, jh) cell ----
    int nloc = tid >> 4, jl = tid & 15;
    int n = nt * 16 + nloc, jh = colbase + jl;
    float wv16[16];
    #pragma unroll
    for (int p = 0; p < 16; p++) wv16[p] = wsm[nloc][p];

    long rm = (long)(t * 8 + (n >> 4)) * 16 + (n & 15);   // actx row
    float s4[4];
    #pragma unroll
    for (int g = 0; g < 4; g++) {
        int j = g * 1024 + jh;
        const unsigned short* awp = AW + ((long)n * G4_ + j) * 16;
        bf16x8 aw0 = *(const bf16x8*)(awp);
        bf16x8 aw1 = *(const bf16x8*)(awp + 8);
        float at = 0.f;
        #pragma unroll
        for (int p = 0; p < 8; p++) at += wv16[p]     * bf2f((unsigned short)aw0[p]);
        #pragma unroll
        for (int p = 0; p < 8; p++) at += wv16[8 + p] * bf2f((unsigned short)aw1[p]);
        s4[g] = act[g][nloc][jl] + bf2f(actx[rm * G4_ + j]) + at + bvec[j];
    }
    float ig = 1.f / (1.f + expf(-s4[0]));
    float fg = 1.f / (1.f + expf(-s4[1]));
    float og = 1.f / (1.f + expf(-s4[2]));
    float gg = tanhf(s4[3]);
    long idx = (long)n * H_ + jh;
    float cn = fg * c[idx] + ig * gg;
    float hn = og * tanhf(cn);
    c[idx] = cn;
    out[((long)n * T_ + t) * H_ + jh] = hn;
    hPout[((long)((n >> 4) * 32 + (jh >> 5)) * 64 + ((jh >> 3) & 3) * 16 + (n & 15)) * 8 + (jh & 7)] = f2bf(hn);

    // score partials for t+1: 16-lane reduce then ONE atomicAdd per thread
    const unsigned short* afp = Af2 + ((long)n * H_ + jh) * 16;
    bf16x8 af0 = *(const bf16x8*)(afp);
    bf16x8 af1 = *(const bf16x8*)(afp + 8);
    float sp[16];
    #pragma unroll
    for (int p = 0; p < 8; p++) { sp[p]     = hn * bf2f((unsigned short)af0[p]);
                                  sp[8 + p] = hn * bf2f((unsigned short)af1[p]); }
    #pragma unroll
    for (int off = 1; off < 16; off <<= 1) {
        #pragma unroll
        for (int p = 0; p < 16; p++) sp[p] += __shfl_xor(sp[p], off);
    }
    float outv = 0.f;
    #pragma unroll
    for (int p = 0; p < 16; p++) if (jl == p) outv = sp[p];
    atomicAdd(&pAcc[n * 16 + jl], outv);
}

// ---------------------------------------------------------------- launch ----

extern "C" void kernel_launch(void* const* d_in, const int* in_sizes, int n_in,
                              void* d_out, int out_size, void* d_ws, size_t ws_size,
                              hipStream_t stream) {
    const float* x     = (const float*)d_in[0];
    const float* A     = (const float*)d_in[1];
    const float* Wx    = (const float*)d_in[2];
    const float* Wh    = (const float*)d_in[3];
    const float* Wattn = (const float*)d_in[4];
    const float* b     = (const float*)d_in[5];
    float* out = (float*)d_out;

    char* ws = (char*)d_ws;
    size_t off = 0;
    auto alloc = [&](size_t bytes) -> void* {
        void* p = ws + off;
        off += (bytes + 255) & ~(size_t)255;
        return p;
    };
    unsigned short* xP32   = (unsigned short*)alloc((size_t)256 * 64 * 512 * 2);   // 16.8MB
    unsigned short* WxP32  = (unsigned short*)alloc((size_t)128 * 64 * 512 * 2);   // 8.4MB
    unsigned short* WhP    = (unsigned short*)alloc((size_t)256 * 32 * 512 * 2);   // 8.4MB
    unsigned short* WatP32 = (unsigned short*)alloc((size_t)128 * 64 * 512 * 2);   // 8.4MB
    unsigned short* AfP32  = (unsigned short*)alloc((size_t)64 * 64 * 512 * 2);    // 4.2MB
    unsigned short* Af2    = (unsigned short*)alloc((size_t)N_ * H_ * 16 * 2);     // 4.2MB
    unsigned short* AW     = (unsigned short*)alloc((size_t)N_ * G4_ * 16 * 2);    // 16.8MB
    unsigned short* actx   = (unsigned short*)alloc((size_t)8192 * G4_ * 2);       // 67.1MB
    float*          hbuf   = (float*)alloc((size_t)N_ * H_ * 4);
    float*          cbuf   = (float*)alloc((size_t)N_ * H_ * 4);
    unsigned short* hP0    = (unsigned short*)alloc((size_t)8 * 32 * 512 * 2);
    unsigned short* hP1    = (unsigned short*)alloc((size_t)8 * 32 * 512 * 2);
    float*          scr    = (float*)alloc((size_t)N_ * 16 * 64 * 4);
    float*          pb     = (float*)alloc((size_t)3 * N_ * 16 * 4);   // 3 x [128][16]

    // prep
    k_pack_w32<<<dim3(128, 16), dim3(256), 0, stream>>>(Wx,    WxP32);
    k_pack_w  <<<dim3(128, 16), dim3(256), 0, stream>>>(Wh,    WhP, 0, 32);
    k_pack_w32<<<dim3(128, 16), dim3(256), 0, stream>>>(Wattn, WatP32);
    k_pack_x32<<<dim3(4096), dim3(256), 0, stream>>>(x, xP32);
    k_pack_af32<<<dim3(128, 16), dim3(256), 0, stream>>>(A, AfP32, Af2);
    k_h0<<<dim3(512), dim3(256), 0, stream>>>(A, hbuf, cbuf, hP0);
    k_part0<<<dim3(N_), dim3(512), 0, stream>>>(hbuf, Af2, scr);
    k_red0<<<dim3(N_), dim3(64), 0, stream>>>(scr, pb);            // pb[0] = sums
    k_zerobuf<<<dim3(4), dim3(1024), 0, stream>>>(pb + 2048);      // pb[1], pb[2] = 0
    k_aw<<<dim3(16, 32), dim3(256), 0, stream>>>(AfP32, WatP32, AW);
    k_actx<<<dim3(64, 32), dim3(256), 0, stream>>>(xP32, WxP32, actx);

    // recurrence: ONE kernel per step; 3-buffer score-partial rotation
    for (int t = 0; t < T_; t++) {
        unsigned short* hin  = (t & 1) ? hP1 : hP0;
        unsigned short* hout = (t & 1) ? hP0 : hP1;
        float* pRead = pb + (t % 3) * 2048;
        float* pAcc  = pb + ((t + 1) % 3) * 2048;
        float* pZero = pb + ((t + 2) % 3) * 2048;
        k_step<<<dim3(64, 8), dim3(256), 0, stream>>>(actx, hin, hout, WhP, AW, Af2,
                                                      pRead, pAcc, pZero, b, cbuf, out, t);
    }
}

// Round 26
// 855.451 us; speedup vs baseline: 1.4045x; 1.0582x over previous
//
#include <hip/hip_runtime.h>
#include <hip/hip_bf16.h>
#include <cmath>

// Problem constants
#define N_   128
#define T_   64
#define D_   1024
#define H_   1024
#define G4_  4096   // 4*H

typedef short bf16x8  __attribute__((ext_vector_type(8)));
typedef float f32x4   __attribute__((ext_vector_type(4)));
typedef float f32x16  __attribute__((ext_vector_type(16)));

__device__ __forceinline__ unsigned short f2bf(float f) {
    union { float f; unsigned int u; } v; v.f = f;
    unsigned int r = (v.u + 0x7FFFu + ((v.u >> 16) & 1u)) >> 16;  // RNE
    return (unsigned short)r;
}
__device__ __forceinline__ float bf2f(unsigned short s) {
    union { unsigned int u; float f; } v; v.u = ((unsigned int)s) << 16;
    return v.f;
}

// 16-row fragment packing (mfma_f32_16x16x32_bf16, lane = kg*16+cl):
//   P[tile][kc32][lane][8] ; fragment load = base + lane*8 -> 1KB contiguous.
// 32-row fragment packing (mfma_f32_32x32x16_bf16, lane = kgrp*32+row):
//   P32[tile32][kc16][lane][8] ; row = lane&31, k = (lane>>5)*8 + e.
//   C/D: col = lane&31, row = (reg&3) + 8*(reg>>2) + 4*(lane>>5).
// Score partials: tiny [128][16] accumulator, atomicAdd from k_step epilogue;
// 3-buffer rotation (read t%3 / acc (t+1)%3 / zero (t+2)%3).

// ---------------------------------------------------------------- prep ----

// 16-row pack (WhP only): src f32 [1024][4096] k-major -> P[jti][kc][64][8].
__global__ void k_pack_w(const float* __restrict__ src, unsigned short* __restrict__ dst,
                         int kcoff, int kctot) {
    __shared__ float ld[64][33];
    int j0 = blockIdx.x * 32, k0 = blockIdx.y * 64;
    int tid = threadIdx.x;
    int c = tid & 31, r = tid >> 5;
    #pragma unroll
    for (int i = 0; i < 8; i++)
        ld[r + i * 8][c] = src[(long)(k0 + r + i * 8) * G4_ + j0 + c];
    __syncthreads();
    int j = tid & 31, ku = tid >> 5;
    int kcl = ku >> 2, kg = ku & 3;
    int jti = (j0 + j) >> 4, cl = (j0 + j) & 15;
    int kc = kcoff + (k0 >> 5) + kcl;
    unsigned short q[8];
    #pragma unroll
    for (int e = 0; e < 8; e++) q[e] = f2bf(ld[ku * 8 + e][j]);
    *(uint4*)(dst + ((long)(jti * kctot + kc) * 64 + kg * 16 + cl) * 8) = *(uint4*)q;
}

// 32-row pack: src f32 [1024][4096] k-major -> P32[j>>5][kc16][64][8].
__global__ void k_pack_w32(const float* __restrict__ src, unsigned short* __restrict__ dst) {
    __shared__ float ld[64][33];
    int j0 = blockIdx.x * 32, k0 = blockIdx.y * 64;
    int tid = threadIdx.x;
    int c = tid & 31, r = tid >> 5;
    #pragma unroll
    for (int i = 0; i < 8; i++)
        ld[r + i * 8][c] = src[(long)(k0 + r + i * 8) * G4_ + j0 + c];
    __syncthreads();
    int cl = tid & 31, kgrp = (tid >> 5) & 1, kcl = tid >> 6;   // kcl 0..3
    int kc = (k0 >> 4) + kcl;
    unsigned short q[8];
    #pragma unroll
    for (int e = 0; e < 8; e++) q[e] = f2bf(ld[kcl * 16 + kgrp * 8 + e][cl]);
    *(uint4*)(dst + (((long)blockIdx.x * 64 + kc) * 64 + kgrp * 32 + cl) * 8) = *(uint4*)q;
}

// x f32 [N][T][D] -> xP32 rows m = t*128+n: tile32 = t*4 + (n>>5), row = n&31.
__global__ void k_pack_x32(const float* __restrict__ x, unsigned short* __restrict__ xP32) {
    long gid = (long)blockIdx.x * 256 + threadIdx.x;   // 8192*128
    int mm = (int)(gid >> 7), u = (int)(gid & 127);
    const float* src = x + (long)mm * 1024 + u * 8;
    int n = mm >> 6, t = mm & 63;
    int tile = t * 4 + (n >> 5);
    int row = n & 31;
    int kc = u >> 1, kgrp = u & 1;
    float4 a = *(const float4*)src, b = *(const float4*)(src + 4);
    unsigned short q[8] = {f2bf(a.x), f2bf(a.y), f2bf(a.z), f2bf(a.w),
                           f2bf(b.x), f2bf(b.y), f2bf(b.z), f2bf(b.w)};
    *(uint4*)(xP32 + (((long)tile * 64 + kc) * 64 + kgrp * 32 + row) * 8) = *(uint4*)q;
}

// A f32 [N][H][16] -> AfP32 (rows = n*16+p: tile = n>>1, row = (n&1)*16+p) + Af2.
__global__ void k_pack_af32(const float* __restrict__ A, unsigned short* __restrict__ AfP32,
                            unsigned short* __restrict__ Af2) {
    __shared__ float ld[64][17];
    int n = blockIdx.x, h0 = blockIdx.y * 64;
    int tid = threadIdx.x;
    int hh = tid >> 2, pq = tid & 3;
    float4 v = *(const float4*)(A + ((long)n * H_ + h0 + hh) * 16 + pq * 4);
    unsigned short o[4] = {f2bf(v.x), f2bf(v.y), f2bf(v.z), f2bf(v.w)};
    *(uint2*)(Af2 + ((long)n * H_ + h0 + hh) * 16 + pq * 4) = *(uint2*)o;
    ld[hh][pq * 4 + 0] = v.x; ld[hh][pq * 4 + 1] = v.y;
    ld[hh][pq * 4 + 2] = v.z; ld[hh][pq * 4 + 3] = v.w;
    __syncthreads();
    if (tid < 128) {
        int p = tid >> 3, ku = tid & 7;
        int kc = (h0 >> 4) + (ku >> 1), kgrp = ku & 1;
        int row = (n & 1) * 16 + p;
        unsigned short q[8];
        #pragma unroll
        for (int e = 0; e < 8; e++) q[e] = f2bf(ld[ku * 8 + e][p]);
        *(uint4*)(AfP32 + (((long)(n >> 1) * 64 + kc) * 64 + kgrp * 32 + row) * 8) = *(uint4*)q;
    }
}

// h0 = mean_p A; c0 = h0; packed h0.
__global__ void k_h0(const float* __restrict__ A, float* __restrict__ h,
                     float* __restrict__ c, unsigned short* __restrict__ hP0) {
    long id = (long)blockIdx.x * 256 + threadIdx.x;
    const float4* ap = (const float4*)(A + id * 16);
    float s = 0.f;
    #pragma unroll
    for (int q = 0; q < 4; q++) { float4 v = ap[q]; s += v.x + v.y + v.z + v.w; }
    float m = s * (1.0f / 16.0f);
    h[id] = m; c[id] = m;
    int n = (int)(id >> 10), j = (int)(id & 1023);
    hP0[((long)((n >> 4) * 32 + (j >> 5)) * 64 + ((j >> 3) & 3) * 16 + (n & 15)) * 8 + (j & 7)] = f2bf(m);
}

// t=0 score partials (per-jt scratch)
__global__ __launch_bounds__(512)
void k_part0(const float* __restrict__ hbuf, const unsigned short* __restrict__ Af2,
             float* __restrict__ partial0) {
    int n = blockIdx.x;
    int tid = threadIdx.x;
    int jh = tid * 2;
    float sp[16];
    #pragma unroll
    for (int p = 0; p < 16; p++) sp[p] = 0.f;
    #pragma unroll
    for (int u = 0; u < 2; u++) {
        float hv = hbuf[(long)n * H_ + jh + u];
        const unsigned short* afp = Af2 + ((long)n * H_ + jh + u) * 16;
        bf16x8 a0 = *(const bf16x8*)(afp);
        bf16x8 a1 = *(const bf16x8*)(afp + 8);
        #pragma unroll
        for (int p = 0; p < 8; p++) { sp[p] += hv * bf2f((unsigned short)a0[p]);
                                      sp[8+p] += hv * bf2f((unsigned short)a1[p]); }
    }
    #pragma unroll
    for (int off = 1; off < 8; off <<= 1) {
        #pragma unroll
        for (int p = 0; p < 16; p++) sp[p] += __shfl_xor(sp[p], off);
    }
    int jt = tid >> 3;
    if ((tid & 7) == 0) {
        #pragma unroll
        for (int p = 0; p < 16; p++)
            partial0[((long)n * 16 + p) * 64 + jt] = sp[p];
    }
}

// prep: reduce scratch -> pbuf0 raw sums [128][16]
__global__ __launch_bounds__(64)
void k_red0(const float* __restrict__ partial, float* __restrict__ p0) {
    int n = blockIdx.x;
    int lane = threadIdx.x;
    int p = lane & 15, c4 = lane >> 4;
    const float* src = partial + ((long)n * 16 + p) * 64 + c4 * 16;
    float s = 0.f;
    #pragma unroll
    for (int q = 0; q < 16; q++) s += src[q];
    s += __shfl_xor(s, 16);
    s += __shfl_xor(s, 32);
    if (c4 == 0) p0[n * 16 + p] = s;
}

__global__ void k_zerobuf(float* __restrict__ p) {
    p[blockIdx.x * 1024 + threadIdx.x] = 0.f;
}

// AW = AfP32 @ WattnP32^T via 32x32x16 MFMA (R23-proven).
__global__ __launch_bounds__(256, 2)
void k_aw(const unsigned short* __restrict__ AfP32, const unsigned short* __restrict__ WattnP32,
          unsigned short* __restrict__ AW) {
    int tid = threadIdx.x;
    int wv = tid >> 6, lane = tid & 63;
    int wr = wv >> 1, wc = wv & 1;
    int at0 = blockIdx.x * 4 + wr * 2;
    int jt0 = blockIdx.y * 4 + wc * 2;

    f32x16 acc[2][2];
    #pragma unroll
    for (int i = 0; i < 2; i++)
        #pragma unroll
        for (int j = 0; j < 2; j++)
            #pragma unroll
            for (int r = 0; r < 16; r++) acc[i][j][r] = 0.f;

    const unsigned short* apx[2];
    const unsigned short* bpx[2];
    #pragma unroll
    for (int i = 0; i < 2; i++) {
        apx[i] = AfP32     + (long)(at0 + i) * (64 * 512) + lane * 8;
        bpx[i] = WattnP32  + (long)(jt0 + i) * (64 * 512) + lane * 8;
    }
    #pragma unroll 2
    for (int kc = 0; kc < 64; kc++) {
        bf16x8 a[2], b[2];
        #pragma unroll
        for (int i = 0; i < 2; i++) a[i] = *(const bf16x8*)(apx[i] + kc * 512);
        #pragma unroll
        for (int i = 0; i < 2; i++) b[i] = *(const bf16x8*)(bpx[i] + kc * 512);
        #pragma unroll
        for (int i = 0; i < 2; i++)
            #pragma unroll
            for (int j = 0; j < 2; j++)
                acc[i][j] = __builtin_amdgcn_mfma_f32_32x32x16_bf16(a[i], b[j], acc[i][j], 0, 0, 0);
    }
    int col_l = lane & 31, rbase = 4 * (lane >> 5);
    #pragma unroll
    for (int i = 0; i < 2; i++) {
        #pragma unroll
        for (int j = 0; j < 2; j++) {
            int col = (jt0 + j) * 32 + col_l;
            #pragma unroll
            for (int r = 0; r < 16; r++) {
                int grow = (at0 + i) * 32 + (r & 3) + 8 * (r >> 2) + rbase;
                int n = grow >> 4, p = grow & 15;
                AW[((long)n * G4_ + col) * 16 + p] = f2bf(acc[i][j][r]);
            }
        }
    }
}

// actx = xP32 @ WxP32^T via 32x32x16 MFMA (R23-proven).
__global__ __launch_bounds__(256, 2)
void k_actx(const unsigned short* __restrict__ xP32, const unsigned short* __restrict__ WxP32,
            unsigned short* __restrict__ actx) {
    int tid = threadIdx.x;
    int wv = tid >> 6, lane = tid & 63;
    int wr = wv >> 1, wc = wv & 1;
    int at0 = blockIdx.x * 4 + wr * 2;
    int jt0 = blockIdx.y * 4 + wc * 2;

    f32x16 acc[2][2];
    #pragma unroll
    for (int i = 0; i < 2; i++)
        #pragma unroll
        for (int j = 0; j < 2; j++)
            #pragma unroll
            for (int r = 0; r < 16; r++) acc[i][j][r] = 0.f;

    const unsigned short* apx[2];
    const unsigned short* bpx[2];
    #pragma unroll
    for (int i = 0; i < 2; i++) {
        apx[i] = xP32  + (long)(at0 + i) * (64 * 512) + lane * 8;
        bpx[i] = WxP32 + (long)(jt0 + i) * (64 * 512) + lane * 8;
    }
    #pragma unroll 2
    for (int kc = 0; kc < 64; kc++) {
        bf16x8 a[2], b[2];
        #pragma unroll
        for (int i = 0; i < 2; i++) a[i] = *(const bf16x8*)(apx[i] + kc * 512);
        #pragma unroll
        for (int i = 0; i < 2; i++) b[i] = *(const bf16x8*)(bpx[i] + kc * 512);
        #pragma unroll
        for (int i = 0; i < 2; i++)
            #pragma unroll
            for (int j = 0; j < 2; j++)
                acc[i][j] = __builtin_amdgcn_mfma_f32_32x32x16_bf16(a[i], b[j], acc[i][j], 0, 0, 0);
    }
    int col_l = lane & 31, rbase = 4 * (lane >> 5);
    #pragma unroll
    for (int i = 0; i < 2; i++) {
        #pragma unroll
        for (int j = 0; j < 2; j++) {
            int col = (jt0 + j) * 32 + col_l;
            #pragma unroll
            for (int r = 0; r < 16; r++) {
                long m = (long)(at0 + i) * 32 + (r & 3) + 8 * (r >> 2) + rbase;
                actx[m * G4_ + col] = f2bf(acc[i][j][r]);
            }
        }
    }
}

// ------------------------------------------------------------- per step ----

// ONE kernel per step. grid (64 jt, 8 nt), 512 thr = 8 waves (g:4 x ks:2)
// = 2 blocks/CU x 8 waves = 16 waves/CU (2x R24/R25 TLP).
// Wave: 16 rows x 16 jh x 1 gate over K=512 (16 iters, 1A+1B->1 MFMA);
// A-frags L1-shared by the 4 gate-waves. 2-way LDS K-reduce (1 round).
__global__ __launch_bounds__(512, 2)
void k_step(const unsigned short* __restrict__ actx,   // bf16 [8192][4096]
            const unsigned short* __restrict__ hPin,
            unsigned short* __restrict__ hPout,
            const unsigned short* __restrict__ WhP,    // [256 jti][32 kc][64][8]
            const unsigned short* __restrict__ AW,     // [N][4096][16]
            const unsigned short* __restrict__ Af2,    // [N][H][16]
            const float* __restrict__ pRead,           // [128][16] raw sums
            float* __restrict__ pAcc,                  // [128][16] atomic target
            float* __restrict__ pZero,                 // [128][16] zero duty
            const float* __restrict__ bvec,
            float* __restrict__ c,
            float* __restrict__ out, int t) {
    int tid = threadIdx.x;
    int wv = tid >> 6, lane = tid & 63;
    int g = wv & 3, ks = wv >> 2;        // gate, K-half
    int cl = lane & 15, kg = lane >> 4;
    int jt = blockIdx.x;
    int nt = blockIdx.y;                 // 16-row tile
    int colbase = jt * 16;

    __shared__ float red[4][64][17];
    __shared__ float act[4][16][17];
    __shared__ float wsm[16][17];

    // ---- front (tid<256): softmax w; jt==0 blocks zero pZero ----
    if (tid < 256) {
        int nloc_f = tid >> 4, jl_f = tid & 15;
        int n_f = nt * 16 + nloc_f;
        float s = pRead[n_f * 16 + jl_f] * (1.0f / 32.0f);   // /sqrt(H)
        float m = s;
        #pragma unroll
        for (int off = 1; off < 16; off <<= 1) m = fmaxf(m, __shfl_xor(m, off));
        float e = expf(s - m);
        float sum = e;
        #pragma unroll
        for (int off = 1; off < 16; off <<= 1) sum += __shfl_xor(sum, off);
        wsm[nloc_f][jl_f] = e / sum;
        if (jt == 0) pZero[nt * 256 + tid] = 0.f;
    }

    // ---- GEMM: 16 rows x 16 jh x 1 gate over K-half 512 (16 kc) ----
    f32x4 acc = (f32x4){0.f, 0.f, 0.f, 0.f};
    const unsigned short* abase = hPin + ((long)nt * 32 + ks * 16) * 512 + lane * 8;
    const unsigned short* bbase = WhP + ((long)(g * 64 + jt) * 32 + ks * 16) * 512 + lane * 8;

    #pragma unroll
    for (int i = 0; i < 16; i++) {
        bf16x8 a = *(const bf16x8*)(abase + i * 512);
        bf16x8 b = *(const bf16x8*)(bbase + i * 512);
        acc = __builtin_amdgcn_mfma_f32_16x16x32_bf16(a, b, acc, 0, 0, 0);
    }

    // ---- 2-way K reduce (1 round) ----
    if (ks == 1) {
        #pragma unroll
        for (int v = 0; v < 4; v++) red[g][lane][v] = acc[v];
    }
    __syncthreads();
    if (ks == 0) {
        #pragma unroll
        for (int v = 0; v < 4; v++)
            act[g][kg * 4 + v][cl] = acc[v] + red[g][lane][v];   // C/D row = 4*kg + v
    }
    __syncthreads();

    // ---- epilogue (tid<256): 1 (n, jh) cell ----
    if (tid < 256) {
        int nloc = tid >> 4, jl = tid & 15;
        int n = nt * 16 + nloc, jh = colbase + jl;
        float wv16[16];
        #pragma unroll
        for (int p = 0; p < 16; p++) wv16[p] = wsm[nloc][p];

        long rm = (long)(t * 8 + (n >> 4)) * 16 + (n & 15);   // actx row
        float s4[4];
        #pragma unroll
        for (int gg2 = 0; gg2 < 4; gg2++) {
            int j = gg2 * 1024 + jh;
            const unsigned short* awp = AW + ((long)n * G4_ + j) * 16;
            bf16x8 aw0 = *(const bf16x8*)(awp);
            bf16x8 aw1 = *(const bf16x8*)(awp + 8);
            float at = 0.f;
            #pragma unroll
            for (int p = 0; p < 8; p++) at += wv16[p]     * bf2f((unsigned short)aw0[p]);
            #pragma unroll
            for (int p = 0; p < 8; p++) at += wv16[8 + p] * bf2f((unsigned short)aw1[p]);
            s4[gg2] = act[gg2][nloc][jl] + bf2f(actx[rm * G4_ + j]) + at + bvec[j];
        }
        float ig = 1.f / (1.f + expf(-s4[0]));
        float fg = 1.f / (1.f + expf(-s4[1]));
        float og = 1.f / (1.f + expf(-s4[2]));
        float gv = tanhf(s4[3]);
        long idx = (long)n * H_ + jh;
        float cn = fg * c[idx] + ig * gv;
        float hn = og * tanhf(cn);
        c[idx] = cn;
        out[((long)n * T_ + t) * H_ + jh] = hn;
        hPout[((long)((n >> 4) * 32 + (jh >> 5)) * 64 + ((jh >> 3) & 3) * 16 + (n & 15)) * 8 + (jh & 7)] = f2bf(hn);

        // score partials for t+1: 16-lane reduce then ONE atomicAdd
        const unsigned short* afp = Af2 + ((long)n * H_ + jh) * 16;
        bf16x8 af0 = *(const bf16x8*)(afp);
        bf16x8 af1 = *(const bf16x8*)(afp + 8);
        float sp[16];
        #pragma unroll
        for (int p = 0; p < 8; p++) { sp[p]     = hn * bf2f((unsigned short)af0[p]);
                                      sp[8 + p] = hn * bf2f((unsigned short)af1[p]); }
        #pragma unroll
        for (int off = 1; off < 16; off <<= 1) {
            #pragma unroll
            for (int p = 0; p < 16; p++) sp[p] += __shfl_xor(sp[p], off);
        }
        float outv = 0.f;
        #pragma unroll
        for (int p = 0; p < 16; p++) if (jl == p) outv = sp[p];
        atomicAdd(&pAcc[n * 16 + jl], outv);
    }
}

// ---------------------------------------------------------------- launch ----

extern "C" void kernel_launch(void* const* d_in, const int* in_sizes, int n_in,
                              void* d_out, int out_size, void* d_ws, size_t ws_size,
                              hipStream_t stream) {
    const float* x     = (const float*)d_in[0];
    const float* A     = (const float*)d_in[1];
    const float* Wx    = (const float*)d_in[2];
    const float* Wh    = (const float*)d_in[3];
    const float* Wattn = (const float*)d_in[4];
    const float* b     = (const float*)d_in[5];
    float* out = (float*)d_out;

    char* ws = (char*)d_ws;
    size_t off = 0;
    auto alloc = [&](size_t bytes) -> void* {
        void* p = ws + off;
        off += (bytes + 255) & ~(size_t)255;
        return p;
    };
    unsigned short* xP32   = (unsigned short*)alloc((size_t)256 * 64 * 512 * 2);   // 16.8MB
    unsigned short* WxP32  = (unsigned short*)alloc((size_t)128 * 64 * 512 * 2);   // 8.4MB
    unsigned short* WhP    = (unsigned short*)alloc((size_t)256 * 32 * 512 * 2);   // 8.4MB
    unsigned short* WatP32 = (unsigned short*)alloc((size_t)128 * 64 * 512 * 2);   // 8.4MB
    unsigned short* AfP32  = (unsigned short*)alloc((size_t)64 * 64 * 512 * 2);    // 4.2MB
    unsigned short* Af2    = (unsigned short*)alloc((size_t)N_ * H_ * 16 * 2);     // 4.2MB
    unsigned short* AW     = (unsigned short*)alloc((size_t)N_ * G4_ * 16 * 2);    // 16.8MB
    unsigned short* actx   = (unsigned short*)alloc((size_t)8192 * G4_ * 2);       // 67.1MB
    float*          hbuf   = (float*)alloc((size_t)N_ * H_ * 4);
    float*          cbuf   = (float*)alloc((size_t)N_ * H_ * 4);
    unsigned short* hP0    = (unsigned short*)alloc((size_t)8 * 32 * 512 * 2);
    unsigned short* hP1    = (unsigned short*)alloc((size_t)8 * 32 * 512 * 2);
    float*          scr    = (float*)alloc((size_t)N_ * 16 * 64 * 4);
    float*          pb     = (float*)alloc((size_t)3 * N_ * 16 * 4);   // 3 x [128][16]

    // prep
    k_pack_w32<<<dim3(128, 16), dim3(256), 0, stream>>>(Wx,    WxP32);
    k_pack_w  <<<dim3(128, 16), dim3(256), 0, stream>>>(Wh,    WhP, 0, 32);
    k_pack_w32<<<dim3(128, 16), dim3(256), 0, stream>>>(Wattn, WatP32);
    k_pack_x32<<<dim3(4096), dim3(256), 0, stream>>>(x, xP32);
    k_pack_af32<<<dim3(128, 16), dim3(256), 0, stream>>>(A, AfP32, Af2);
    k_h0<<<dim3(512), dim3(256), 0, stream>>>(A, hbuf, cbuf, hP0);
    k_part0<<<dim3(N_), dim3(512), 0, stream>>>(hbuf, Af2, scr);
    k_red0<<<dim3(N_), dim3(64), 0, stream>>>(scr, pb);            // pb[0] = sums
    k_zerobuf<<<dim3(4), dim3(1024), 0, stream>>>(pb + 2048);      // pb[1], pb[2] = 0
    k_aw<<<dim3(16, 32), dim3(256), 0, stream>>>(AfP32, WatP32, AW);
    k_actx<<<dim3(64, 32), dim3(256), 0, stream>>>(xP32, WxP32, actx);

    // recurrence: ONE kernel per step; 3-buffer score-partial rotation
    for (int t = 0; t < T_; t++) {
        unsigned short* hin  = (t & 1) ? hP1 : hP0;
        unsigned short* hout = (t & 1) ? hP0 : hP1;
        float* pRead = pb + (t % 3) * 2048;
        float* pAcc  = pb + ((t + 1) % 3) * 2048;
        float* pZero = pb + ((t + 2) % 3) * 2048;
        k_step<<<dim3(64, 8), dim3(512), 0, stream>>>(actx, hin, hout, WhP, AW, Af2,
                                                      pRead, pAcc, pZero, b, cbuf, out, t);
    }
}